// Round 5
// baseline (298.400 us; speedup 1.0000x reference)
//
#include <hip/hip_runtime.h>

typedef _Float16 half8 __attribute__((ext_vector_type(8)));
typedef _Float16 half4 __attribute__((ext_vector_type(4)));
typedef _Float16 h2    __attribute__((ext_vector_type(2)));
typedef __fp16  fp16x2 __attribute__((ext_vector_type(2)));
typedef float floatx4 __attribute__((ext_vector_type(4)));

#define TPB 256

// quad-table geometry (cells = res*res, row stride res, matching reference's
// tab[y*res+x] indexing; clamp x1=min(x0+1,res) never binds for u,v in [0,1))
#define NC0 (512 * 512)
#define NC1 (264 * 264)
#define NC2 (16 * 16)

struct GAddr { int i00, i10, i01, i11; float wx, wy; };

__device__ __forceinline__ GAddr gaddr(int res, float u, float v) {
    float r = (float)res;
    float sx = u * r, sy = v * r;
    int x0 = (int)sx, y0 = (int)sy;            // truncation, matches astype(int32)
    float wx = sx - (float)x0, wy = sy - (float)y0;
    int x1 = min(x0 + 1, res), y1 = min(y0 + 1, res);
    GAddr g;
    g.i00 = y0 * res + x0;  g.i10 = y0 * res + x1;   // reference stride = res
    g.i01 = y1 * res + x0;  g.i11 = y1 * res + x1;
    g.wx = wx; g.wy = wy;
    return g;
}

struct GQ { int c; float wx, wy; };

__device__ __forceinline__ GQ gq(int res, float u, float v) {
    float r = (float)res;
    float sx = u * r, sy = v * r;
    int x0 = (int)sx, y0 = (int)sy;
    GQ g; g.c = y0 * res + x0; g.wx = sx - (float)x0; g.wy = sy - (float)y0;
    return g;
}

__device__ __forceinline__ void bil4(float4 v00, float4 v10, float4 v01, float4 v11,
                                     float wx, float wy, float* f) {
    float omx = 1.0f - wx, omy = 1.0f - wy;
    f[0] = (v00.x * omx + v10.x * wx) * omy + (v01.x * omx + v11.x * wx) * wy;
    f[1] = (v00.y * omx + v10.y * wx) * omy + (v01.y * omx + v11.y * wx) * wy;
    f[2] = (v00.z * omx + v10.z * wx) * omy + (v01.z * omx + v11.z * wx) * wy;
    f[3] = (v00.w * omx + v10.w * wx) * omy + (v01.w * omx + v11.w * wx) * wy;
}

__device__ __forceinline__ h2 pk2(float a, float b) {
    fp16x2 r = __builtin_amdgcn_cvt_pkrtz(a, b);
    union { fp16x2 f; h2 h; } u; u.f = r; return u.h;
}

// packed-fp16 bilinear on a 32B quad {v00[4],v10[4]} {v01[4],v11[4]}.
// 12 v_pk ops + 4 pkrtz; outputs f[0]=(feat0,feat1), f[1]=(feat2,feat3).
__device__ __forceinline__ void bilq(half8 q0, half8 q1, float wx, float wy, h2* f) {
    h2 wx2  = pk2(wx, wx),           wy2  = pk2(wy, wy);
    h2 omx2 = pk2(1.f - wx, 1.f - wx), omy2 = pk2(1.f - wy, 1.f - wy);
    union { half8 v; h2 p[4]; } a, b;
    a.v = q0; b.v = q1;
    h2 t0 = a.p[0] * omx2 + a.p[2] * wx2;
    h2 t1 = a.p[1] * omx2 + a.p[3] * wx2;
    h2 c0 = b.p[0] * omx2 + b.p[2] * wx2;
    h2 c1 = b.p[1] * omx2 + b.p[3] * wx2;
    f[0] = t0 * omy2 + c0 * wy2;
    f[1] = t1 * omy2 + c1 * wy2;
}

// relu (f32) then packed f32->f16 convert: 4 v_max + 2 v_cvt_pkrtz.
__device__ __forceinline__ half4 relu_pk4(float a, float b, float c, float d) {
    union { half4 v; fp16x2 p[2]; } u;
    u.p[0] = __builtin_amdgcn_cvt_pkrtz(fmaxf(a, 0.0f), fmaxf(b, 0.0f));
    u.p[1] = __builtin_amdgcn_cvt_pkrtz(fmaxf(c, 0.0f), fmaxf(d, 0.0f));
    return u.v;
}

// ---- per-launch table pack: float4 corner tables -> fp16 quad tables in ws.
// cell (y,x) of table t -> 32B = {v00,v10}{v01,v11} fp16. 32B-aligned so a
// quad never straddles a 64B line: gathers go 4 divergent loads -> 1 address.
__global__ void pack_tables(const float4* __restrict__ e0,
                            const float4* __restrict__ e1,
                            const float4* __restrict__ e2,
                            half8* __restrict__ q)
{
    int c = blockIdx.x * blockDim.x + threadIdx.x;
    const float4* src; int res, qb;
    if (c < NC0)                    { src = e0; res = 512; qb = 0; }
    else if (c < NC0 + NC1)         { src = e1; res = 264; qb = 2 * NC0; c -= NC0; }
    else if (c < NC0 + NC1 + NC2)   { src = e2; res = 16;  qb = 2 * (NC0 + NC1); c -= NC0 + NC1; }
    else return;
    float4 A = src[c], B = src[c + 1], C = src[c + res], D = src[c + res + 1];
    union { half8 v; fp16x2 p[4]; } u0, u1;
    u0.p[0] = __builtin_amdgcn_cvt_pkrtz(A.x, A.y);
    u0.p[1] = __builtin_amdgcn_cvt_pkrtz(A.z, A.w);
    u0.p[2] = __builtin_amdgcn_cvt_pkrtz(B.x, B.y);
    u0.p[3] = __builtin_amdgcn_cvt_pkrtz(B.z, B.w);
    u1.p[0] = __builtin_amdgcn_cvt_pkrtz(C.x, C.y);
    u1.p[1] = __builtin_amdgcn_cvt_pkrtz(C.z, C.w);
    u1.p[2] = __builtin_amdgcn_cvt_pkrtz(D.x, D.y);
    u1.p[3] = __builtin_amdgcn_cvt_pkrtz(D.z, D.w);
    q[qb + 2 * c]     = u0.v;
    q[qb + 2 * c + 1] = u1.v;
}

// Round-4 findings: quad-pack removed the TCP-request wall (196->130us,
// VALU 35->45%, Mfma 13->19%). Cycle accounting still shows ~75% stall
// (4.9K cyc/tile vs ~1K issue) with nothing saturated -> latency-bound at
// 3 waves/SIMD. Round-1's "more waves didn't help" was under TCP saturation
// and no longer applies. This round: (256,4) -> 128-reg budget -> 4
// waves/SIMD (fits: arch VGPR 76 + ~30 pipeline/acc regs < 128; the old
// (256,4) spill was with 32 float4-prefetch + 56 weight regs, since removed),
// grid 1024 = 4 blocks/CU; emb2 folded into the prefetch pipeline so no
// synchronous load sits at the head of the per-tile dependency chain.
__global__ __launch_bounds__(TPB, 4) void dgn_mfma(
    const float*  __restrict__ x,
    const half8*  __restrict__ qt,
    const float*  __restrict__ w1, const float* __restrict__ b1,
    const float*  __restrict__ w2, const float* __restrict__ b2,
    const float*  __restrict__ w3, const float* __restrict__ b3,
    float*        __restrict__ out, int npts)
{
    __shared__ __align__(16) _Float16 smem[4 * 4096];   // 4 waves * 8KB, wave-private
    __shared__ __align__(16) _Float16 w2l[4096];        // 8KB shared w2 fragments

    const half8* q0t = qt;
    const half8* q1t = qt + 2 * NC0;
    const half8* q2t = qt + 2 * (NC0 + NC1);

    const int tid  = threadIdx.x;
    const int lane = tid & 63;
    const int wv   = tid >> 6;
    const int l15  = lane & 15;
    const int quad = lane >> 4;

    // ---- one-time w2 fragment staging into LDS (swizzled like rd2) ----
    for (int e = tid; e < 4096; e += TPB) {
        int nt = e >> 10, rem = e & 1023, lw = rem >> 6, s = rem & 63;
        int oh = ((s & 3) << 4) | (s >> 2);             // sigma^{-1}
        w2l[nt * 1024 + lw * 64 + (s ^ ((lw & 7) << 3))] =
            (_Float16)w2[oh * 64 + nt * 16 + lw];
    }
    __syncthreads();

    // ---- persistent weight fragments. w1 K-permutation: slot k<12 -> row k+1
    // (features), slot 12 -> row 0 (idf), slots 13-15 -> zero. ----
    half8 w1f[4];
    #pragma unroll
    for (int nt = 0; nt < 4; ++nt)
        #pragma unroll
        for (int j = 0; j < 8; ++j) {
            int k = quad * 8 + j;
            int row = (k < 12) ? (k + 1) : ((k == 12) ? 0 : -1);
            w1f[nt][j] = (row >= 0) ? (_Float16)w1[row * 64 + nt * 16 + l15] : (_Float16)0.0f;
        }
    float b1v[4], b2v[4];
    #pragma unroll
    for (int nt = 0; nt < 4; ++nt) { b1v[nt] = b1[nt * 16 + l15]; b2v[nt] = b2[nt * 16 + l15]; }
    half8 w3f[2];
    #pragma unroll
    for (int ks = 0; ks < 2; ++ks)
        #pragma unroll
        for (int j = 0; j < 8; ++j) {
            int s  = ks * 32 + quad * 8 + j;
            int oh = ((s & 3) << 4) | (s >> 2);
            w3f[ks][j] = (l15 < 3) ? (_Float16)w3[oh * 3 + l15] : (_Float16)0.0f;
        }
    const float qsel = (quad == 0) ? 1.0f : 0.0f;
    const float qb30 = qsel * b3[0], qb31 = qsel * b3[1], qb32 = qsel * b3[2];

    // ---- precomputed LDS addresses (half-element units) ----
    const int bufh = wv * 4096;
    const int ewr0 = bufh + lane * 64 + ((lane & 7) ^ 0) * 8;
    const int ewr1 = bufh + lane * 64 + ((lane & 7) ^ 1) * 8;
    const int erd  = bufh + l15 * 64 + (quad ^ (l15 & 7)) * 8;          // quad<2 only
    int hwb[4];
    #pragma unroll
    for (int r = 0; r < 4; ++r) {
        int pr = quad * 4 + r;
        hwb[r] = bufh + pr * 64 + (((l15 >> 1) ^ (pr & 7)) * 8) + (l15 & 1) * 4;
    }
    int rd2[2];
    #pragma unroll
    for (int ks = 0; ks < 2; ++ks)
        rd2[ks] = bufh + l15 * 64 + (((ks * 4 + quad) ^ (l15 & 7)) * 8);
    int w2a[2];
    #pragma unroll
    for (int ks = 0; ks < 2; ++ks)
        w2a[ks] = l15 * 64 + (((ks * 4 + quad) ^ (l15 & 7)) * 8);

    const int ntiles = npts >> 8;
    const int gdim   = gridDim.x;

    // ---- prologue: tile-0 x + all three quad loads in flight ----
    float cidf, cu, cv, wx0, wy0, wx1, wy1, wx2, wy2;
    half8 t0a, t0b, t1a, t1b, t2a, t2b;
    {
        int p0 = (blockIdx.x << 8) + (wv << 6) + lane;
        cidf = x[3 * p0]; cu = x[3 * p0 + 1]; cv = x[3 * p0 + 2];
        GQ g0 = gq(512, cu, cv); wx0 = g0.wx; wy0 = g0.wy;
        t0a = q0t[2 * g0.c]; t0b = q0t[2 * g0.c + 1];
        GQ g1 = gq(264, cu, cv); wx1 = g1.wx; wy1 = g1.wy;
        t1a = q1t[2 * g1.c]; t1b = q1t[2 * g1.c + 1];
        GQ g2 = gq(16, cu, cv); wx2 = g2.wx; wy2 = g2.wy;
        t2a = q2t[2 * g2.c]; t2b = q2t[2 * g2.c + 1];
    }

    for (int tile = blockIdx.x; tile < ntiles; tile += gdim) {
        // ---- finish current tile's features (packed-fp16 lerp, no loads) ----
        h2 F0[2], F1[2], F2[2];
        bilq(t0a, t0b, wx0, wy0, F0);
        bilq(t1a, t1b, wx1, wy1, F1);
        bilq(t2a, t2b, wx2, wy2, F2);
        // E pack: slots 0-11 = features, slot 12 = idf, 13-15 = 0
        union H8 { half8 v; h2 p[4]; } e0u, e1u;
        e0u.p[0] = F0[0]; e0u.p[1] = F0[1]; e0u.p[2] = F1[0]; e0u.p[3] = F1[1];
        e1u.p[0] = F2[0]; e1u.p[1] = F2[1];
        e1u.p[2] = pk2(cidf, 0.0f); e1u.p[3] = pk2(0.0f, 0.0f);
        *(half8*)&smem[ewr0] = e0u.v;
        *(half8*)&smem[ewr1] = e1u.v;

        // ---- prefetch next tile's x (latency hidden by layer 1) ----
        int nxt = tile + gdim;
        int ptn = (((nxt < ntiles) ? nxt : tile) << 8) + (wv << 6) + lane;
        float nidf = x[3 * ptn], nu = x[3 * ptn + 1], nv = x[3 * ptn + 2];

        // ---- layer 1: K=32 (quads 2-3 feed zeros), bias in C-init ----
        #pragma unroll
        for (int mt = 0; mt < 4; ++mt) {
            half8 ea = { (_Float16)0, (_Float16)0, (_Float16)0, (_Float16)0,
                         (_Float16)0, (_Float16)0, (_Float16)0, (_Float16)0 };
            if (quad < 2) ea = *(const half8*)&smem[erd + mt * 1024];
            floatx4 acc[4];
            #pragma unroll
            for (int nt = 0; nt < 4; ++nt) {
                acc[nt] = (floatx4){ b1v[nt], b1v[nt], b1v[nt], b1v[nt] };
                acc[nt] = __builtin_amdgcn_mfma_f32_16x16x32_f16(ea, w1f[nt], acc[nt], 0, 0, 0);
            }
            #pragma unroll
            for (int r = 0; r < 4; ++r)
                *(half4*)&smem[hwb[r] + mt * 1024] =
                    relu_pk4(acc[0][r], acc[1][r], acc[2][r], acc[3][r]);
        }

        // ---- issue next tile's emb0/emb1/emb2 quad loads (hidden by L2-3) ----
        float nwx0, nwy0, nwx1, nwy1, nwx2, nwy2;
        half8 m0a, m0b, m1a, m1b, m2a, m2b;
        {
            GQ g0 = gq(512, nu, nv); nwx0 = g0.wx; nwy0 = g0.wy;
            m0a = q0t[2 * g0.c]; m0b = q0t[2 * g0.c + 1];
            GQ g1 = gq(264, nu, nv); nwx1 = g1.wx; nwy1 = g1.wy;
            m1a = q1t[2 * g1.c]; m1b = q1t[2 * g1.c + 1];
            GQ g2 = gq(16, nu, nv); nwx2 = g2.wx; nwy2 = g2.wy;
            m2a = q2t[2 * g2.c]; m2b = q2t[2 * g2.c + 1];
        }

        // ---- layer 2 (K=64): w2 frags reloaded phase-locally from LDS ----
        half8 w2r[4][2];
        #pragma unroll
        for (int nt = 0; nt < 4; ++nt)
            #pragma unroll
            for (int ks = 0; ks < 2; ++ks)
                w2r[nt][ks] = *(const half8*)&w2l[nt * 1024 + w2a[ks]];
        #pragma unroll
        for (int mt = 0; mt < 4; ++mt) {
            floatx4 acc[4];
            #pragma unroll
            for (int nt = 0; nt < 4; ++nt)
                acc[nt] = (floatx4){ b2v[nt], b2v[nt], b2v[nt], b2v[nt] };
            #pragma unroll
            for (int ks = 0; ks < 2; ++ks) {
                half8 a2 = *(const half8*)&smem[rd2[ks] + mt * 1024];
                #pragma unroll
                for (int nt = 0; nt < 4; ++nt)
                    acc[nt] = __builtin_amdgcn_mfma_f32_16x16x32_f16(a2, w2r[nt][ks], acc[nt], 0, 0, 0);
            }
            #pragma unroll
            for (int r = 0; r < 4; ++r)
                *(half4*)&smem[hwb[r] + mt * 1024] =
                    relu_pk4(acc[0][r], acc[1][r], acc[2][r], acc[3][r]);
        }

        // ---- layer 3 (transposed) ----
        #pragma unroll
        for (int mt = 0; mt < 4; ++mt) {
            floatx4 acc3 = (floatx4){ qb30, qb31, qb32, 0.0f };
            #pragma unroll
            for (int ks = 0; ks < 2; ++ks) {
                half8 bfr = *(const half8*)&smem[rd2[ks] + mt * 1024];
                acc3 = __builtin_amdgcn_mfma_f32_16x16x32_f16(w3f[ks], bfr, acc3, 0, 0, 0);
            }
            if (quad == 0) {
                const int P = (tile << 8) + (wv << 6) + mt * 16 + l15;
                out[3 * P + 0] = acc3[0];
                out[3 * P + 1] = acc3[1];
                out[3 * P + 2] = acc3[2];
            }
        }

        // ---- rotate pipeline registers ----
        cidf = nidf; cu = nu; cv = nv;
        wx0 = nwx0; wy0 = nwy0; wx1 = nwx1; wy1 = nwy1; wx2 = nwx2; wy2 = nwy2;
        t0a = m0a; t0b = m0b; t1a = m1a; t1b = m1b; t2a = m2a; t2b = m2b;
    }
}

// ---- fallback (validated round-3 kernel, float4 gathers) for tiny ws ----
__global__ __launch_bounds__(TPB, 3) void dgn_mfma_fb(
    const float*  __restrict__ x,
    const float4* __restrict__ emb0,
    const float4* __restrict__ emb1,
    const float4* __restrict__ emb2,
    const float*  __restrict__ w1, const float* __restrict__ b1,
    const float*  __restrict__ w2, const float* __restrict__ b2,
    const float*  __restrict__ w3, const float* __restrict__ b3,
    float*        __restrict__ out, int npts)
{
    __shared__ __align__(16) _Float16 smem[4 * 4096];
    __shared__ __align__(16) _Float16 w2l[4096];

    const int tid  = threadIdx.x;
    const int lane = tid & 63;
    const int wv   = tid >> 6;
    const int l15  = lane & 15;
    const int quad = lane >> 4;

    for (int e = tid; e < 4096; e += TPB) {
        int nt = e >> 10, rem = e & 1023, lw = rem >> 6, s = rem & 63;
        int oh = ((s & 3) << 4) | (s >> 2);
        w2l[nt * 1024 + lw * 64 + (s ^ ((lw & 7) << 3))] =
            (_Float16)w2[oh * 64 + nt * 16 + lw];
    }
    __syncthreads();

    half8 w1f[4];
    #pragma unroll
    for (int nt = 0; nt < 4; ++nt)
        #pragma unroll
        for (int j = 0; j < 8; ++j) {
            int k = quad * 8 + j;
            w1f[nt][j] = (k < 13) ? (_Float16)w1[k * 64 + nt * 16 + l15] : (_Float16)0.0f;
        }
    float b1v[4], b2v[4];
    #pragma unroll
    for (int nt = 0; nt < 4; ++nt) { b1v[nt] = b1[nt * 16 + l15]; b2v[nt] = b2[nt * 16 + l15]; }
    half8 w3f[2];
    #pragma unroll
    for (int ks = 0; ks < 2; ++ks)
        #pragma unroll
        for (int j = 0; j < 8; ++j) {
            int s  = ks * 32 + quad * 8 + j;
            int oh = ((s & 3) << 4) | (s >> 2);
            w3f[ks][j] = (l15 < 3) ? (_Float16)w3[oh * 3 + l15] : (_Float16)0.0f;
        }
    const float qsel = (quad == 0) ? 1.0f : 0.0f;
    const float qb30 = qsel * b3[0], qb31 = qsel * b3[1], qb32 = qsel * b3[2];

    const int bufh = wv * 4096;
    const int ewr0 = bufh + lane * 64 + ((lane & 7) ^ 0) * 8;
    const int ewr1 = bufh + lane * 64 + ((lane & 7) ^ 1) * 8;
    const int erd  = bufh + l15 * 64 + (quad ^ (l15 & 7)) * 8;
    int hwb[4];
    #pragma unroll
    for (int r = 0; r < 4; ++r) {
        int pr = quad * 4 + r;
        hwb[r] = bufh + pr * 64 + (((l15 >> 1) ^ (pr & 7)) * 8) + (l15 & 1) * 4;
    }
    int rd2[2];
    #pragma unroll
    for (int ks = 0; ks < 2; ++ks)
        rd2[ks] = bufh + l15 * 64 + (((ks * 4 + quad) ^ (l15 & 7)) * 8);
    int w2a[2];
    #pragma unroll
    for (int ks = 0; ks < 2; ++ks)
        w2a[ks] = l15 * 64 + (((ks * 4 + quad) ^ (l15 & 7)) * 8);

    const int ntiles = npts >> 8;
    const int gdim   = gridDim.x;

    float cidf, cu, cv, wx0, wy0, wx1, wy1;
    float4 t00, t01, t02, t03, t10, t11, t12, t13;
    {
        int p0 = (blockIdx.x << 8) + (wv << 6) + lane;
        cidf = x[3 * p0]; cu = x[3 * p0 + 1]; cv = x[3 * p0 + 2];
        GAddr g0 = gaddr(512, cu, cv); wx0 = g0.wx; wy0 = g0.wy;
        t00 = emb0[g0.i00]; t01 = emb0[g0.i10]; t02 = emb0[g0.i01]; t03 = emb0[g0.i11];
        GAddr g1 = gaddr(264, cu, cv); wx1 = g1.wx; wy1 = g1.wy;
        t10 = emb1[g1.i00]; t11 = emb1[g1.i10]; t12 = emb1[g1.i01]; t13 = emb1[g1.i11];
    }

    for (int tile = blockIdx.x; tile < ntiles; tile += gdim) {
        float f[12];
        bil4(t00, t01, t02, t03, wx0, wy0, f);
        bil4(t10, t11, t12, t13, wx1, wy1, f + 4);
        {
            GAddr g2 = gaddr(16, cu, cv);
            bil4(emb2[g2.i00], emb2[g2.i10], emb2[g2.i01], emb2[g2.i11], g2.wx, g2.wy, f + 8);
        }
        union H8 { half8 v; fp16x2 p[4]; } e0u, e1u;
        e0u.p[0] = __builtin_amdgcn_cvt_pkrtz(cidf, f[0]);
        e0u.p[1] = __builtin_amdgcn_cvt_pkrtz(f[1], f[2]);
        e0u.p[2] = __builtin_amdgcn_cvt_pkrtz(f[3], f[4]);
        e0u.p[3] = __builtin_amdgcn_cvt_pkrtz(f[5], f[6]);
        e1u.p[0] = __builtin_amdgcn_cvt_pkrtz(f[7], f[8]);
        e1u.p[1] = __builtin_amdgcn_cvt_pkrtz(f[9], f[10]);
        e1u.p[2] = __builtin_amdgcn_cvt_pkrtz(f[11], 0.0f);
        e1u.p[3] = __builtin_amdgcn_cvt_pkrtz(0.0f, 0.0f);
        *(half8*)&smem[ewr0] = e0u.v;
        *(half8*)&smem[ewr1] = e1u.v;

        int nxt = tile + gdim;
        int ptn = (((nxt < ntiles) ? nxt : tile) << 8) + (wv << 6) + lane;
        float nidf = x[3 * ptn], nu = x[3 * ptn + 1], nv = x[3 * ptn + 2];

        #pragma unroll
        for (int mt = 0; mt < 4; ++mt) {
            half8 ea = { (_Float16)0, (_Float16)0, (_Float16)0, (_Float16)0,
                         (_Float16)0, (_Float16)0, (_Float16)0, (_Float16)0 };
            if (quad < 2) ea = *(const half8*)&smem[erd + mt * 1024];
            floatx4 acc[4];
            #pragma unroll
            for (int nt = 0; nt < 4; ++nt) {
                acc[nt] = (floatx4){ b1v[nt], b1v[nt], b1v[nt], b1v[nt] };
                acc[nt] = __builtin_amdgcn_mfma_f32_16x16x32_f16(ea, w1f[nt], acc[nt], 0, 0, 0);
            }
            #pragma unroll
            for (int r = 0; r < 4; ++r)
                *(half4*)&smem[hwb[r] + mt * 1024] =
                    relu_pk4(acc[0][r], acc[1][r], acc[2][r], acc[3][r]);
        }

        float nwx0, nwy0, nwx1, nwy1;
        float4 n00, n01, n02, n03, n10, n11, n12, n13;
        {
            GAddr g0 = gaddr(512, nu, nv); nwx0 = g0.wx; nwy0 = g0.wy;
            n00 = emb0[g0.i00]; n01 = emb0[g0.i10]; n02 = emb0[g0.i01]; n03 = emb0[g0.i11];
            GAddr g1 = gaddr(264, nu, nv); nwx1 = g1.wx; nwy1 = g1.wy;
            n10 = emb1[g1.i00]; n11 = emb1[g1.i10]; n12 = emb1[g1.i01]; n13 = emb1[g1.i11];
        }

        half8 w2r[4][2];
        #pragma unroll
        for (int nt = 0; nt < 4; ++nt)
            #pragma unroll
            for (int ks = 0; ks < 2; ++ks)
                w2r[nt][ks] = *(const half8*)&w2l[nt * 1024 + w2a[ks]];
        #pragma unroll
        for (int mt = 0; mt < 4; ++mt) {
            floatx4 acc[4];
            #pragma unroll
            for (int nt = 0; nt < 4; ++nt)
                acc[nt] = (floatx4){ b2v[nt], b2v[nt], b2v[nt], b2v[nt] };
            #pragma unroll
            for (int ks = 0; ks < 2; ++ks) {
                half8 a2 = *(const half8*)&smem[rd2[ks] + mt * 1024];
                #pragma unroll
                for (int nt = 0; nt < 4; ++nt)
                    acc[nt] = __builtin_amdgcn_mfma_f32_16x16x32_f16(a2, w2r[nt][ks], acc[nt], 0, 0, 0);
            }
            #pragma unroll
            for (int r = 0; r < 4; ++r)
                *(half4*)&smem[hwb[r] + mt * 1024] =
                    relu_pk4(acc[0][r], acc[1][r], acc[2][r], acc[3][r]);
        }

        #pragma unroll
        for (int mt = 0; mt < 4; ++mt) {
            floatx4 acc3 = (floatx4){ qb30, qb31, qb32, 0.0f };
            #pragma unroll
            for (int ks = 0; ks < 2; ++ks) {
                half8 bfr = *(const half8*)&smem[rd2[ks] + mt * 1024];
                acc3 = __builtin_amdgcn_mfma_f32_16x16x32_f16(w3f[ks], bfr, acc3, 0, 0, 0);
            }
            if (quad == 0) {
                const int P = (tile << 8) + (wv << 6) + mt * 16 + l15;
                out[3 * P + 0] = acc3[0];
                out[3 * P + 1] = acc3[1];
                out[3 * P + 2] = acc3[2];
            }
        }

        cidf = nidf; cu = nu; cv = nv;
        wx0 = nwx0; wy0 = nwy0; wx1 = nwx1; wy1 = nwy1;
        t00 = n00; t01 = n01; t02 = n02; t03 = n03;
        t10 = n10; t11 = n11; t12 = n12; t13 = n13;
    }
}

extern "C" void kernel_launch(void* const* d_in, const int* in_sizes, int n_in,
                              void* d_out, int out_size, void* d_ws, size_t ws_size,
                              hipStream_t stream) {
    const float*  x    = (const float*)  d_in[0];
    const float4* emb0 = (const float4*) d_in[1];
    const float4* emb1 = (const float4*) d_in[2];
    const float4* emb2 = (const float4*) d_in[3];
    const float*  w1   = (const float*)  d_in[4];
    const float*  b1   = (const float*)  d_in[5];
    const float*  w2   = (const float*)  d_in[6];
    const float*  b2   = (const float*)  d_in[7];
    const float*  w3   = (const float*)  d_in[8];
    const float*  b3   = (const float*)  d_in[9];
    float* out = (float*)d_out;

    int npts = in_sizes[0] / 3;
    const size_t need = (size_t)(NC0 + NC1 + NC2) * 32;   // 10.6 MB quad tables

    if (d_ws != nullptr && ws_size >= need) {
        int cells = NC0 + NC1 + NC2;
        pack_tables<<<(cells + 255) / 256, 256, 0, stream>>>(emb0, emb1, emb2, (half8*)d_ws);
        dgn_mfma<<<1024, TPB, 0, stream>>>(x, (const half8*)d_ws,
                                           w1, b1, w2, b2, w3, b3, out, npts);
    } else {
        dgn_mfma_fb<<<768, TPB, 0, stream>>>(x, emb0, emb1, emb2,
                                             w1, b1, w2, b2, w3, b3, out, npts);
    }
}

// Round 6
// 274.668 us; speedup vs baseline: 1.0864x; 1.0864x over previous
//
#include <hip/hip_runtime.h>

typedef _Float16 half8 __attribute__((ext_vector_type(8)));
typedef _Float16 half4 __attribute__((ext_vector_type(4)));
typedef _Float16 h2    __attribute__((ext_vector_type(2)));
typedef __fp16  fp16x2 __attribute__((ext_vector_type(2)));
typedef float floatx4 __attribute__((ext_vector_type(4)));

#define TPB 256

// quad-table geometry (cells = res*res, row stride res, matching reference's
// tab[y*res+x] indexing; clamp x1=min(x0+1,res) never binds for u,v in [0,1))
#define NC0 (512 * 512)
#define NC1 (264 * 264)
#define NC2 (16 * 16)

struct GAddr { int i00, i10, i01, i11; float wx, wy; };

__device__ __forceinline__ GAddr gaddr(int res, float u, float v) {
    float r = (float)res;
    float sx = u * r, sy = v * r;
    int x0 = (int)sx, y0 = (int)sy;            // truncation, matches astype(int32)
    float wx = sx - (float)x0, wy = sy - (float)y0;
    int x1 = min(x0 + 1, res), y1 = min(y0 + 1, res);
    GAddr g;
    g.i00 = y0 * res + x0;  g.i10 = y0 * res + x1;   // reference stride = res
    g.i01 = y1 * res + x0;  g.i11 = y1 * res + x1;
    g.wx = wx; g.wy = wy;
    return g;
}

struct GQ { int c; float wx, wy; };

__device__ __forceinline__ GQ gq(int res, float u, float v) {
    float r = (float)res;
    float sx = u * r, sy = v * r;
    int x0 = (int)sx, y0 = (int)sy;
    GQ g; g.c = y0 * res + x0; g.wx = sx - (float)x0; g.wy = sy - (float)y0;
    return g;
}

__device__ __forceinline__ void bil4(float4 v00, float4 v10, float4 v01, float4 v11,
                                     float wx, float wy, float* f) {
    float omx = 1.0f - wx, omy = 1.0f - wy;
    f[0] = (v00.x * omx + v10.x * wx) * omy + (v01.x * omx + v11.x * wx) * wy;
    f[1] = (v00.y * omx + v10.y * wx) * omy + (v01.y * omx + v11.y * wx) * wy;
    f[2] = (v00.z * omx + v10.z * wx) * omy + (v01.z * omx + v11.z * wx) * wy;
    f[3] = (v00.w * omx + v10.w * wx) * omy + (v01.w * omx + v11.w * wx) * wy;
}

__device__ __forceinline__ h2 pk2(float a, float b) {
    fp16x2 r = __builtin_amdgcn_cvt_pkrtz(a, b);
    union { fp16x2 f; h2 h; } u; u.f = r; return u.h;
}

// packed-fp16 bilinear on a 32B quad {v00[4],v10[4]} {v01[4],v11[4]}.
// 12 v_pk ops + 4 pkrtz; outputs f[0]=(feat0,feat1), f[1]=(feat2,feat3).
__device__ __forceinline__ void bilq(half8 q0, half8 q1, float wx, float wy, h2* f) {
    h2 wx2  = pk2(wx, wx),           wy2  = pk2(wy, wy);
    h2 omx2 = pk2(1.f - wx, 1.f - wx), omy2 = pk2(1.f - wy, 1.f - wy);
    union { half8 v; h2 p[4]; } a, b;
    a.v = q0; b.v = q1;
    h2 t0 = a.p[0] * omx2 + a.p[2] * wx2;
    h2 t1 = a.p[1] * omx2 + a.p[3] * wx2;
    h2 c0 = b.p[0] * omx2 + b.p[2] * wx2;
    h2 c1 = b.p[1] * omx2 + b.p[3] * wx2;
    f[0] = t0 * omy2 + c0 * wy2;
    f[1] = t1 * omy2 + c1 * wy2;
}

// relu (f32) then packed f32->f16 convert: 4 v_max + 2 v_cvt_pkrtz.
__device__ __forceinline__ half4 relu_pk4(float a, float b, float c, float d) {
    union { half4 v; fp16x2 p[2]; } u;
    u.p[0] = __builtin_amdgcn_cvt_pkrtz(fmaxf(a, 0.0f), fmaxf(b, 0.0f));
    u.p[1] = __builtin_amdgcn_cvt_pkrtz(fmaxf(c, 0.0f), fmaxf(d, 0.0f));
    return u.v;
}

// ---- per-launch table pack: float4 corner tables -> fp16 quad tables in ws.
// cell (y,x) of table t -> 32B = {v00,v10}{v01,v11} fp16. 32B-aligned so a
// quad never straddles a 64B line: gathers go 4 divergent loads -> 1 address.
__global__ void pack_tables(const float4* __restrict__ e0,
                            const float4* __restrict__ e1,
                            const float4* __restrict__ e2,
                            half8* __restrict__ q)
{
    int c = blockIdx.x * blockDim.x + threadIdx.x;
    const float4* src; int res, qb;
    if (c < NC0)                    { src = e0; res = 512; qb = 0; }
    else if (c < NC0 + NC1)         { src = e1; res = 264; qb = 2 * NC0; c -= NC0; }
    else if (c < NC0 + NC1 + NC2)   { src = e2; res = 16;  qb = 2 * (NC0 + NC1); c -= NC0 + NC1; }
    else return;
    float4 A = src[c], B = src[c + 1], C = src[c + res], D = src[c + res + 1];
    union { half8 v; fp16x2 p[4]; } u0, u1;
    u0.p[0] = __builtin_amdgcn_cvt_pkrtz(A.x, A.y);
    u0.p[1] = __builtin_amdgcn_cvt_pkrtz(A.z, A.w);
    u0.p[2] = __builtin_amdgcn_cvt_pkrtz(B.x, B.y);
    u0.p[3] = __builtin_amdgcn_cvt_pkrtz(B.z, B.w);
    u1.p[0] = __builtin_amdgcn_cvt_pkrtz(C.x, C.y);
    u1.p[1] = __builtin_amdgcn_cvt_pkrtz(C.z, C.w);
    u1.p[2] = __builtin_amdgcn_cvt_pkrtz(D.x, D.y);
    u1.p[3] = __builtin_amdgcn_cvt_pkrtz(D.z, D.w);
    q[qb + 2 * c]     = u0.v;
    q[qb + 2 * c + 1] = u1.v;
}

// Round-5 findings: (256,4) spilled (arch VGPR squeezed to 64, FETCH +274MB,
// 130->200us) — 4 waves/SIMD via launch bounds is closed (128-reg total
// budget < ~140 live set; LDS also exactly full at 4 blocks). But 42%
// occupancy pushed 3.35 TB/s -> round-4's 2.8 TB/s was NOT a BW wall;
// still latency-bound. This round keeps the validated (256,3) shape and
// adds pipeline DEPTH instead of occupancy:
//   - x pipeline 2 tiles deep: x[t+1] is already in registers at tile start,
//     so its ~600cyc load latency never sits in front of gather issue.
//   - all 6 table-quad gathers for t+1 issue at the TOP of the loop, giving
//     them the whole tile body (~2-3K cyc) to complete vs L3-miss ~600-900.
__global__ __launch_bounds__(TPB, 3) void dgn_mfma(
    const float*  __restrict__ x,
    const half8*  __restrict__ qt,
    const float*  __restrict__ w1, const float* __restrict__ b1,
    const float*  __restrict__ w2, const float* __restrict__ b2,
    const float*  __restrict__ w3, const float* __restrict__ b3,
    float*        __restrict__ out, int npts)
{
    __shared__ __align__(16) _Float16 smem[4 * 4096];   // 4 waves * 8KB, wave-private
    __shared__ __align__(16) _Float16 w2l[4096];        // 8KB shared w2 fragments

    const half8* q0t = qt;
    const half8* q1t = qt + 2 * NC0;
    const half8* q2t = qt + 2 * (NC0 + NC1);

    const int tid  = threadIdx.x;
    const int lane = tid & 63;
    const int wv   = tid >> 6;
    const int l15  = lane & 15;
    const int quad = lane >> 4;

    // ---- one-time w2 fragment staging into LDS (swizzled like rd2) ----
    for (int e = tid; e < 4096; e += TPB) {
        int nt = e >> 10, rem = e & 1023, lw = rem >> 6, s = rem & 63;
        int oh = ((s & 3) << 4) | (s >> 2);             // sigma^{-1}
        w2l[nt * 1024 + lw * 64 + (s ^ ((lw & 7) << 3))] =
            (_Float16)w2[oh * 64 + nt * 16 + lw];
    }
    __syncthreads();

    // ---- persistent weight fragments. w1 K-permutation: slot k<12 -> row k+1
    // (features), slot 12 -> row 0 (idf), slots 13-15 -> zero. ----
    half8 w1f[4];
    #pragma unroll
    for (int nt = 0; nt < 4; ++nt)
        #pragma unroll
        for (int j = 0; j < 8; ++j) {
            int k = quad * 8 + j;
            int row = (k < 12) ? (k + 1) : ((k == 12) ? 0 : -1);
            w1f[nt][j] = (row >= 0) ? (_Float16)w1[row * 64 + nt * 16 + l15] : (_Float16)0.0f;
        }
    float b1v[4], b2v[4];
    #pragma unroll
    for (int nt = 0; nt < 4; ++nt) { b1v[nt] = b1[nt * 16 + l15]; b2v[nt] = b2[nt * 16 + l15]; }
    half8 w3f[2];
    #pragma unroll
    for (int ks = 0; ks < 2; ++ks)
        #pragma unroll
        for (int j = 0; j < 8; ++j) {
            int s  = ks * 32 + quad * 8 + j;
            int oh = ((s & 3) << 4) | (s >> 2);
            w3f[ks][j] = (l15 < 3) ? (_Float16)w3[oh * 3 + l15] : (_Float16)0.0f;
        }
    const float qsel = (quad == 0) ? 1.0f : 0.0f;
    const float qb30 = qsel * b3[0], qb31 = qsel * b3[1], qb32 = qsel * b3[2];

    // ---- precomputed LDS addresses (half-element units) ----
    const int bufh = wv * 4096;
    const int ewr0 = bufh + lane * 64 + ((lane & 7) ^ 0) * 8;
    const int ewr1 = bufh + lane * 64 + ((lane & 7) ^ 1) * 8;
    const int erd  = bufh + l15 * 64 + (quad ^ (l15 & 7)) * 8;          // quad<2 only
    int hwb[4];
    #pragma unroll
    for (int r = 0; r < 4; ++r) {
        int pr = quad * 4 + r;
        hwb[r] = bufh + pr * 64 + (((l15 >> 1) ^ (pr & 7)) * 8) + (l15 & 1) * 4;
    }
    int rd2[2];
    #pragma unroll
    for (int ks = 0; ks < 2; ++ks)
        rd2[ks] = bufh + l15 * 64 + (((ks * 4 + quad) ^ (l15 & 7)) * 8);
    int w2a[2];
    #pragma unroll
    for (int ks = 0; ks < 2; ++ks)
        w2a[ks] = l15 * 64 + (((ks * 4 + quad) ^ (l15 & 7)) * 8);

    const int ntiles = npts >> 8;
    const int gdim   = gridDim.x;

    // ---- prologue: x[t0], x[t0+g] loaded; tile-0 gathers in flight ----
    float cidf, cu, cv;            // x of current tile
    float nidf, nu, nv;            // x of next tile (2-deep pipeline)
    float wx0, wy0, wx1, wy1, wx2, wy2;
    half8 t0a, t0b, t1a, t1b, t2a, t2b;
    {
        int p0 = (blockIdx.x << 8) + (wv << 6) + lane;
        cidf = x[3 * p0]; cu = x[3 * p0 + 1]; cv = x[3 * p0 + 2];
        int tn = blockIdx.x + gdim;
        int p1 = (((tn < ntiles) ? tn : blockIdx.x) << 8) + (wv << 6) + lane;
        nidf = x[3 * p1]; nu = x[3 * p1 + 1]; nv = x[3 * p1 + 2];
        GQ g0 = gq(512, cu, cv); wx0 = g0.wx; wy0 = g0.wy;
        t0a = q0t[2 * g0.c]; t0b = q0t[2 * g0.c + 1];
        GQ g1 = gq(264, cu, cv); wx1 = g1.wx; wy1 = g1.wy;
        t1a = q1t[2 * g1.c]; t1b = q1t[2 * g1.c + 1];
        GQ g2 = gq(16, cu, cv); wx2 = g2.wx; wy2 = g2.wy;
        t2a = q2t[2 * g2.c]; t2b = q2t[2 * g2.c + 1];
    }

    for (int tile = blockIdx.x; tile < ntiles; tile += gdim) {
        // ---- 1. issue next tile's gathers FIRST (x[t+1] already in regs);
        //         in flight across the entire tile body ----
        float nwx0, nwy0, nwx1, nwy1, nwx2, nwy2;
        half8 m0a, m0b, m1a, m1b, m2a, m2b;
        {
            GQ g0 = gq(512, nu, nv); nwx0 = g0.wx; nwy0 = g0.wy;
            m0a = q0t[2 * g0.c]; m0b = q0t[2 * g0.c + 1];
            GQ g1 = gq(264, nu, nv); nwx1 = g1.wx; nwy1 = g1.wy;
            m1a = q1t[2 * g1.c]; m1b = q1t[2 * g1.c + 1];
            GQ g2 = gq(16, nu, nv); nwx2 = g2.wx; nwy2 = g2.wy;
            m2a = q2t[2 * g2.c]; m2b = q2t[2 * g2.c + 1];
        }

        // ---- 2. issue x load for tile+2 (consumed next iteration) ----
        int nxt2 = tile + 2 * gdim;
        int ptn = (((nxt2 < ntiles) ? nxt2 : tile) << 8) + (wv << 6) + lane;
        float fidf = x[3 * ptn], fu = x[3 * ptn + 1], fv = x[3 * ptn + 2];

        // ---- 3. finish current tile's features (packed-fp16 lerp) ----
        h2 F0[2], F1[2], F2[2];
        bilq(t0a, t0b, wx0, wy0, F0);
        bilq(t1a, t1b, wx1, wy1, F1);
        bilq(t2a, t2b, wx2, wy2, F2);
        // E pack: slots 0-11 = features, slot 12 = idf, 13-15 = 0
        union H8 { half8 v; h2 p[4]; } e0u, e1u;
        e0u.p[0] = F0[0]; e0u.p[1] = F0[1]; e0u.p[2] = F1[0]; e0u.p[3] = F1[1];
        e1u.p[0] = F2[0]; e1u.p[1] = F2[1];
        e1u.p[2] = pk2(cidf, 0.0f); e1u.p[3] = pk2(0.0f, 0.0f);
        *(half8*)&smem[ewr0] = e0u.v;
        *(half8*)&smem[ewr1] = e1u.v;

        // ---- layer 1: K=32 (quads 2-3 feed zeros), bias in C-init ----
        #pragma unroll
        for (int mt = 0; mt < 4; ++mt) {
            half8 ea = { (_Float16)0, (_Float16)0, (_Float16)0, (_Float16)0,
                         (_Float16)0, (_Float16)0, (_Float16)0, (_Float16)0 };
            if (quad < 2) ea = *(const half8*)&smem[erd + mt * 1024];
            floatx4 acc[4];
            #pragma unroll
            for (int nt = 0; nt < 4; ++nt) {
                acc[nt] = (floatx4){ b1v[nt], b1v[nt], b1v[nt], b1v[nt] };
                acc[nt] = __builtin_amdgcn_mfma_f32_16x16x32_f16(ea, w1f[nt], acc[nt], 0, 0, 0);
            }
            #pragma unroll
            for (int r = 0; r < 4; ++r)
                *(half4*)&smem[hwb[r] + mt * 1024] =
                    relu_pk4(acc[0][r], acc[1][r], acc[2][r], acc[3][r]);
        }

        // ---- layer 2 (K=64): w2 frags reloaded phase-locally from LDS ----
        half8 w2r[4][2];
        #pragma unroll
        for (int nt = 0; nt < 4; ++nt)
            #pragma unroll
            for (int ks = 0; ks < 2; ++ks)
                w2r[nt][ks] = *(const half8*)&w2l[nt * 1024 + w2a[ks]];
        #pragma unroll
        for (int mt = 0; mt < 4; ++mt) {
            floatx4 acc[4];
            #pragma unroll
            for (int nt = 0; nt < 4; ++nt)
                acc[nt] = (floatx4){ b2v[nt], b2v[nt], b2v[nt], b2v[nt] };
            #pragma unroll
            for (int ks = 0; ks < 2; ++ks) {
                half8 a2 = *(const half8*)&smem[rd2[ks] + mt * 1024];
                #pragma unroll
                for (int nt = 0; nt < 4; ++nt)
                    acc[nt] = __builtin_amdgcn_mfma_f32_16x16x32_f16(a2, w2r[nt][ks], acc[nt], 0, 0, 0);
            }
            #pragma unroll
            for (int r = 0; r < 4; ++r)
                *(half4*)&smem[hwb[r] + mt * 1024] =
                    relu_pk4(acc[0][r], acc[1][r], acc[2][r], acc[3][r]);
        }

        // ---- layer 3 (transposed) ----
        #pragma unroll
        for (int mt = 0; mt < 4; ++mt) {
            floatx4 acc3 = (floatx4){ qb30, qb31, qb32, 0.0f };
            #pragma unroll
            for (int ks = 0; ks < 2; ++ks) {
                half8 bfr = *(const half8*)&smem[rd2[ks] + mt * 1024];
                acc3 = __builtin_amdgcn_mfma_f32_16x16x32_f16(w3f[ks], bfr, acc3, 0, 0, 0);
            }
            if (quad == 0) {
                const int P = (tile << 8) + (wv << 6) + mt * 16 + l15;
                out[3 * P + 0] = acc3[0];
                out[3 * P + 1] = acc3[1];
                out[3 * P + 2] = acc3[2];
            }
        }

        // ---- rotate pipeline registers ----
        cidf = nidf; cu = nu; cv = nv;
        nidf = fidf; nu = fu; nv = fv;
        wx0 = nwx0; wy0 = nwy0; wx1 = nwx1; wy1 = nwy1; wx2 = nwx2; wy2 = nwy2;
        t0a = m0a; t0b = m0b; t1a = m1a; t1b = m1b; t2a = m2a; t2b = m2b;
    }
}

// ---- fallback (validated round-3 kernel, float4 gathers) for tiny ws ----
__global__ __launch_bounds__(TPB, 3) void dgn_mfma_fb(
    const float*  __restrict__ x,
    const float4* __restrict__ emb0,
    const float4* __restrict__ emb1,
    const float4* __restrict__ emb2,
    const float*  __restrict__ w1, const float* __restrict__ b1,
    const float*  __restrict__ w2, const float* __restrict__ b2,
    const float*  __restrict__ w3, const float* __restrict__ b3,
    float*        __restrict__ out, int npts)
{
    __shared__ __align__(16) _Float16 smem[4 * 4096];
    __shared__ __align__(16) _Float16 w2l[4096];

    const int tid  = threadIdx.x;
    const int lane = tid & 63;
    const int wv   = tid >> 6;
    const int l15  = lane & 15;
    const int quad = lane >> 4;

    for (int e = tid; e < 4096; e += TPB) {
        int nt = e >> 10, rem = e & 1023, lw = rem >> 6, s = rem & 63;
        int oh = ((s & 3) << 4) | (s >> 2);
        w2l[nt * 1024 + lw * 64 + (s ^ ((lw & 7) << 3))] =
            (_Float16)w2[oh * 64 + nt * 16 + lw];
    }
    __syncthreads();

    half8 w1f[4];
    #pragma unroll
    for (int nt = 0; nt < 4; ++nt)
        #pragma unroll
        for (int j = 0; j < 8; ++j) {
            int k = quad * 8 + j;
            w1f[nt][j] = (k < 13) ? (_Float16)w1[k * 64 + nt * 16 + l15] : (_Float16)0.0f;
        }
    float b1v[4], b2v[4];
    #pragma unroll
    for (int nt = 0; nt < 4; ++nt) { b1v[nt] = b1[nt * 16 + l15]; b2v[nt] = b2[nt * 16 + l15]; }
    half8 w3f[2];
    #pragma unroll
    for (int ks = 0; ks < 2; ++ks)
        #pragma unroll
        for (int j = 0; j < 8; ++j) {
            int s  = ks * 32 + quad * 8 + j;
            int oh = ((s & 3) << 4) | (s >> 2);
            w3f[ks][j] = (l15 < 3) ? (_Float16)w3[oh * 3 + l15] : (_Float16)0.0f;
        }
    const float qsel = (quad == 0) ? 1.0f : 0.0f;
    const float qb30 = qsel * b3[0], qb31 = qsel * b3[1], qb32 = qsel * b3[2];

    const int bufh = wv * 4096;
    const int ewr0 = bufh + lane * 64 + ((lane & 7) ^ 0) * 8;
    const int ewr1 = bufh + lane * 64 + ((lane & 7) ^ 1) * 8;
    const int erd  = bufh + l15 * 64 + (quad ^ (l15 & 7)) * 8;
    int hwb[4];
    #pragma unroll
    for (int r = 0; r < 4; ++r) {
        int pr = quad * 4 + r;
        hwb[r] = bufh + pr * 64 + (((l15 >> 1) ^ (pr & 7)) * 8) + (l15 & 1) * 4;
    }
    int rd2[2];
    #pragma unroll
    for (int ks = 0; ks < 2; ++ks)
        rd2[ks] = bufh + l15 * 64 + (((ks * 4 + quad) ^ (l15 & 7)) * 8);
    int w2a[2];
    #pragma unroll
    for (int ks = 0; ks < 2; ++ks)
        w2a[ks] = l15 * 64 + (((ks * 4 + quad) ^ (l15 & 7)) * 8);

    const int ntiles = npts >> 8;
    const int gdim   = gridDim.x;

    float cidf, cu, cv, wx0, wy0, wx1, wy1;
    float4 t00, t01, t02, t03, t10, t11, t12, t13;
    {
        int p0 = (blockIdx.x << 8) + (wv << 6) + lane;
        cidf = x[3 * p0]; cu = x[3 * p0 + 1]; cv = x[3 * p0 + 2];
        GAddr g0 = gaddr(512, cu, cv); wx0 = g0.wx; wy0 = g0.wy;
        t00 = emb0[g0.i00]; t01 = emb0[g0.i10]; t02 = emb0[g0.i01]; t03 = emb0[g0.i11];
        GAddr g1 = gaddr(264, cu, cv); wx1 = g1.wx; wy1 = g1.wy;
        t10 = emb1[g1.i00]; t11 = emb1[g1.i10]; t12 = emb1[g1.i01]; t13 = emb1[g1.i11];
    }

    for (int tile = blockIdx.x; tile < ntiles; tile += gdim) {
        float f[12];
        bil4(t00, t01, t02, t03, wx0, wy0, f);
        bil4(t10, t11, t12, t13, wx1, wy1, f + 4);
        {
            GAddr g2 = gaddr(16, cu, cv);
            bil4(emb2[g2.i00], emb2[g2.i10], emb2[g2.i01], emb2[g2.i11], g2.wx, g2.wy, f + 8);
        }
        union H8 { half8 v; fp16x2 p[4]; } e0u, e1u;
        e0u.p[0] = __builtin_amdgcn_cvt_pkrtz(cidf, f[0]);
        e0u.p[1] = __builtin_amdgcn_cvt_pkrtz(f[1], f[2]);
        e0u.p[2] = __builtin_amdgcn_cvt_pkrtz(f[3], f[4]);
        e0u.p[3] = __builtin_amdgcn_cvt_pkrtz(f[5], f[6]);
        e1u.p[0] = __builtin_amdgcn_cvt_pkrtz(f[7], f[8]);
        e1u.p[1] = __builtin_amdgcn_cvt_pkrtz(f[9], f[10]);
        e1u.p[2] = __builtin_amdgcn_cvt_pkrtz(f[11], 0.0f);
        e1u.p[3] = __builtin_amdgcn_cvt_pkrtz(0.0f, 0.0f);
        *(half8*)&smem[ewr0] = e0u.v;
        *(half8*)&smem[ewr1] = e1u.v;

        int nxt = tile + gdim;
        int ptn = (((nxt < ntiles) ? nxt : tile) << 8) + (wv << 6) + lane;
        float nidf = x[3 * ptn], nu = x[3 * ptn + 1], nv = x[3 * ptn + 2];

        #pragma unroll
        for (int mt = 0; mt < 4; ++mt) {
            half8 ea = { (_Float16)0, (_Float16)0, (_Float16)0, (_Float16)0,
                         (_Float16)0, (_Float16)0, (_Float16)0, (_Float16)0 };
            if (quad < 2) ea = *(const half8*)&smem[erd + mt * 1024];
            floatx4 acc[4];
            #pragma unroll
            for (int nt = 0; nt < 4; ++nt) {
                acc[nt] = (floatx4){ b1v[nt], b1v[nt], b1v[nt], b1v[nt] };
                acc[nt] = __builtin_amdgcn_mfma_f32_16x16x32_f16(ea, w1f[nt], acc[nt], 0, 0, 0);
            }
            #pragma unroll
            for (int r = 0; r < 4; ++r)
                *(half4*)&smem[hwb[r] + mt * 1024] =
                    relu_pk4(acc[0][r], acc[1][r], acc[2][r], acc[3][r]);
        }

        float nwx0, nwy0, nwx1, nwy1;
        float4 n00, n01, n02, n03, n10, n11, n12, n13;
        {
            GAddr g0 = gaddr(512, nu, nv); nwx0 = g0.wx; nwy0 = g0.wy;
            n00 = emb0[g0.i00]; n01 = emb0[g0.i10]; n02 = emb0[g0.i01]; n03 = emb0[g0.i11];
            GAddr g1 = gaddr(264, nu, nv); nwx1 = g1.wx; nwy1 = g1.wy;
            n10 = emb1[g1.i00]; n11 = emb1[g1.i10]; n12 = emb1[g1.i01]; n13 = emb1[g1.i11];
        }

        half8 w2r[4][2];
        #pragma unroll
        for (int nt = 0; nt < 4; ++nt)
            #pragma unroll
            for (int ks = 0; ks < 2; ++ks)
                w2r[nt][ks] = *(const half8*)&w2l[nt * 1024 + w2a[ks]];
        #pragma unroll
        for (int mt = 0; mt < 4; ++mt) {
            floatx4 acc[4];
            #pragma unroll
            for (int nt = 0; nt < 4; ++nt)
                acc[nt] = (floatx4){ b2v[nt], b2v[nt], b2v[nt], b2v[nt] };
            #pragma unroll
            for (int ks = 0; ks < 2; ++ks) {
                half8 a2 = *(const half8*)&smem[rd2[ks] + mt * 1024];
                #pragma unroll
                for (int nt = 0; nt < 4; ++nt)
                    acc[nt] = __builtin_amdgcn_mfma_f32_16x16x32_f16(a2, w2r[nt][ks], acc[nt], 0, 0, 0);
            }
            #pragma unroll
            for (int r = 0; r < 4; ++r)
                *(half4*)&smem[hwb[r] + mt * 1024] =
                    relu_pk4(acc[0][r], acc[1][r], acc[2][r], acc[3][r]);
        }

        #pragma unroll
        for (int mt = 0; mt < 4; ++mt) {
            floatx4 acc3 = (floatx4){ qb30, qb31, qb32, 0.0f };
            #pragma unroll
            for (int ks = 0; ks < 2; ++ks) {
                half8 bfr = *(const half8*)&smem[rd2[ks] + mt * 1024];
                acc3 = __builtin_amdgcn_mfma_f32_16x16x32_f16(w3f[ks], bfr, acc3, 0, 0, 0);
            }
            if (quad == 0) {
                const int P = (tile << 8) + (wv << 6) + mt * 16 + l15;
                out[3 * P + 0] = acc3[0];
                out[3 * P + 1] = acc3[1];
                out[3 * P + 2] = acc3[2];
            }
        }

        cidf = nidf; cu = nu; cv = nv;
        wx0 = nwx0; wy0 = nwy0; wx1 = nwx1; wy1 = nwy1;
        t00 = n00; t01 = n01; t02 = n02; t03 = n03;
        t10 = n10; t11 = n11; t12 = n12; t13 = n13;
    }
}

extern "C" void kernel_launch(void* const* d_in, const int* in_sizes, int n_in,
                              void* d_out, int out_size, void* d_ws, size_t ws_size,
                              hipStream_t stream) {
    const float*  x    = (const float*)  d_in[0];
    const float4* emb0 = (const float4*) d_in[1];
    const float4* emb1 = (const float4*) d_in[2];
    const float4* emb2 = (const float4*) d_in[3];
    const float*  w1   = (const float*)  d_in[4];
    const float*  b1   = (const float*)  d_in[5];
    const float*  w2   = (const float*)  d_in[6];
    const float*  b2   = (const float*)  d_in[7];
    const float*  w3   = (const float*)  d_in[8];
    const float*  b3   = (const float*)  d_in[9];
    float* out = (float*)d_out;

    int npts = in_sizes[0] / 3;
    const size_t need = (size_t)(NC0 + NC1 + NC2) * 32;   // 10.6 MB quad tables

    if (d_ws != nullptr && ws_size >= need) {
        int cells = NC0 + NC1 + NC2;
        pack_tables<<<(cells + 255) / 256, 256, 0, stream>>>(emb0, emb1, emb2, (half8*)d_ws);
        dgn_mfma<<<768, TPB, 0, stream>>>(x, (const half8*)d_ws,
                                          w1, b1, w2, b2, w3, b3, out, npts);
    } else {
        dgn_mfma_fb<<<768, TPB, 0, stream>>>(x, emb0, emb1, emb2,
                                             w1, b1, w2, b2, w3, b3, out, npts);
    }
}

// Round 7
// 220.064 us; speedup vs baseline: 1.3560x; 1.2481x over previous
//
#include <hip/hip_runtime.h>

typedef _Float16 half8 __attribute__((ext_vector_type(8)));
typedef _Float16 half4 __attribute__((ext_vector_type(4)));
typedef _Float16 h2    __attribute__((ext_vector_type(2)));
typedef __fp16  fp16x2 __attribute__((ext_vector_type(2)));
typedef float floatx4 __attribute__((ext_vector_type(4)));

#define TPB 256

// quad-table geometry (cells = res*res, row stride res, matching reference's
// tab[y*res+x] indexing; clamp x1=min(x0+1,res) never binds for u,v in [0,1))
#define NC0 (512 * 512)
#define NC1 (264 * 264)
#define NC2 (16 * 16)

struct GAddr { int i00, i10, i01, i11; float wx, wy; };

__device__ __forceinline__ GAddr gaddr(int res, float u, float v) {
    float r = (float)res;
    float sx = u * r, sy = v * r;
    int x0 = (int)sx, y0 = (int)sy;            // truncation, matches astype(int32)
    float wx = sx - (float)x0, wy = sy - (float)y0;
    int x1 = min(x0 + 1, res), y1 = min(y0 + 1, res);
    GAddr g;
    g.i00 = y0 * res + x0;  g.i10 = y0 * res + x1;   // reference stride = res
    g.i01 = y1 * res + x0;  g.i11 = y1 * res + x1;
    g.wx = wx; g.wy = wy;
    return g;
}

struct GQ { int c; float wx, wy; };

__device__ __forceinline__ GQ gq(int res, float u, float v) {
    float r = (float)res;
    float sx = u * r, sy = v * r;
    int x0 = (int)sx, y0 = (int)sy;
    GQ g; g.c = y0 * res + x0; g.wx = sx - (float)x0; g.wy = sy - (float)y0;
    return g;
}

__device__ __forceinline__ void bil4(float4 v00, float4 v10, float4 v01, float4 v11,
                                     float wx, float wy, float* f) {
    float omx = 1.0f - wx, omy = 1.0f - wy;
    f[0] = (v00.x * omx + v10.x * wx) * omy + (v01.x * omx + v11.x * wx) * wy;
    f[1] = (v00.y * omx + v10.y * wx) * omy + (v01.y * omx + v11.y * wx) * wy;
    f[2] = (v00.z * omx + v10.z * wx) * omy + (v01.z * omx + v11.z * wx) * wy;
    f[3] = (v00.w * omx + v10.w * wx) * omy + (v01.w * omx + v11.w * wx) * wy;
}

__device__ __forceinline__ h2 pk2(float a, float b) {
    fp16x2 r = __builtin_amdgcn_cvt_pkrtz(a, b);
    union { fp16x2 f; h2 h; } u; u.f = r; return u.h;
}

// packed-fp16 bilinear on a 32B quad {v00[4],v10[4]} {v01[4],v11[4]}.
// 12 v_pk ops + 4 pkrtz; outputs f[0]=(feat0,feat1), f[1]=(feat2,feat3).
__device__ __forceinline__ void bilq(half8 q0, half8 q1, float wx, float wy, h2* f) {
    h2 wx2  = pk2(wx, wx),           wy2  = pk2(wy, wy);
    h2 omx2 = pk2(1.f - wx, 1.f - wx), omy2 = pk2(1.f - wy, 1.f - wy);
    union { half8 v; h2 p[4]; } a, b;
    a.v = q0; b.v = q1;
    h2 t0 = a.p[0] * omx2 + a.p[2] * wx2;
    h2 t1 = a.p[1] * omx2 + a.p[3] * wx2;
    h2 c0 = b.p[0] * omx2 + b.p[2] * wx2;
    h2 c1 = b.p[1] * omx2 + b.p[3] * wx2;
    f[0] = t0 * omy2 + c0 * wy2;
    f[1] = t1 * omy2 + c1 * wy2;
}

// relu (f32) then packed f32->f16 convert: 4 v_max + 2 v_cvt_pkrtz.
__device__ __forceinline__ half4 relu_pk4(float a, float b, float c, float d) {
    union { half4 v; fp16x2 p[2]; } u;
    u.p[0] = __builtin_amdgcn_cvt_pkrtz(fmaxf(a, 0.0f), fmaxf(b, 0.0f));
    u.p[1] = __builtin_amdgcn_cvt_pkrtz(fmaxf(c, 0.0f), fmaxf(d, 0.0f));
    return u.v;
}

// ---- per-launch table pack: float4 corner tables -> fp16 quad tables in ws.
// cell (y,x) of table t -> 32B = {v00,v10}{v01,v11} fp16. 32B-aligned so a
// quad never straddles a 64B line: gathers go 4 divergent loads -> 1 address.
__global__ void pack_tables(const float4* __restrict__ e0,
                            const float4* __restrict__ e1,
                            const float4* __restrict__ e2,
                            half8* __restrict__ q)
{
    int c = blockIdx.x * blockDim.x + threadIdx.x;
    const float4* src; int res, qb;
    if (c < NC0)                    { src = e0; res = 512; qb = 0; }
    else if (c < NC0 + NC1)         { src = e1; res = 264; qb = 2 * NC0; c -= NC0; }
    else if (c < NC0 + NC1 + NC2)   { src = e2; res = 16;  qb = 2 * (NC0 + NC1); c -= NC0 + NC1; }
    else return;
    float4 A = src[c], B = src[c + 1], C = src[c + res], D = src[c + res + 1];
    union { half8 v; fp16x2 p[4]; } u0, u1;
    u0.p[0] = __builtin_amdgcn_cvt_pkrtz(A.x, A.y);
    u0.p[1] = __builtin_amdgcn_cvt_pkrtz(A.z, A.w);
    u0.p[2] = __builtin_amdgcn_cvt_pkrtz(B.x, B.y);
    u0.p[3] = __builtin_amdgcn_cvt_pkrtz(B.z, B.w);
    u1.p[0] = __builtin_amdgcn_cvt_pkrtz(C.x, C.y);
    u1.p[1] = __builtin_amdgcn_cvt_pkrtz(C.z, C.w);
    u1.p[2] = __builtin_amdgcn_cvt_pkrtz(D.x, D.y);
    u1.p[3] = __builtin_amdgcn_cvt_pkrtz(D.z, D.w);
    q[qb + 2 * c]     = u0.v;
    q[qb + 2 * c + 1] = u1.v;
}

// Session evidence (r0-r6): +waves at constant gather pattern = 0% (r0->r3);
// halving divergent gather requests = -34% (r3->r4); every attempt to add
// registers (4 waves/SIMD r5, deeper pipeline r6) spills and regresses.
// Conclusion: per-CU vector-memory REQUEST throughput (TA/TCP) is the wall;
// the lever is requests/point, not occupancy/depth.
// This round = exact r4 structure (validated 130us, no spill) + emb2 quad
// table (8KB) staged in LDS: its 2 divergent global loads/point (L1-hits but
// TA-slot burners, ~1/3 of table requests) become ds_reads on the LDS pipe.
// Bonus: t2*/m2* prefetch regs disappear -> ~18 fewer live regs than r4.
__global__ __launch_bounds__(TPB, 3) void dgn_mfma(
    const float*  __restrict__ x,
    const half8*  __restrict__ qt,
    const float*  __restrict__ w1, const float* __restrict__ b1,
    const float*  __restrict__ w2, const float* __restrict__ b2,
    const float*  __restrict__ w3, const float* __restrict__ b3,
    float*        __restrict__ out, int npts)
{
    __shared__ __align__(16) _Float16 smem[4 * 4096];   // 4 waves * 8KB, wave-private
    __shared__ __align__(16) _Float16 w2l[4096];        // 8KB shared w2 fragments
    __shared__ __align__(16) _Float16 e2l[4096];        // 8KB emb2 quad table

    const half8* q0t = qt;
    const half8* q1t = qt + 2 * NC0;
    const half8* q2t = qt + 2 * (NC0 + NC1);

    const int tid  = threadIdx.x;
    const int lane = tid & 63;
    const int wv   = tid >> 6;
    const int l15  = lane & 15;
    const int quad = lane >> 4;

    // ---- one-time staging: w2 fragments (swizzled) + emb2 quad table ----
    for (int e = tid; e < 4096; e += TPB) {
        int nt = e >> 10, rem = e & 1023, lw = rem >> 6, s = rem & 63;
        int oh = ((s & 3) << 4) | (s >> 2);             // sigma^{-1}
        w2l[nt * 1024 + lw * 64 + (s ^ ((lw & 7) << 3))] =
            (_Float16)w2[oh * 64 + nt * 16 + lw];
    }
    for (int e = tid; e < 2 * NC2; e += TPB)            // 512 x half8 = 8KB
        ((half8*)e2l)[e] = q2t[e];
    __syncthreads();

    // ---- persistent weight fragments. w1 K-permutation: slot k<12 -> row k+1
    // (features), slot 12 -> row 0 (idf), slots 13-15 -> zero. ----
    half8 w1f[4];
    #pragma unroll
    for (int nt = 0; nt < 4; ++nt)
        #pragma unroll
        for (int j = 0; j < 8; ++j) {
            int k = quad * 8 + j;
            int row = (k < 12) ? (k + 1) : ((k == 12) ? 0 : -1);
            w1f[nt][j] = (row >= 0) ? (_Float16)w1[row * 64 + nt * 16 + l15] : (_Float16)0.0f;
        }
    float b1v[4], b2v[4];
    #pragma unroll
    for (int nt = 0; nt < 4; ++nt) { b1v[nt] = b1[nt * 16 + l15]; b2v[nt] = b2[nt * 16 + l15]; }
    half8 w3f[2];
    #pragma unroll
    for (int ks = 0; ks < 2; ++ks)
        #pragma unroll
        for (int j = 0; j < 8; ++j) {
            int s  = ks * 32 + quad * 8 + j;
            int oh = ((s & 3) << 4) | (s >> 2);
            w3f[ks][j] = (l15 < 3) ? (_Float16)w3[oh * 3 + l15] : (_Float16)0.0f;
        }
    const float qsel = (quad == 0) ? 1.0f : 0.0f;
    const float qb30 = qsel * b3[0], qb31 = qsel * b3[1], qb32 = qsel * b3[2];

    // ---- precomputed LDS addresses (half-element units) ----
    const int bufh = wv * 4096;
    const int ewr0 = bufh + lane * 64 + ((lane & 7) ^ 0) * 8;
    const int ewr1 = bufh + lane * 64 + ((lane & 7) ^ 1) * 8;
    const int erd  = bufh + l15 * 64 + (quad ^ (l15 & 7)) * 8;          // quad<2 only
    int hwb[4];
    #pragma unroll
    for (int r = 0; r < 4; ++r) {
        int pr = quad * 4 + r;
        hwb[r] = bufh + pr * 64 + (((l15 >> 1) ^ (pr & 7)) * 8) + (l15 & 1) * 4;
    }
    int rd2[2];
    #pragma unroll
    for (int ks = 0; ks < 2; ++ks)
        rd2[ks] = bufh + l15 * 64 + (((ks * 4 + quad) ^ (l15 & 7)) * 8);
    int w2a[2];
    #pragma unroll
    for (int ks = 0; ks < 2; ++ks)
        w2a[ks] = l15 * 64 + (((ks * 4 + quad) ^ (l15 & 7)) * 8);

    const int ntiles = npts >> 8;
    const int gdim   = gridDim.x;

    // ---- prologue: tile-0 x + emb0/emb1 quad loads in flight ----
    float cidf, cu, cv, wx0, wy0, wx1, wy1;
    half8 t0a, t0b, t1a, t1b;
    {
        int p0 = (blockIdx.x << 8) + (wv << 6) + lane;
        cidf = x[3 * p0]; cu = x[3 * p0 + 1]; cv = x[3 * p0 + 2];
        GQ g0 = gq(512, cu, cv); wx0 = g0.wx; wy0 = g0.wy;
        t0a = q0t[2 * g0.c]; t0b = q0t[2 * g0.c + 1];
        GQ g1 = gq(264, cu, cv); wx1 = g1.wx; wy1 = g1.wy;
        t1a = q1t[2 * g1.c]; t1b = q1t[2 * g1.c + 1];
    }

    for (int tile = blockIdx.x; tile < ntiles; tile += gdim) {
        // ---- finish current tile's features (emb2 from LDS, no TA slot) ----
        h2 F0[2], F1[2], F2[2];
        bilq(t0a, t0b, wx0, wy0, F0);
        bilq(t1a, t1b, wx1, wy1, F1);
        {
            GQ g2 = gq(16, cu, cv);
            half8 qa = *(const half8*)&e2l[g2.c * 16];
            half8 qb = *(const half8*)&e2l[g2.c * 16 + 8];
            bilq(qa, qb, g2.wx, g2.wy, F2);
        }
        // E pack: slots 0-11 = features, slot 12 = idf, 13-15 = 0
        union H8 { half8 v; h2 p[4]; } e0u, e1u;
        e0u.p[0] = F0[0]; e0u.p[1] = F0[1]; e0u.p[2] = F1[0]; e0u.p[3] = F1[1];
        e1u.p[0] = F2[0]; e1u.p[1] = F2[1];
        e1u.p[2] = pk2(cidf, 0.0f); e1u.p[3] = pk2(0.0f, 0.0f);
        *(half8*)&smem[ewr0] = e0u.v;
        *(half8*)&smem[ewr1] = e1u.v;

        // ---- prefetch next tile's x (latency hidden by layer 1) ----
        int nxt = tile + gdim;
        int ptn = (((nxt < ntiles) ? nxt : tile) << 8) + (wv << 6) + lane;
        float nidf = x[3 * ptn], nu = x[3 * ptn + 1], nv = x[3 * ptn + 2];

        // ---- layer 1: K=32 (quads 2-3 feed zeros), bias in C-init ----
        #pragma unroll
        for (int mt = 0; mt < 4; ++mt) {
            half8 ea = { (_Float16)0, (_Float16)0, (_Float16)0, (_Float16)0,
                         (_Float16)0, (_Float16)0, (_Float16)0, (_Float16)0 };
            if (quad < 2) ea = *(const half8*)&smem[erd + mt * 1024];
            floatx4 acc[4];
            #pragma unroll
            for (int nt = 0; nt < 4; ++nt) {
                acc[nt] = (floatx4){ b1v[nt], b1v[nt], b1v[nt], b1v[nt] };
                acc[nt] = __builtin_amdgcn_mfma_f32_16x16x32_f16(ea, w1f[nt], acc[nt], 0, 0, 0);
            }
            #pragma unroll
            for (int r = 0; r < 4; ++r)
                *(half4*)&smem[hwb[r] + mt * 1024] =
                    relu_pk4(acc[0][r], acc[1][r], acc[2][r], acc[3][r]);
        }

        // ---- issue next tile's emb0/emb1 quad loads (hidden by L2-3) ----
        float nwx0, nwy0, nwx1, nwy1;
        half8 m0a, m0b, m1a, m1b;
        {
            GQ g0 = gq(512, nu, nv); nwx0 = g0.wx; nwy0 = g0.wy;
            m0a = q0t[2 * g0.c]; m0b = q0t[2 * g0.c + 1];
            GQ g1 = gq(264, nu, nv); nwx1 = g1.wx; nwy1 = g1.wy;
            m1a = q1t[2 * g1.c]; m1b = q1t[2 * g1.c + 1];
        }

        // ---- layer 2 (K=64): w2 frags reloaded phase-locally from LDS ----
        half8 w2r[4][2];
        #pragma unroll
        for (int nt = 0; nt < 4; ++nt)
            #pragma unroll
            for (int ks = 0; ks < 2; ++ks)
                w2r[nt][ks] = *(const half8*)&w2l[nt * 1024 + w2a[ks]];
        #pragma unroll
        for (int mt = 0; mt < 4; ++mt) {
            floatx4 acc[4];
            #pragma unroll
            for (int nt = 0; nt < 4; ++nt)
                acc[nt] = (floatx4){ b2v[nt], b2v[nt], b2v[nt], b2v[nt] };
            #pragma unroll
            for (int ks = 0; ks < 2; ++ks) {
                half8 a2 = *(const half8*)&smem[rd2[ks] + mt * 1024];
                #pragma unroll
                for (int nt = 0; nt < 4; ++nt)
                    acc[nt] = __builtin_amdgcn_mfma_f32_16x16x32_f16(a2, w2r[nt][ks], acc[nt], 0, 0, 0);
            }
            #pragma unroll
            for (int r = 0; r < 4; ++r)
                *(half4*)&smem[hwb[r] + mt * 1024] =
                    relu_pk4(acc[0][r], acc[1][r], acc[2][r], acc[3][r]);
        }

        // ---- layer 3 (transposed) ----
        #pragma unroll
        for (int mt = 0; mt < 4; ++mt) {
            floatx4 acc3 = (floatx4){ qb30, qb31, qb32, 0.0f };
            #pragma unroll
            for (int ks = 0; ks < 2; ++ks) {
                half8 bfr = *(const half8*)&smem[rd2[ks] + mt * 1024];
                acc3 = __builtin_amdgcn_mfma_f32_16x16x32_f16(w3f[ks], bfr, acc3, 0, 0, 0);
            }
            if (quad == 0) {
                const int P = (tile << 8) + (wv << 6) + mt * 16 + l15;
                out[3 * P + 0] = acc3[0];
                out[3 * P + 1] = acc3[1];
                out[3 * P + 2] = acc3[2];
            }
        }

        // ---- rotate pipeline registers ----
        cidf = nidf; cu = nu; cv = nv;
        wx0 = nwx0; wy0 = nwy0; wx1 = nwx1; wy1 = nwy1;
        t0a = m0a; t0b = m0b; t1a = m1a; t1b = m1b;
    }
}

// ---- fallback (validated round-3 kernel, float4 gathers) for tiny ws ----
__global__ __launch_bounds__(TPB, 3) void dgn_mfma_fb(
    const float*  __restrict__ x,
    const float4* __restrict__ emb0,
    const float4* __restrict__ emb1,
    const float4* __restrict__ emb2,
    const float*  __restrict__ w1, const float* __restrict__ b1,
    const float*  __restrict__ w2, const float* __restrict__ b2,
    const float*  __restrict__ w3, const float* __restrict__ b3,
    float*        __restrict__ out, int npts)
{
    __shared__ __align__(16) _Float16 smem[4 * 4096];
    __shared__ __align__(16) _Float16 w2l[4096];

    const int tid  = threadIdx.x;
    const int lane = tid & 63;
    const int wv   = tid >> 6;
    const int l15  = lane & 15;
    const int quad = lane >> 4;

    for (int e = tid; e < 4096; e += TPB) {
        int nt = e >> 10, rem = e & 1023, lw = rem >> 6, s = rem & 63;
        int oh = ((s & 3) << 4) | (s >> 2);
        w2l[nt * 1024 + lw * 64 + (s ^ ((lw & 7) << 3))] =
            (_Float16)w2[oh * 64 + nt * 16 + lw];
    }
    __syncthreads();

    half8 w1f[4];
    #pragma unroll
    for (int nt = 0; nt < 4; ++nt)
        #pragma unroll
        for (int j = 0; j < 8; ++j) {
            int k = quad * 8 + j;
            w1f[nt][j] = (k < 13) ? (_Float16)w1[k * 64 + nt * 16 + l15] : (_Float16)0.0f;
        }
    float b1v[4], b2v[4];
    #pragma unroll
    for (int nt = 0; nt < 4; ++nt) { b1v[nt] = b1[nt * 16 + l15]; b2v[nt] = b2[nt * 16 + l15]; }
    half8 w3f[2];
    #pragma unroll
    for (int ks = 0; ks < 2; ++ks)
        #pragma unroll
        for (int j = 0; j < 8; ++j) {
            int s  = ks * 32 + quad * 8 + j;
            int oh = ((s & 3) << 4) | (s >> 2);
            w3f[ks][j] = (l15 < 3) ? (_Float16)w3[oh * 3 + l15] : (_Float16)0.0f;
        }
    const float qsel = (quad == 0) ? 1.0f : 0.0f;
    const float qb30 = qsel * b3[0], qb31 = qsel * b3[1], qb32 = qsel * b3[2];

    const int bufh = wv * 4096;
    const int ewr0 = bufh + lane * 64 + ((lane & 7) ^ 0) * 8;
    const int ewr1 = bufh + lane * 64 + ((lane & 7) ^ 1) * 8;
    const int erd  = bufh + l15 * 64 + (quad ^ (l15 & 7)) * 8;
    int hwb[4];
    #pragma unroll
    for (int r = 0; r < 4; ++r) {
        int pr = quad * 4 + r;
        hwb[r] = bufh + pr * 64 + (((l15 >> 1) ^ (pr & 7)) * 8) + (l15 & 1) * 4;
    }
    int rd2[2];
    #pragma unroll
    for (int ks = 0; ks < 2; ++ks)
        rd2[ks] = bufh + l15 * 64 + (((ks * 4 + quad) ^ (l15 & 7)) * 8);
    int w2a[2];
    #pragma unroll
    for (int ks = 0; ks < 2; ++ks)
        w2a[ks] = l15 * 64 + (((ks * 4 + quad) ^ (l15 & 7)) * 8);

    const int ntiles = npts >> 8;
    const int gdim   = gridDim.x;

    float cidf, cu, cv, wx0, wy0, wx1, wy1;
    float4 t00, t01, t02, t03, t10, t11, t12, t13;
    {
        int p0 = (blockIdx.x << 8) + (wv << 6) + lane;
        cidf = x[3 * p0]; cu = x[3 * p0 + 1]; cv = x[3 * p0 + 2];
        GAddr g0 = gaddr(512, cu, cv); wx0 = g0.wx; wy0 = g0.wy;
        t00 = emb0[g0.i00]; t01 = emb0[g0.i10]; t02 = emb0[g0.i01]; t03 = emb0[g0.i11];
        GAddr g1 = gaddr(264, cu, cv); wx1 = g1.wx; wy1 = g1.wy;
        t10 = emb1[g1.i00]; t11 = emb1[g1.i10]; t12 = emb1[g1.i01]; t13 = emb1[g1.i11];
    }

    for (int tile = blockIdx.x; tile < ntiles; tile += gdim) {
        float f[12];
        bil4(t00, t01, t02, t03, wx0, wy0, f);
        bil4(t10, t11, t12, t13, wx1, wy1, f + 4);
        {
            GAddr g2 = gaddr(16, cu, cv);
            bil4(emb2[g2.i00], emb2[g2.i10], emb2[g2.i01], emb2[g2.i11], g2.wx, g2.wy, f + 8);
        }
        union H8 { half8 v; fp16x2 p[4]; } e0u, e1u;
        e0u.p[0] = __builtin_amdgcn_cvt_pkrtz(cidf, f[0]);
        e0u.p[1] = __builtin_amdgcn_cvt_pkrtz(f[1], f[2]);
        e0u.p[2] = __builtin_amdgcn_cvt_pkrtz(f[3], f[4]);
        e0u.p[3] = __builtin_amdgcn_cvt_pkrtz(f[5], f[6]);
        e1u.p[0] = __builtin_amdgcn_cvt_pkrtz(f[7], f[8]);
        e1u.p[1] = __builtin_amdgcn_cvt_pkrtz(f[9], f[10]);
        e1u.p[2] = __builtin_amdgcn_cvt_pkrtz(f[11], 0.0f);
        e1u.p[3] = __builtin_amdgcn_cvt_pkrtz(0.0f, 0.0f);
        *(half8*)&smem[ewr0] = e0u.v;
        *(half8*)&smem[ewr1] = e1u.v;

        int nxt = tile + gdim;
        int ptn = (((nxt < ntiles) ? nxt : tile) << 8) + (wv << 6) + lane;
        float nidf = x[3 * ptn], nu = x[3 * ptn + 1], nv = x[3 * ptn + 2];

        #pragma unroll
        for (int mt = 0; mt < 4; ++mt) {
            half8 ea = { (_Float16)0, (_Float16)0, (_Float16)0, (_Float16)0,
                         (_Float16)0, (_Float16)0, (_Float16)0, (_Float16)0 };
            if (quad < 2) ea = *(const half8*)&smem[erd + mt * 1024];
            floatx4 acc[4];
            #pragma unroll
            for (int nt = 0; nt < 4; ++nt) {
                acc[nt] = (floatx4){ b1v[nt], b1v[nt], b1v[nt], b1v[nt] };
                acc[nt] = __builtin_amdgcn_mfma_f32_16x16x32_f16(ea, w1f[nt], acc[nt], 0, 0, 0);
            }
            #pragma unroll
            for (int r = 0; r < 4; ++r)
                *(half4*)&smem[hwb[r] + mt * 1024] =
                    relu_pk4(acc[0][r], acc[1][r], acc[2][r], acc[3][r]);
        }

        float nwx0, nwy0, nwx1, nwy1;
        float4 n00, n01, n02, n03, n10, n11, n12, n13;
        {
            GAddr g0 = gaddr(512, nu, nv); nwx0 = g0.wx; nwy0 = g0.wy;
            n00 = emb0[g0.i00]; n01 = emb0[g0.i10]; n02 = emb0[g0.i01]; n03 = emb0[g0.i11];
            GAddr g1 = gaddr(264, nu, nv); nwx1 = g1.wx; nwy1 = g1.wy;
            n10 = emb1[g1.i00]; n11 = emb1[g1.i10]; n12 = emb1[g1.i01]; n13 = emb1[g1.i11];
        }

        half8 w2r[4][2];
        #pragma unroll
        for (int nt = 0; nt < 4; ++nt)
            #pragma unroll
            for (int ks = 0; ks < 2; ++ks)
                w2r[nt][ks] = *(const half8*)&w2l[nt * 1024 + w2a[ks]];
        #pragma unroll
        for (int mt = 0; mt < 4; ++mt) {
            floatx4 acc[4];
            #pragma unroll
            for (int nt = 0; nt < 4; ++nt)
                acc[nt] = (floatx4){ b2v[nt], b2v[nt], b2v[nt], b2v[nt] };
            #pragma unroll
            for (int ks = 0; ks < 2; ++ks) {
                half8 a2 = *(const half8*)&smem[rd2[ks] + mt * 1024];
                #pragma unroll
                for (int nt = 0; nt < 4; ++nt)
                    acc[nt] = __builtin_amdgcn_mfma_f32_16x16x32_f16(a2, w2r[nt][ks], acc[nt], 0, 0, 0);
            }
            #pragma unroll
            for (int r = 0; r < 4; ++r)
                *(half4*)&smem[hwb[r] + mt * 1024] =
                    relu_pk4(acc[0][r], acc[1][r], acc[2][r], acc[3][r]);
        }

        #pragma unroll
        for (int mt = 0; mt < 4; ++mt) {
            floatx4 acc3 = (floatx4){ qb30, qb31, qb32, 0.0f };
            #pragma unroll
            for (int ks = 0; ks < 2; ++ks) {
                half8 bfr = *(const half8*)&smem[rd2[ks] + mt * 1024];
                acc3 = __builtin_amdgcn_mfma_f32_16x16x32_f16(w3f[ks], bfr, acc3, 0, 0, 0);
            }
            if (quad == 0) {
                const int P = (tile << 8) + (wv << 6) + mt * 16 + l15;
                out[3 * P + 0] = acc3[0];
                out[3 * P + 1] = acc3[1];
                out[3 * P + 2] = acc3[2];
            }
        }

        cidf = nidf; cu = nu; cv = nv;
        wx0 = nwx0; wy0 = nwy0; wx1 = nwx1; wy1 = nwy1;
        t00 = n00; t01 = n01; t02 = n02; t03 = n03;
        t10 = n10; t11 = n11; t12 = n12; t13 = n13;
    }
}

extern "C" void kernel_launch(void* const* d_in, const int* in_sizes, int n_in,
                              void* d_out, int out_size, void* d_ws, size_t ws_size,
                              hipStream_t stream) {
    const float*  x    = (const float*)  d_in[0];
    const float4* emb0 = (const float4*) d_in[1];
    const float4* emb1 = (const float4*) d_in[2];
    const float4* emb2 = (const float4*) d_in[3];
    const float*  w1   = (const float*)  d_in[4];
    const float*  b1   = (const float*)  d_in[5];
    const float*  w2   = (const float*)  d_in[6];
    const float*  b2   = (const float*)  d_in[7];
    const float*  w3   = (const float*)  d_in[8];
    const float*  b3   = (const float*)  d_in[9];
    float* out = (float*)d_out;

    int npts = in_sizes[0] / 3;
    const size_t need = (size_t)(NC0 + NC1 + NC2) * 32;   // 10.6 MB quad tables

    if (d_ws != nullptr && ws_size >= need) {
        int cells = NC0 + NC1 + NC2;
        pack_tables<<<(cells + 255) / 256, 256, 0, stream>>>(emb0, emb1, emb2, (half8*)d_ws);
        dgn_mfma<<<768, TPB, 0, stream>>>(x, (const half8*)d_ws,
                                          w1, b1, w2, b2, w3, b3, out, npts);
    } else {
        dgn_mfma_fb<<<768, TPB, 0, stream>>>(x, emb0, emb1, emb2,
                                             w1, b1, w2, b2, w3, b3, out, npts);
    }
}

// Round 8
// 218.665 us; speedup vs baseline: 1.3646x; 1.0064x over previous
//
#include <hip/hip_runtime.h>

typedef _Float16 half8 __attribute__((ext_vector_type(8)));
typedef _Float16 half4 __attribute__((ext_vector_type(4)));
typedef _Float16 h2    __attribute__((ext_vector_type(2)));
typedef __fp16  fp16x2 __attribute__((ext_vector_type(2)));
typedef float floatx4 __attribute__((ext_vector_type(4)));

#define TPB 256

// quad-table geometry (cells = res*res, row stride res, matching reference's
// tab[y*res+x] indexing; clamp x1=min(x0+1,res) never binds for u,v in [0,1))
#define NC0 (512 * 512)
#define NC1 (264 * 264)
#define NC2 (16 * 16)

struct GAddr { int i00, i10, i01, i11; float wx, wy; };

__device__ __forceinline__ GAddr gaddr(int res, float u, float v) {
    float r = (float)res;
    float sx = u * r, sy = v * r;
    int x0 = (int)sx, y0 = (int)sy;            // truncation, matches astype(int32)
    float wx = sx - (float)x0, wy = sy - (float)y0;
    int x1 = min(x0 + 1, res), y1 = min(y0 + 1, res);
    GAddr g;
    g.i00 = y0 * res + x0;  g.i10 = y0 * res + x1;   // reference stride = res
    g.i01 = y1 * res + x0;  g.i11 = y1 * res + x1;
    g.wx = wx; g.wy = wy;
    return g;
}

struct GQ { int c; float wx, wy; };

__device__ __forceinline__ GQ gq(int res, float u, float v) {
    float r = (float)res;
    float sx = u * r, sy = v * r;
    int x0 = (int)sx, y0 = (int)sy;
    GQ g; g.c = y0 * res + x0; g.wx = sx - (float)x0; g.wy = sy - (float)y0;
    return g;
}

__device__ __forceinline__ void bil4(float4 v00, float4 v10, float4 v01, float4 v11,
                                     float wx, float wy, float* f) {
    float omx = 1.0f - wx, omy = 1.0f - wy;
    f[0] = (v00.x * omx + v10.x * wx) * omy + (v01.x * omx + v11.x * wx) * wy;
    f[1] = (v00.y * omx + v10.y * wx) * omy + (v01.y * omx + v11.y * wx) * wy;
    f[2] = (v00.z * omx + v10.z * wx) * omy + (v01.z * omx + v11.z * wx) * wy;
    f[3] = (v00.w * omx + v10.w * wx) * omy + (v01.w * omx + v11.w * wx) * wy;
}

__device__ __forceinline__ h2 pk2(float a, float b) {
    fp16x2 r = __builtin_amdgcn_cvt_pkrtz(a, b);
    union { fp16x2 f; h2 h; } u; u.f = r; return u.h;
}

// packed-fp16 bilinear on a 32B quad {v00[4],v10[4]} {v01[4],v11[4]}.
// 12 v_pk ops + 4 pkrtz; outputs f[0]=(feat0,feat1), f[1]=(feat2,feat3).
__device__ __forceinline__ void bilq(half8 q0, half8 q1, float wx, float wy, h2* f) {
    h2 wx2  = pk2(wx, wx),           wy2  = pk2(wy, wy);
    h2 omx2 = pk2(1.f - wx, 1.f - wx), omy2 = pk2(1.f - wy, 1.f - wy);
    union { half8 v; h2 p[4]; } a, b;
    a.v = q0; b.v = q1;
    h2 t0 = a.p[0] * omx2 + a.p[2] * wx2;
    h2 t1 = a.p[1] * omx2 + a.p[3] * wx2;
    h2 c0 = b.p[0] * omx2 + b.p[2] * wx2;
    h2 c1 = b.p[1] * omx2 + b.p[3] * wx2;
    f[0] = t0 * omy2 + c0 * wy2;
    f[1] = t1 * omy2 + c1 * wy2;
}

// packed relu: cvt first, then v_pk_max_f16 vs 0 — 4 ops vs 6 (r8: -64
// VALU/tile across 32 calls). rtz-then-max(0) == max(0)-then-rtz (no NaNs).
__device__ __forceinline__ half4 relu_pk4(float a, float b, float c, float d) {
    union { half4 v; h2 p[2]; } u;
    u.p[0] = pk2(a, b);
    u.p[1] = pk2(c, d);
    half4 z = {(_Float16)0, (_Float16)0, (_Float16)0, (_Float16)0};
    return __builtin_elementwise_max(u.v, z);
}

// f32 relu variant for the fallback kernel (kept identical to validated r3).
__device__ __forceinline__ half4 relu_pk4f(float a, float b, float c, float d) {
    union { half4 v; fp16x2 p[2]; } u;
    u.p[0] = __builtin_amdgcn_cvt_pkrtz(fmaxf(a, 0.0f), fmaxf(b, 0.0f));
    u.p[1] = __builtin_amdgcn_cvt_pkrtz(fmaxf(c, 0.0f), fmaxf(d, 0.0f));
    return u.v;
}

// ---- per-launch table pack: float4 corner tables -> fp16 quad tables in ws.
// cell (y,x) of table t -> 32B = {v00,v10}{v01,v11} fp16. 32B-aligned so a
// quad never straddles a 64B line: gathers go 4 divergent loads -> 1 address.
__global__ void pack_tables(const float4* __restrict__ e0,
                            const float4* __restrict__ e1,
                            const float4* __restrict__ e2,
                            half8* __restrict__ q)
{
    int c = blockIdx.x * blockDim.x + threadIdx.x;
    const float4* src; int res, qb;
    if (c < NC0)                    { src = e0; res = 512; qb = 0; }
    else if (c < NC0 + NC1)         { src = e1; res = 264; qb = 2 * NC0; c -= NC0; }
    else if (c < NC0 + NC1 + NC2)   { src = e2; res = 16;  qb = 2 * (NC0 + NC1); c -= NC0 + NC1; }
    else return;
    float4 A = src[c], B = src[c + 1], C = src[c + res], D = src[c + res + 1];
    union { half8 v; fp16x2 p[4]; } u0, u1;
    u0.p[0] = __builtin_amdgcn_cvt_pkrtz(A.x, A.y);
    u0.p[1] = __builtin_amdgcn_cvt_pkrtz(A.z, A.w);
    u0.p[2] = __builtin_amdgcn_cvt_pkrtz(B.x, B.y);
    u0.p[3] = __builtin_amdgcn_cvt_pkrtz(B.z, B.w);
    u1.p[0] = __builtin_amdgcn_cvt_pkrtz(C.x, C.y);
    u1.p[1] = __builtin_amdgcn_cvt_pkrtz(C.z, C.w);
    u1.p[2] = __builtin_amdgcn_cvt_pkrtz(D.x, D.y);
    u1.p[3] = __builtin_amdgcn_cvt_pkrtz(D.z, D.w);
    q[qb + 2 * c]     = u0.v;
    q[qb + 2 * c + 1] = u1.v;
}

// r7 findings: emb2->LDS = 130->123.6us, no spill (VGPR 72), bank-conflict
// from e2l ~2% of wall (ignore). Remaining stall: x prefetch has only
// layer-1 (~350cyc) of cover vs ~900cyc streaming-HBM latency, delaying the
// gather issue every tile. r8 = r7 +
//   (1) 2-deep x pipeline ONLY (+3 regs; r6's spill came from also extending
//       m* gather-reg liveness, which stays put here), and
//   (2) packed-fp16 relu (cvt then v_pk_max: 4 ops vs 6, -64 VALU/tile).
__global__ __launch_bounds__(TPB, 3) void dgn_mfma(
    const float*  __restrict__ x,
    const half8*  __restrict__ qt,
    const float*  __restrict__ w1, const float* __restrict__ b1,
    const float*  __restrict__ w2, const float* __restrict__ b2,
    const float*  __restrict__ w3, const float* __restrict__ b3,
    float*        __restrict__ out, int npts)
{
    __shared__ __align__(16) _Float16 smem[4 * 4096];   // 4 waves * 8KB, wave-private
    __shared__ __align__(16) _Float16 w2l[4096];        // 8KB shared w2 fragments
    __shared__ __align__(16) _Float16 e2l[4096];        // 8KB emb2 quad table

    const half8* q0t = qt;
    const half8* q1t = qt + 2 * NC0;
    const half8* q2t = qt + 2 * (NC0 + NC1);

    const int tid  = threadIdx.x;
    const int lane = tid & 63;
    const int wv   = tid >> 6;
    const int l15  = lane & 15;
    const int quad = lane >> 4;

    // ---- one-time staging: w2 fragments (swizzled) + emb2 quad table ----
    for (int e = tid; e < 4096; e += TPB) {
        int nt = e >> 10, rem = e & 1023, lw = rem >> 6, s = rem & 63;
        int oh = ((s & 3) << 4) | (s >> 2);             // sigma^{-1}
        w2l[nt * 1024 + lw * 64 + (s ^ ((lw & 7) << 3))] =
            (_Float16)w2[oh * 64 + nt * 16 + lw];
    }
    for (int e = tid; e < 2 * NC2; e += TPB)            // 512 x half8 = 8KB
        ((half8*)e2l)[e] = q2t[e];
    __syncthreads();

    // ---- persistent weight fragments. w1 K-permutation: slot k<12 -> row k+1
    // (features), slot 12 -> row 0 (idf), slots 13-15 -> zero. ----
    half8 w1f[4];
    #pragma unroll
    for (int nt = 0; nt < 4; ++nt)
        #pragma unroll
        for (int j = 0; j < 8; ++j) {
            int k = quad * 8 + j;
            int row = (k < 12) ? (k + 1) : ((k == 12) ? 0 : -1);
            w1f[nt][j] = (row >= 0) ? (_Float16)w1[row * 64 + nt * 16 + l15] : (_Float16)0.0f;
        }
    float b1v[4], b2v[4];
    #pragma unroll
    for (int nt = 0; nt < 4; ++nt) { b1v[nt] = b1[nt * 16 + l15]; b2v[nt] = b2[nt * 16 + l15]; }
    half8 w3f[2];
    #pragma unroll
    for (int ks = 0; ks < 2; ++ks)
        #pragma unroll
        for (int j = 0; j < 8; ++j) {
            int s  = ks * 32 + quad * 8 + j;
            int oh = ((s & 3) << 4) | (s >> 2);
            w3f[ks][j] = (l15 < 3) ? (_Float16)w3[oh * 3 + l15] : (_Float16)0.0f;
        }
    const float qsel = (quad == 0) ? 1.0f : 0.0f;
    const float qb30 = qsel * b3[0], qb31 = qsel * b3[1], qb32 = qsel * b3[2];

    // ---- precomputed LDS addresses (half-element units) ----
    const int bufh = wv * 4096;
    const int ewr0 = bufh + lane * 64 + ((lane & 7) ^ 0) * 8;
    const int ewr1 = bufh + lane * 64 + ((lane & 7) ^ 1) * 8;
    const int erd  = bufh + l15 * 64 + (quad ^ (l15 & 7)) * 8;          // quad<2 only
    int hwb[4];
    #pragma unroll
    for (int r = 0; r < 4; ++r) {
        int pr = quad * 4 + r;
        hwb[r] = bufh + pr * 64 + (((l15 >> 1) ^ (pr & 7)) * 8) + (l15 & 1) * 4;
    }
    int rd2[2];
    #pragma unroll
    for (int ks = 0; ks < 2; ++ks)
        rd2[ks] = bufh + l15 * 64 + (((ks * 4 + quad) ^ (l15 & 7)) * 8);
    int w2a[2];
    #pragma unroll
    for (int ks = 0; ks < 2; ++ks)
        w2a[ks] = l15 * 64 + (((ks * 4 + quad) ^ (l15 & 7)) * 8);

    const int ntiles = npts >> 8;
    const int gdim   = gridDim.x;

    // ---- prologue: x[t0] and x[t0+g] loaded; tile-0 gathers in flight ----
    float cidf, cu, cv;            // x of current tile
    float nidf, nu, nv;            // x of next tile (2-deep pipeline)
    float wx0, wy0, wx1, wy1;
    half8 t0a, t0b, t1a, t1b;
    {
        int p0 = (blockIdx.x << 8) + (wv << 6) + lane;
        cidf = x[3 * p0]; cu = x[3 * p0 + 1]; cv = x[3 * p0 + 2];
        int tn = blockIdx.x + gdim;
        int p1 = (((tn < ntiles) ? tn : blockIdx.x) << 8) + (wv << 6) + lane;
        nidf = x[3 * p1]; nu = x[3 * p1 + 1]; nv = x[3 * p1 + 2];
        GQ g0 = gq(512, cu, cv); wx0 = g0.wx; wy0 = g0.wy;
        t0a = q0t[2 * g0.c]; t0b = q0t[2 * g0.c + 1];
        GQ g1 = gq(264, cu, cv); wx1 = g1.wx; wy1 = g1.wy;
        t1a = q1t[2 * g1.c]; t1b = q1t[2 * g1.c + 1];
    }

    for (int tile = blockIdx.x; tile < ntiles; tile += gdim) {
        // ---- issue x load for tile+2 at the very top (full-tile cover) ----
        int nxt2 = tile + 2 * gdim;
        int ptn = (((nxt2 < ntiles) ? nxt2 : tile) << 8) + (wv << 6) + lane;
        float fidf = x[3 * ptn], fu = x[3 * ptn + 1], fv = x[3 * ptn + 2];

        // ---- finish current tile's features (emb2 from LDS, no TA slot) ----
        h2 F0[2], F1[2], F2[2];
        bilq(t0a, t0b, wx0, wy0, F0);
        bilq(t1a, t1b, wx1, wy1, F1);
        {
            GQ g2 = gq(16, cu, cv);
            half8 qa = *(const half8*)&e2l[g2.c * 16];
            half8 qb = *(const half8*)&e2l[g2.c * 16 + 8];
            bilq(qa, qb, g2.wx, g2.wy, F2);
        }
        // E pack: slots 0-11 = features, slot 12 = idf, 13-15 = 0
        union H8 { half8 v; h2 p[4]; } e0u, e1u;
        e0u.p[0] = F0[0]; e0u.p[1] = F0[1]; e0u.p[2] = F1[0]; e0u.p[3] = F1[1];
        e1u.p[0] = F2[0]; e1u.p[1] = F2[1];
        e1u.p[2] = pk2(cidf, 0.0f); e1u.p[3] = pk2(0.0f, 0.0f);
        *(half8*)&smem[ewr0] = e0u.v;
        *(half8*)&smem[ewr1] = e1u.v;

        // ---- layer 1: K=32 (quads 2-3 feed zeros), bias in C-init ----
        #pragma unroll
        for (int mt = 0; mt < 4; ++mt) {
            half8 ea = { (_Float16)0, (_Float16)0, (_Float16)0, (_Float16)0,
                         (_Float16)0, (_Float16)0, (_Float16)0, (_Float16)0 };
            if (quad < 2) ea = *(const half8*)&smem[erd + mt * 1024];
            floatx4 acc[4];
            #pragma unroll
            for (int nt = 0; nt < 4; ++nt) {
                acc[nt] = (floatx4){ b1v[nt], b1v[nt], b1v[nt], b1v[nt] };
                acc[nt] = __builtin_amdgcn_mfma_f32_16x16x32_f16(ea, w1f[nt], acc[nt], 0, 0, 0);
            }
            #pragma unroll
            for (int r = 0; r < 4; ++r)
                *(half4*)&smem[hwb[r] + mt * 1024] =
                    relu_pk4(acc[0][r], acc[1][r], acc[2][r], acc[3][r]);
        }

        // ---- issue next tile's emb0/emb1 quad loads (x[t+1] already in
        //      regs — no x-latency stall in front of the gather issue) ----
        float nwx0, nwy0, nwx1, nwy1;
        half8 m0a, m0b, m1a, m1b;
        {
            GQ g0 = gq(512, nu, nv); nwx0 = g0.wx; nwy0 = g0.wy;
            m0a = q0t[2 * g0.c]; m0b = q0t[2 * g0.c + 1];
            GQ g1 = gq(264, nu, nv); nwx1 = g1.wx; nwy1 = g1.wy;
            m1a = q1t[2 * g1.c]; m1b = q1t[2 * g1.c + 1];
        }

        // ---- layer 2 (K=64): w2 frags reloaded phase-locally from LDS ----
        half8 w2r[4][2];
        #pragma unroll
        for (int nt = 0; nt < 4; ++nt)
            #pragma unroll
            for (int ks = 0; ks < 2; ++ks)
                w2r[nt][ks] = *(const half8*)&w2l[nt * 1024 + w2a[ks]];
        #pragma unroll
        for (int mt = 0; mt < 4; ++mt) {
            floatx4 acc[4];
            #pragma unroll
            for (int nt = 0; nt < 4; ++nt)
                acc[nt] = (floatx4){ b2v[nt], b2v[nt], b2v[nt], b2v[nt] };
            #pragma unroll
            for (int ks = 0; ks < 2; ++ks) {
                half8 a2 = *(const half8*)&smem[rd2[ks] + mt * 1024];
                #pragma unroll
                for (int nt = 0; nt < 4; ++nt)
                    acc[nt] = __builtin_amdgcn_mfma_f32_16x16x32_f16(a2, w2r[nt][ks], acc[nt], 0, 0, 0);
            }
            #pragma unroll
            for (int r = 0; r < 4; ++r)
                *(half4*)&smem[hwb[r] + mt * 1024] =
                    relu_pk4(acc[0][r], acc[1][r], acc[2][r], acc[3][r]);
        }

        // ---- layer 3 (transposed) ----
        #pragma unroll
        for (int mt = 0; mt < 4; ++mt) {
            floatx4 acc3 = (floatx4){ qb30, qb31, qb32, 0.0f };
            #pragma unroll
            for (int ks = 0; ks < 2; ++ks) {
                half8 bfr = *(const half8*)&smem[rd2[ks] + mt * 1024];
                acc3 = __builtin_amdgcn_mfma_f32_16x16x32_f16(w3f[ks], bfr, acc3, 0, 0, 0);
            }
            if (quad == 0) {
                const int P = (tile << 8) + (wv << 6) + mt * 16 + l15;
                out[3 * P + 0] = acc3[0];
                out[3 * P + 1] = acc3[1];
                out[3 * P + 2] = acc3[2];
            }
        }

        // ---- rotate pipeline registers ----
        cidf = nidf; cu = nu; cv = nv;
        nidf = fidf; nu = fu; nv = fv;
        wx0 = nwx0; wy0 = nwy0; wx1 = nwx1; wy1 = nwy1;
        t0a = m0a; t0b = m0b; t1a = m1a; t1b = m1b;
    }
}

// ---- fallback (validated round-3 kernel, float4 gathers) for tiny ws ----
__global__ __launch_bounds__(TPB, 3) void dgn_mfma_fb(
    const float*  __restrict__ x,
    const float4* __restrict__ emb0,
    const float4* __restrict__ emb1,
    const float4* __restrict__ emb2,
    const float*  __restrict__ w1, const float* __restrict__ b1,
    const float*  __restrict__ w2, const float* __restrict__ b2,
    const float*  __restrict__ w3, const float* __restrict__ b3,
    float*        __restrict__ out, int npts)
{
    __shared__ __align__(16) _Float16 smem[4 * 4096];
    __shared__ __align__(16) _Float16 w2l[4096];

    const int tid  = threadIdx.x;
    const int lane = tid & 63;
    const int wv   = tid >> 6;
    const int l15  = lane & 15;
    const int quad = lane >> 4;

    for (int e = tid; e < 4096; e += TPB) {
        int nt = e >> 10, rem = e & 1023, lw = rem >> 6, s = rem & 63;
        int oh = ((s & 3) << 4) | (s >> 2);
        w2l[nt * 1024 + lw * 64 + (s ^ ((lw & 7) << 3))] =
            (_Float16)w2[oh * 64 + nt * 16 + lw];
    }
    __syncthreads();

    half8 w1f[4];
    #pragma unroll
    for (int nt = 0; nt < 4; ++nt)
        #pragma unroll
        for (int j = 0; j < 8; ++j) {
            int k = quad * 8 + j;
            w1f[nt][j] = (k < 13) ? (_Float16)w1[k * 64 + nt * 16 + l15] : (_Float16)0.0f;
        }
    float b1v[4], b2v[4];
    #pragma unroll
    for (int nt = 0; nt < 4; ++nt) { b1v[nt] = b1[nt * 16 + l15]; b2v[nt] = b2[nt * 16 + l15]; }
    half8 w3f[2];
    #pragma unroll
    for (int ks = 0; ks < 2; ++ks)
        #pragma unroll
        for (int j = 0; j < 8; ++j) {
            int s  = ks * 32 + quad * 8 + j;
            int oh = ((s & 3) << 4) | (s >> 2);
            w3f[ks][j] = (l15 < 3) ? (_Float16)w3[oh * 3 + l15] : (_Float16)0.0f;
        }
    const float qsel = (quad == 0) ? 1.0f : 0.0f;
    const float qb30 = qsel * b3[0], qb31 = qsel * b3[1], qb32 = qsel * b3[2];

    const int bufh = wv * 4096;
    const int ewr0 = bufh + lane * 64 + ((lane & 7) ^ 0) * 8;
    const int ewr1 = bufh + lane * 64 + ((lane & 7) ^ 1) * 8;
    const int erd  = bufh + l15 * 64 + (quad ^ (l15 & 7)) * 8;
    int hwb[4];
    #pragma unroll
    for (int r = 0; r < 4; ++r) {
        int pr = quad * 4 + r;
        hwb[r] = bufh + pr * 64 + (((l15 >> 1) ^ (pr & 7)) * 8) + (l15 & 1) * 4;
    }
    int rd2[2];
    #pragma unroll
    for (int ks = 0; ks < 2; ++ks)
        rd2[ks] = bufh + l15 * 64 + (((ks * 4 + quad) ^ (l15 & 7)) * 8);
    int w2a[2];
    #pragma unroll
    for (int ks = 0; ks < 2; ++ks)
        w2a[ks] = l15 * 64 + (((ks * 4 + quad) ^ (l15 & 7)) * 8);

    const int ntiles = npts >> 8;
    const int gdim   = gridDim.x;

    float cidf, cu, cv, wx0, wy0, wx1, wy1;
    float4 t00, t01, t02, t03, t10, t11, t12, t13;
    {
        int p0 = (blockIdx.x << 8) + (wv << 6) + lane;
        cidf = x[3 * p0]; cu = x[3 * p0 + 1]; cv = x[3 * p0 + 2];
        GAddr g0 = gaddr(512, cu, cv); wx0 = g0.wx; wy0 = g0.wy;
        t00 = emb0[g0.i00]; t01 = emb0[g0.i10]; t02 = emb0[g0.i01]; t03 = emb0[g0.i11];
        GAddr g1 = gaddr(264, cu, cv); wx1 = g1.wx; wy1 = g1.wy;
        t10 = emb1[g1.i00]; t11 = emb1[g1.i10]; t12 = emb1[g1.i01]; t13 = emb1[g1.i11];
    }

    for (int tile = blockIdx.x; tile < ntiles; tile += gdim) {
        float f[12];
        bil4(t00, t01, t02, t03, wx0, wy0, f);
        bil4(t10, t11, t12, t13, wx1, wy1, f + 4);
        {
            GAddr g2 = gaddr(16, cu, cv);
            bil4(emb2[g2.i00], emb2[g2.i10], emb2[g2.i01], emb2[g2.i11], g2.wx, g2.wy, f + 8);
        }
        union H8 { half8 v; fp16x2 p[4]; } e0u, e1u;
        e0u.p[0] = __builtin_amdgcn_cvt_pkrtz(cidf, f[0]);
        e0u.p[1] = __builtin_amdgcn_cvt_pkrtz(f[1], f[2]);
        e0u.p[2] = __builtin_amdgcn_cvt_pkrtz(f[3], f[4]);
        e0u.p[3] = __builtin_amdgcn_cvt_pkrtz(f[5], f[6]);
        e1u.p[0] = __builtin_amdgcn_cvt_pkrtz(f[7], f[8]);
        e1u.p[1] = __builtin_amdgcn_cvt_pkrtz(f[9], f[10]);
        e1u.p[2] = __builtin_amdgcn_cvt_pkrtz(f[11], 0.0f);
        e1u.p[3] = __builtin_amdgcn_cvt_pkrtz(0.0f, 0.0f);
        *(half8*)&smem[ewr0] = e0u.v;
        *(half8*)&smem[ewr1] = e1u.v;

        int nxt = tile + gdim;
        int ptn = (((nxt < ntiles) ? nxt : tile) << 8) + (wv << 6) + lane;
        float nidf = x[3 * ptn], nu = x[3 * ptn + 1], nv = x[3 * ptn + 2];

        #pragma unroll
        for (int mt = 0; mt < 4; ++mt) {
            half8 ea = { (_Float16)0, (_Float16)0, (_Float16)0, (_Float16)0,
                         (_Float16)0, (_Float16)0, (_Float16)0, (_Float16)0 };
            if (quad < 2) ea = *(const half8*)&smem[erd + mt * 1024];
            floatx4 acc[4];
            #pragma unroll
            for (int nt = 0; nt < 4; ++nt) {
                acc[nt] = (floatx4){ b1v[nt], b1v[nt], b1v[nt], b1v[nt] };
                acc[nt] = __builtin_amdgcn_mfma_f32_16x16x32_f16(ea, w1f[nt], acc[nt], 0, 0, 0);
            }
            #pragma unroll
            for (int r = 0; r < 4; ++r)
                *(half4*)&smem[hwb[r] + mt * 1024] =
                    relu_pk4f(acc[0][r], acc[1][r], acc[2][r], acc[3][r]);
        }

        float nwx0, nwy0, nwx1, nwy1;
        float4 n00, n01, n02, n03, n10, n11, n12, n13;
        {
            GAddr g0 = gaddr(512, nu, nv); nwx0 = g0.wx; nwy0 = g0.wy;
            n00 = emb0[g0.i00]; n01 = emb0[g0.i10]; n02 = emb0[g0.i01]; n03 = emb0[g0.i11];
            GAddr g1 = gaddr(264, nu, nv); nwx1 = g1.wx; nwy1 = g1.wy;
            n10 = emb1[g1.i00]; n11 = emb1[g1.i10]; n12 = emb1[g1.i01]; n13 = emb1[g1.i11];
        }

        half8 w2r[4][2];
        #pragma unroll
        for (int nt = 0; nt < 4; ++nt)
            #pragma unroll
            for (int ks = 0; ks < 2; ++ks)
                w2r[nt][ks] = *(const half8*)&w2l[nt * 1024 + w2a[ks]];
        #pragma unroll
        for (int mt = 0; mt < 4; ++mt) {
            floatx4 acc[4];
            #pragma unroll
            for (int nt = 0; nt < 4; ++nt)
                acc[nt] = (floatx4){ b2v[nt], b2v[nt], b2v[nt], b2v[nt] };
            #pragma unroll
            for (int ks = 0; ks < 2; ++ks) {
                half8 a2 = *(const half8*)&smem[rd2[ks] + mt * 1024];
                #pragma unroll
                for (int nt = 0; nt < 4; ++nt)
                    acc[nt] = __builtin_amdgcn_mfma_f32_16x16x32_f16(a2, w2r[nt][ks], acc[nt], 0, 0, 0);
            }
            #pragma unroll
            for (int r = 0; r < 4; ++r)
                *(half4*)&smem[hwb[r] + mt * 1024] =
                    relu_pk4f(acc[0][r], acc[1][r], acc[2][r], acc[3][r]);
        }

        #pragma unroll
        for (int mt = 0; mt < 4; ++mt) {
            floatx4 acc3 = (floatx4){ qb30, qb31, qb32, 0.0f };
            #pragma unroll
            for (int ks = 0; ks < 2; ++ks) {
                half8 bfr = *(const half8*)&smem[rd2[ks] + mt * 1024];
                acc3 = __builtin_amdgcn_mfma_f32_16x16x32_f16(w3f[ks], bfr, acc3, 0, 0, 0);
            }
            if (quad == 0) {
                const int P = (tile << 8) + (wv << 6) + mt * 16 + l15;
                out[3 * P + 0] = acc3[0];
                out[3 * P + 1] = acc3[1];
                out[3 * P + 2] = acc3[2];
            }
        }

        cidf = nidf; cu = nu; cv = nv;
        wx0 = nwx0; wy0 = nwy0; wx1 = nwx1; wy1 = nwy1;
        t00 = n00; t01 = n01; t02 = n02; t03 = n03;
        t10 = n10; t11 = n11; t12 = n12; t13 = n13;
    }
}

extern "C" void kernel_launch(void* const* d_in, const int* in_sizes, int n_in,
                              void* d_out, int out_size, void* d_ws, size_t ws_size,
                              hipStream_t stream) {
    const float*  x    = (const float*)  d_in[0];
    const float4* emb0 = (const float4*) d_in[1];
    const float4* emb1 = (const float4*) d_in[2];
    const float4* emb2 = (const float4*) d_in[3];
    const float*  w1   = (const float*)  d_in[4];
    const float*  b1   = (const float*)  d_in[5];
    const float*  w2   = (const float*)  d_in[6];
    const float*  b2   = (const float*)  d_in[7];
    const float*  w3   = (const float*)  d_in[8];
    const float*  b3   = (const float*)  d_in[9];
    float* out = (float*)d_out;

    int npts = in_sizes[0] / 3;
    const size_t need = (size_t)(NC0 + NC1 + NC2) * 32;   // 10.6 MB quad tables

    if (d_ws != nullptr && ws_size >= need) {
        int cells = NC0 + NC1 + NC2;
        pack_tables<<<(cells + 255) / 256, 256, 0, stream>>>(emb0, emb1, emb2, (half8*)d_ws);
        dgn_mfma<<<768, TPB, 0, stream>>>(x, (const half8*)d_ws,
                                          w1, b1, w2, b2, w3, b3, out, npts);
    } else {
        dgn_mfma_fb<<<768, TPB, 0, stream>>>(x, emb0, emb1, emb2,
                                             w1, b1, w2, b2, w3, b3, out, npts);
    }
}

// Round 9
// 216.951 us; speedup vs baseline: 1.3754x; 1.0079x over previous
//
#include <hip/hip_runtime.h>

typedef _Float16 half8 __attribute__((ext_vector_type(8)));
typedef _Float16 half4 __attribute__((ext_vector_type(4)));
typedef _Float16 h2    __attribute__((ext_vector_type(2)));
typedef __fp16  fp16x2 __attribute__((ext_vector_type(2)));
typedef float floatx4 __attribute__((ext_vector_type(4)));

#define TPB 256

// quad-table geometry (cells = res*res, row stride res, matching reference's
// tab[y*res+x] indexing; clamp x1=min(x0+1,res) never binds for u,v in [0,1))
#define NC0 (512 * 512)
#define NC1 (264 * 264)
#define NC2 (16 * 16)

struct GAddr { int i00, i10, i01, i11; float wx, wy; };

__device__ __forceinline__ GAddr gaddr(int res, float u, float v) {
    float r = (float)res;
    float sx = u * r, sy = v * r;
    int x0 = (int)sx, y0 = (int)sy;            // truncation, matches astype(int32)
    float wx = sx - (float)x0, wy = sy - (float)y0;
    int x1 = min(x0 + 1, res), y1 = min(y0 + 1, res);
    GAddr g;
    g.i00 = y0 * res + x0;  g.i10 = y0 * res + x1;   // reference stride = res
    g.i01 = y1 * res + x0;  g.i11 = y1 * res + x1;
    g.wx = wx; g.wy = wy;
    return g;
}

struct GQ { int c; float wx, wy; };

__device__ __forceinline__ GQ gq(int res, float u, float v) {
    float r = (float)res;
    float sx = u * r, sy = v * r;
    int x0 = (int)sx, y0 = (int)sy;
    GQ g; g.c = y0 * res + x0; g.wx = sx - (float)x0; g.wy = sy - (float)y0;
    return g;
}

__device__ __forceinline__ void bil4(float4 v00, float4 v10, float4 v01, float4 v11,
                                     float wx, float wy, float* f) {
    float omx = 1.0f - wx, omy = 1.0f - wy;
    f[0] = (v00.x * omx + v10.x * wx) * omy + (v01.x * omx + v11.x * wx) * wy;
    f[1] = (v00.y * omx + v10.y * wx) * omy + (v01.y * omx + v11.y * wx) * wy;
    f[2] = (v00.z * omx + v10.z * wx) * omy + (v01.z * omx + v11.z * wx) * wy;
    f[3] = (v00.w * omx + v10.w * wx) * omy + (v01.w * omx + v11.w * wx) * wy;
}

__device__ __forceinline__ h2 pk2(float a, float b) {
    fp16x2 r = __builtin_amdgcn_cvt_pkrtz(a, b);
    union { fp16x2 f; h2 h; } u; u.f = r; return u.h;
}

// packed-fp16 bilinear on a 32B quad {v00[4],v10[4]} {v01[4],v11[4]}.
// 12 v_pk ops + 4 pkrtz; outputs f[0]=(feat0,feat1), f[1]=(feat2,feat3).
__device__ __forceinline__ void bilq(half8 q0, half8 q1, float wx, float wy, h2* f) {
    h2 wx2  = pk2(wx, wx),           wy2  = pk2(wy, wy);
    h2 omx2 = pk2(1.f - wx, 1.f - wx), omy2 = pk2(1.f - wy, 1.f - wy);
    union { half8 v; h2 p[4]; } a, b;
    a.v = q0; b.v = q1;
    h2 t0 = a.p[0] * omx2 + a.p[2] * wx2;
    h2 t1 = a.p[1] * omx2 + a.p[3] * wx2;
    h2 c0 = b.p[0] * omx2 + b.p[2] * wx2;
    h2 c1 = b.p[1] * omx2 + b.p[3] * wx2;
    f[0] = t0 * omy2 + c0 * wy2;
    f[1] = t1 * omy2 + c1 * wy2;
}

// packed relu: cvt first, then v_pk_max_f16 vs 0 — 4 ops vs 6.
// rtz-then-max(0) == max(0)-then-rtz (no NaNs).
__device__ __forceinline__ half4 relu_pk4(float a, float b, float c, float d) {
    union { half4 v; h2 p[2]; } u;
    u.p[0] = pk2(a, b);
    u.p[1] = pk2(c, d);
    half4 z = {(_Float16)0, (_Float16)0, (_Float16)0, (_Float16)0};
    return __builtin_elementwise_max(u.v, z);
}

// f32 relu variant for the fallback kernel (kept identical to validated r3).
__device__ __forceinline__ half4 relu_pk4f(float a, float b, float c, float d) {
    union { half4 v; fp16x2 p[2]; } u;
    u.p[0] = __builtin_amdgcn_cvt_pkrtz(fmaxf(a, 0.0f), fmaxf(b, 0.0f));
    u.p[1] = __builtin_amdgcn_cvt_pkrtz(fmaxf(c, 0.0f), fmaxf(d, 0.0f));
    return u.v;
}

// ---- per-launch table pack: float4 corner tables -> fp16 quad tables in ws.
// cell (y,x) of table t -> 32B = {v00,v10}{v01,v11} fp16. 32B-aligned so a
// quad never straddles a 64B line: gathers go 4 divergent loads -> 1 address.
__global__ void pack_tables(const float4* __restrict__ e0,
                            const float4* __restrict__ e1,
                            const float4* __restrict__ e2,
                            half8* __restrict__ q)
{
    int c = blockIdx.x * blockDim.x + threadIdx.x;
    const float4* src; int res, qb;
    if (c < NC0)                    { src = e0; res = 512; qb = 0; }
    else if (c < NC0 + NC1)         { src = e1; res = 264; qb = 2 * NC0; c -= NC0; }
    else if (c < NC0 + NC1 + NC2)   { src = e2; res = 16;  qb = 2 * (NC0 + NC1); c -= NC0 + NC1; }
    else return;
    float4 A = src[c], B = src[c + 1], C = src[c + res], D = src[c + res + 1];
    union { half8 v; fp16x2 p[4]; } u0, u1;
    u0.p[0] = __builtin_amdgcn_cvt_pkrtz(A.x, A.y);
    u0.p[1] = __builtin_amdgcn_cvt_pkrtz(A.z, A.w);
    u0.p[2] = __builtin_amdgcn_cvt_pkrtz(B.x, B.y);
    u0.p[3] = __builtin_amdgcn_cvt_pkrtz(B.z, B.w);
    u1.p[0] = __builtin_amdgcn_cvt_pkrtz(C.x, C.y);
    u1.p[1] = __builtin_amdgcn_cvt_pkrtz(C.z, C.w);
    u1.p[2] = __builtin_amdgcn_cvt_pkrtz(D.x, D.y);
    u1.p[3] = __builtin_amdgcn_cvt_pkrtz(D.z, D.w);
    q[qb + 2 * c]     = u0.v;
    q[qb + 2 * c + 1] = u1.v;
}

// r8 findings: packed relu cut VALUBusy 47.6->29.7% with ZERO dur change ->
// VALU issue is not the wall; 2-deep x alone also null -> x latency wasn't
// the exposed stall. Remaining exposed latency: the emb0/emb1 gathers,
// issued after layer 1 and consumed at the NEXT tile's bilq — cover is only
// layers 2+3 (~500cyc) vs ~600-900cyc L2-miss/L3 latency (emb0's 8.4MB quad
// table misses the 4MB/XCD L2 ~half the time). r9: move the gather issue to
// the VERY TOP of the tile body (enabled by r8's 2-deep x pipeline: x[t+1]
// already in regs) -> cover ~1400cyc. This is the one piece of r6 that
// mattered, now affordable: r6 also carried t2/m2 (+16 regs, moved to LDS
// in r7) and spilled; here only m* liveness extends (+16 over one phase,
// est. total ~155 < 170-reg budget at (256,3)).
__global__ __launch_bounds__(TPB, 3) void dgn_mfma(
    const float*  __restrict__ x,
    const half8*  __restrict__ qt,
    const float*  __restrict__ w1, const float* __restrict__ b1,
    const float*  __restrict__ w2, const float* __restrict__ b2,
    const float*  __restrict__ w3, const float* __restrict__ b3,
    float*        __restrict__ out, int npts)
{
    __shared__ __align__(16) _Float16 smem[4 * 4096];   // 4 waves * 8KB, wave-private
    __shared__ __align__(16) _Float16 w2l[4096];        // 8KB shared w2 fragments
    __shared__ __align__(16) _Float16 e2l[4096];        // 8KB emb2 quad table

    const half8* q0t = qt;
    const half8* q1t = qt + 2 * NC0;
    const half8* q2t = qt + 2 * (NC0 + NC1);

    const int tid  = threadIdx.x;
    const int lane = tid & 63;
    const int wv   = tid >> 6;
    const int l15  = lane & 15;
    const int quad = lane >> 4;

    // ---- one-time staging: w2 fragments (swizzled) + emb2 quad table ----
    for (int e = tid; e < 4096; e += TPB) {
        int nt = e >> 10, rem = e & 1023, lw = rem >> 6, s = rem & 63;
        int oh = ((s & 3) << 4) | (s >> 2);             // sigma^{-1}
        w2l[nt * 1024 + lw * 64 + (s ^ ((lw & 7) << 3))] =
            (_Float16)w2[oh * 64 + nt * 16 + lw];
    }
    for (int e = tid; e < 2 * NC2; e += TPB)            // 512 x half8 = 8KB
        ((half8*)e2l)[e] = q2t[e];
    __syncthreads();

    // ---- persistent weight fragments. w1 K-permutation: slot k<12 -> row k+1
    // (features), slot 12 -> row 0 (idf), slots 13-15 -> zero. ----
    half8 w1f[4];
    #pragma unroll
    for (int nt = 0; nt < 4; ++nt)
        #pragma unroll
        for (int j = 0; j < 8; ++j) {
            int k = quad * 8 + j;
            int row = (k < 12) ? (k + 1) : ((k == 12) ? 0 : -1);
            w1f[nt][j] = (row >= 0) ? (_Float16)w1[row * 64 + nt * 16 + l15] : (_Float16)0.0f;
        }
    float b1v[4], b2v[4];
    #pragma unroll
    for (int nt = 0; nt < 4; ++nt) { b1v[nt] = b1[nt * 16 + l15]; b2v[nt] = b2[nt * 16 + l15]; }
    half8 w3f[2];
    #pragma unroll
    for (int ks = 0; ks < 2; ++ks)
        #pragma unroll
        for (int j = 0; j < 8; ++j) {
            int s  = ks * 32 + quad * 8 + j;
            int oh = ((s & 3) << 4) | (s >> 2);
            w3f[ks][j] = (l15 < 3) ? (_Float16)w3[oh * 3 + l15] : (_Float16)0.0f;
        }
    const float qsel = (quad == 0) ? 1.0f : 0.0f;
    const float qb30 = qsel * b3[0], qb31 = qsel * b3[1], qb32 = qsel * b3[2];

    // ---- precomputed LDS addresses (half-element units) ----
    const int bufh = wv * 4096;
    const int ewr0 = bufh + lane * 64 + ((lane & 7) ^ 0) * 8;
    const int ewr1 = bufh + lane * 64 + ((lane & 7) ^ 1) * 8;
    const int erd  = bufh + l15 * 64 + (quad ^ (l15 & 7)) * 8;          // quad<2 only
    int hwb[4];
    #pragma unroll
    for (int r = 0; r < 4; ++r) {
        int pr = quad * 4 + r;
        hwb[r] = bufh + pr * 64 + (((l15 >> 1) ^ (pr & 7)) * 8) + (l15 & 1) * 4;
    }
    int rd2[2];
    #pragma unroll
    for (int ks = 0; ks < 2; ++ks)
        rd2[ks] = bufh + l15 * 64 + (((ks * 4 + quad) ^ (l15 & 7)) * 8);
    int w2a[2];
    #pragma unroll
    for (int ks = 0; ks < 2; ++ks)
        w2a[ks] = l15 * 64 + (((ks * 4 + quad) ^ (l15 & 7)) * 8);

    const int ntiles = npts >> 8;
    const int gdim   = gridDim.x;

    // ---- prologue: x[t0] and x[t0+g] loaded; tile-0 gathers in flight ----
    float cidf, cu, cv;            // x of current tile
    float nidf, nu, nv;            // x of next tile (2-deep pipeline)
    float wx0, wy0, wx1, wy1;
    half8 t0a, t0b, t1a, t1b;
    {
        int p0 = (blockIdx.x << 8) + (wv << 6) + lane;
        cidf = x[3 * p0]; cu = x[3 * p0 + 1]; cv = x[3 * p0 + 2];
        int tn = blockIdx.x + gdim;
        int p1 = (((tn < ntiles) ? tn : blockIdx.x) << 8) + (wv << 6) + lane;
        nidf = x[3 * p1]; nu = x[3 * p1 + 1]; nv = x[3 * p1 + 2];
        GQ g0 = gq(512, cu, cv); wx0 = g0.wx; wy0 = g0.wy;
        t0a = q0t[2 * g0.c]; t0b = q0t[2 * g0.c + 1];
        GQ g1 = gq(264, cu, cv); wx1 = g1.wx; wy1 = g1.wy;
        t1a = q1t[2 * g1.c]; t1b = q1t[2 * g1.c + 1];
    }

    for (int tile = blockIdx.x; tile < ntiles; tile += gdim) {
        // ---- 1. issue NEXT tile's emb0/emb1 gathers at the very top:
        //         x[t+1] already in regs, loads fly across the whole body ----
        float nwx0, nwy0, nwx1, nwy1;
        half8 m0a, m0b, m1a, m1b;
        {
            GQ g0 = gq(512, nu, nv); nwx0 = g0.wx; nwy0 = g0.wy;
            m0a = q0t[2 * g0.c]; m0b = q0t[2 * g0.c + 1];
            GQ g1 = gq(264, nu, nv); nwx1 = g1.wx; nwy1 = g1.wy;
            m1a = q1t[2 * g1.c]; m1b = q1t[2 * g1.c + 1];
        }

        // ---- 2. issue x load for tile+2 (consumed next iteration) ----
        int nxt2 = tile + 2 * gdim;
        int ptn = (((nxt2 < ntiles) ? nxt2 : tile) << 8) + (wv << 6) + lane;
        float fidf = x[3 * ptn], fu = x[3 * ptn + 1], fv = x[3 * ptn + 2];

        // ---- 3. finish current tile's features (t* loaded a full tile ago;
        //         emb2 from LDS, no TA slot) ----
        h2 F0[2], F1[2], F2[2];
        bilq(t0a, t0b, wx0, wy0, F0);
        bilq(t1a, t1b, wx1, wy1, F1);
        {
            GQ g2 = gq(16, cu, cv);
            half8 qa = *(const half8*)&e2l[g2.c * 16];
            half8 qb = *(const half8*)&e2l[g2.c * 16 + 8];
            bilq(qa, qb, g2.wx, g2.wy, F2);
        }
        // E pack: slots 0-11 = features, slot 12 = idf, 13-15 = 0
        union H8 { half8 v; h2 p[4]; } e0u, e1u;
        e0u.p[0] = F0[0]; e0u.p[1] = F0[1]; e0u.p[2] = F1[0]; e0u.p[3] = F1[1];
        e1u.p[0] = F2[0]; e1u.p[1] = F2[1];
        e1u.p[2] = pk2(cidf, 0.0f); e1u.p[3] = pk2(0.0f, 0.0f);
        *(half8*)&smem[ewr0] = e0u.v;
        *(half8*)&smem[ewr1] = e1u.v;

        // ---- layer 1: K=32 (quads 2-3 feed zeros), bias in C-init ----
        #pragma unroll
        for (int mt = 0; mt < 4; ++mt) {
            half8 ea = { (_Float16)0, (_Float16)0, (_Float16)0, (_Float16)0,
                         (_Float16)0, (_Float16)0, (_Float16)0, (_Float16)0 };
            if (quad < 2) ea = *(const half8*)&smem[erd + mt * 1024];
            floatx4 acc[4];
            #pragma unroll
            for (int nt = 0; nt < 4; ++nt) {
                acc[nt] = (floatx4){ b1v[nt], b1v[nt], b1v[nt], b1v[nt] };
                acc[nt] = __builtin_amdgcn_mfma_f32_16x16x32_f16(ea, w1f[nt], acc[nt], 0, 0, 0);
            }
            #pragma unroll
            for (int r = 0; r < 4; ++r)
                *(half4*)&smem[hwb[r] + mt * 1024] =
                    relu_pk4(acc[0][r], acc[1][r], acc[2][r], acc[3][r]);
        }

        // ---- layer 2 (K=64): w2 frags reloaded phase-locally from LDS ----
        half8 w2r[4][2];
        #pragma unroll
        for (int nt = 0; nt < 4; ++nt)
            #pragma unroll
            for (int ks = 0; ks < 2; ++ks)
                w2r[nt][ks] = *(const half8*)&w2l[nt * 1024 + w2a[ks]];
        #pragma unroll
        for (int mt = 0; mt < 4; ++mt) {
            floatx4 acc[4];
            #pragma unroll
            for (int nt = 0; nt < 4; ++nt)
                acc[nt] = (floatx4){ b2v[nt], b2v[nt], b2v[nt], b2v[nt] };
            #pragma unroll
            for (int ks = 0; ks < 2; ++ks) {
                half8 a2 = *(const half8*)&smem[rd2[ks] + mt * 1024];
                #pragma unroll
                for (int nt = 0; nt < 4; ++nt)
                    acc[nt] = __builtin_amdgcn_mfma_f32_16x16x32_f16(a2, w2r[nt][ks], acc[nt], 0, 0, 0);
            }
            #pragma unroll
            for (int r = 0; r < 4; ++r)
                *(half4*)&smem[hwb[r] + mt * 1024] =
                    relu_pk4(acc[0][r], acc[1][r], acc[2][r], acc[3][r]);
        }

        // ---- layer 3 (transposed) ----
        #pragma unroll
        for (int mt = 0; mt < 4; ++mt) {
            floatx4 acc3 = (floatx4){ qb30, qb31, qb32, 0.0f };
            #pragma unroll
            for (int ks = 0; ks < 2; ++ks) {
                half8 bfr = *(const half8*)&smem[rd2[ks] + mt * 1024];
                acc3 = __builtin_amdgcn_mfma_f32_16x16x32_f16(w3f[ks], bfr, acc3, 0, 0, 0);
            }
            if (quad == 0) {
                const int P = (tile << 8) + (wv << 6) + mt * 16 + l15;
                out[3 * P + 0] = acc3[0];
                out[3 * P + 1] = acc3[1];
                out[3 * P + 2] = acc3[2];
            }
        }

        // ---- rotate pipeline registers ----
        cidf = nidf; cu = nu; cv = nv;
        nidf = fidf; nu = fu; nv = fv;
        wx0 = nwx0; wy0 = nwy0; wx1 = nwx1; wy1 = nwy1;
        t0a = m0a; t0b = m0b; t1a = m1a; t1b = m1b;
    }
}

// ---- fallback (validated round-3 kernel, float4 gathers) for tiny ws ----
__global__ __launch_bounds__(TPB, 3) void dgn_mfma_fb(
    const float*  __restrict__ x,
    const float4* __restrict__ emb0,
    const float4* __restrict__ emb1,
    const float4* __restrict__ emb2,
    const float*  __restrict__ w1, const float* __restrict__ b1,
    const float*  __restrict__ w2, const float* __restrict__ b2,
    const float*  __restrict__ w3, const float* __restrict__ b3,
    float*        __restrict__ out, int npts)
{
    __shared__ __align__(16) _Float16 smem[4 * 4096];
    __shared__ __align__(16) _Float16 w2l[4096];

    const int tid  = threadIdx.x;
    const int lane = tid & 63;
    const int wv   = tid >> 6;
    const int l15  = lane & 15;
    const int quad = lane >> 4;

    for (int e = tid; e < 4096; e += TPB) {
        int nt = e >> 10, rem = e & 1023, lw = rem >> 6, s = rem & 63;
        int oh = ((s & 3) << 4) | (s >> 2);
        w2l[nt * 1024 + lw * 64 + (s ^ ((lw & 7) << 3))] =
            (_Float16)w2[oh * 64 + nt * 16 + lw];
    }
    __syncthreads();

    half8 w1f[4];
    #pragma unroll
    for (int nt = 0; nt < 4; ++nt)
        #pragma unroll
        for (int j = 0; j < 8; ++j) {
            int k = quad * 8 + j;
            w1f[nt][j] = (k < 13) ? (_Float16)w1[k * 64 + nt * 16 + l15] : (_Float16)0.0f;
        }
    float b1v[4], b2v[4];
    #pragma unroll
    for (int nt = 0; nt < 4; ++nt) { b1v[nt] = b1[nt * 16 + l15]; b2v[nt] = b2[nt * 16 + l15]; }
    half8 w3f[2];
    #pragma unroll
    for (int ks = 0; ks < 2; ++ks)
        #pragma unroll
        for (int j = 0; j < 8; ++j) {
            int s  = ks * 32 + quad * 8 + j;
            int oh = ((s & 3) << 4) | (s >> 2);
            w3f[ks][j] = (l15 < 3) ? (_Float16)w3[oh * 3 + l15] : (_Float16)0.0f;
        }
    const float qsel = (quad == 0) ? 1.0f : 0.0f;
    const float qb30 = qsel * b3[0], qb31 = qsel * b3[1], qb32 = qsel * b3[2];

    const int bufh = wv * 4096;
    const int ewr0 = bufh + lane * 64 + ((lane & 7) ^ 0) * 8;
    const int ewr1 = bufh + lane * 64 + ((lane & 7) ^ 1) * 8;
    const int erd  = bufh + l15 * 64 + (quad ^ (l15 & 7)) * 8;
    int hwb[4];
    #pragma unroll
    for (int r = 0; r < 4; ++r) {
        int pr = quad * 4 + r;
        hwb[r] = bufh + pr * 64 + (((l15 >> 1) ^ (pr & 7)) * 8) + (l15 & 1) * 4;
    }
    int rd2[2];
    #pragma unroll
    for (int ks = 0; ks < 2; ++ks)
        rd2[ks] = bufh + l15 * 64 + (((ks * 4 + quad) ^ (l15 & 7)) * 8);
    int w2a[2];
    #pragma unroll
    for (int ks = 0; ks < 2; ++ks)
        w2a[ks] = l15 * 64 + (((ks * 4 + quad) ^ (l15 & 7)) * 8);

    const int ntiles = npts >> 8;
    const int gdim   = gridDim.x;

    float cidf, cu, cv, wx0, wy0, wx1, wy1;
    float4 t00, t01, t02, t03, t10, t11, t12, t13;
    {
        int p0 = (blockIdx.x << 8) + (wv << 6) + lane;
        cidf = x[3 * p0]; cu = x[3 * p0 + 1]; cv = x[3 * p0 + 2];
        GAddr g0 = gaddr(512, cu, cv); wx0 = g0.wx; wy0 = g0.wy;
        t00 = emb0[g0.i00]; t01 = emb0[g0.i10]; t02 = emb0[g0.i01]; t03 = emb0[g0.i11];
        GAddr g1 = gaddr(264, cu, cv); wx1 = g1.wx; wy1 = g1.wy;
        t10 = emb1[g1.i00]; t11 = emb1[g1.i10]; t12 = emb1[g1.i01]; t13 = emb1[g1.i11];
    }

    for (int tile = blockIdx.x; tile < ntiles; tile += gdim) {
        float f[12];
        bil4(t00, t01, t02, t03, wx0, wy0, f);
        bil4(t10, t11, t12, t13, wx1, wy1, f + 4);
        {
            GAddr g2 = gaddr(16, cu, cv);
            bil4(emb2[g2.i00], emb2[g2.i10], emb2[g2.i01], emb2[g2.i11], g2.wx, g2.wy, f + 8);
        }
        union H8 { half8 v; fp16x2 p[4]; } e0u, e1u;
        e0u.p[0] = __builtin_amdgcn_cvt_pkrtz(cidf, f[0]);
        e0u.p[1] = __builtin_amdgcn_cvt_pkrtz(f[1], f[2]);
        e0u.p[2] = __builtin_amdgcn_cvt_pkrtz(f[3], f[4]);
        e0u.p[3] = __builtin_amdgcn_cvt_pkrtz(f[5], f[6]);
        e1u.p[0] = __builtin_amdgcn_cvt_pkrtz(f[7], f[8]);
        e1u.p[1] = __builtin_amdgcn_cvt_pkrtz(f[9], f[10]);
        e1u.p[2] = __builtin_amdgcn_cvt_pkrtz(f[11], 0.0f);
        e1u.p[3] = __builtin_amdgcn_cvt_pkrtz(0.0f, 0.0f);
        *(half8*)&smem[ewr0] = e0u.v;
        *(half8*)&smem[ewr1] = e1u.v;

        int nxt = tile + gdim;
        int ptn = (((nxt < ntiles) ? nxt : tile) << 8) + (wv << 6) + lane;
        float nidf = x[3 * ptn], nu = x[3 * ptn + 1], nv = x[3 * ptn + 2];

        #pragma unroll
        for (int mt = 0; mt < 4; ++mt) {
            half8 ea = { (_Float16)0, (_Float16)0, (_Float16)0, (_Float16)0,
                         (_Float16)0, (_Float16)0, (_Float16)0, (_Float16)0 };
            if (quad < 2) ea = *(const half8*)&smem[erd + mt * 1024];
            floatx4 acc[4];
            #pragma unroll
            for (int nt = 0; nt < 4; ++nt) {
                acc[nt] = (floatx4){ b1v[nt], b1v[nt], b1v[nt], b1v[nt] };
                acc[nt] = __builtin_amdgcn_mfma_f32_16x16x32_f16(ea, w1f[nt], acc[nt], 0, 0, 0);
            }
            #pragma unroll
            for (int r = 0; r < 4; ++r)
                *(half4*)&smem[hwb[r] + mt * 1024] =
                    relu_pk4f(acc[0][r], acc[1][r], acc[2][r], acc[3][r]);
        }

        float nwx0, nwy0, nwx1, nwy1;
        float4 n00, n01, n02, n03, n10, n11, n12, n13;
        {
            GAddr g0 = gaddr(512, nu, nv); nwx0 = g0.wx; nwy0 = g0.wy;
            n00 = emb0[g0.i00]; n01 = emb0[g0.i10]; n02 = emb0[g0.i01]; n03 = emb0[g0.i11];
            GAddr g1 = gaddr(264, nu, nv); nwx1 = g1.wx; nwy1 = g1.wy;
            n10 = emb1[g1.i00]; n11 = emb1[g1.i10]; n12 = emb1[g1.i01]; n13 = emb1[g1.i11];
        }

        half8 w2r[4][2];
        #pragma unroll
        for (int nt = 0; nt < 4; ++nt)
            #pragma unroll
            for (int ks = 0; ks < 2; ++ks)
                w2r[nt][ks] = *(const half8*)&w2l[nt * 1024 + w2a[ks]];
        #pragma unroll
        for (int mt = 0; mt < 4; ++mt) {
            floatx4 acc[4];
            #pragma unroll
            for (int nt = 0; nt < 4; ++nt)
                acc[nt] = (floatx4){ b2v[nt], b2v[nt], b2v[nt], b2v[nt] };
            #pragma unroll
            for (int ks = 0; ks < 2; ++ks) {
                half8 a2 = *(const half8*)&smem[rd2[ks] + mt * 1024];
                #pragma unroll
                for (int nt = 0; nt < 4; ++nt)
                    acc[nt] = __builtin_amdgcn_mfma_f32_16x16x32_f16(a2, w2r[nt][ks], acc[nt], 0, 0, 0);
            }
            #pragma unroll
            for (int r = 0; r < 4; ++r)
                *(half4*)&smem[hwb[r] + mt * 1024] =
                    relu_pk4f(acc[0][r], acc[1][r], acc[2][r], acc[3][r]);
        }

        #pragma unroll
        for (int mt = 0; mt < 4; ++mt) {
            floatx4 acc3 = (floatx4){ qb30, qb31, qb32, 0.0f };
            #pragma unroll
            for (int ks = 0; ks < 2; ++ks) {
                half8 bfr = *(const half8*)&smem[rd2[ks] + mt * 1024];
                acc3 = __builtin_amdgcn_mfma_f32_16x16x32_f16(w3f[ks], bfr, acc3, 0, 0, 0);
            }
            if (quad == 0) {
                const int P = (tile << 8) + (wv << 6) + mt * 16 + l15;
                out[3 * P + 0] = acc3[0];
                out[3 * P + 1] = acc3[1];
                out[3 * P + 2] = acc3[2];
            }
        }

        cidf = nidf; cu = nu; cv = nv;
        wx0 = nwx0; wy0 = nwy0; wx1 = nwx1; wy1 = nwy1;
        t00 = n00; t01 = n01; t02 = n02; t03 = n03;
        t10 = n10; t11 = n11; t12 = n12; t13 = n13;
    }
}

extern "C" void kernel_launch(void* const* d_in, const int* in_sizes, int n_in,
                              void* d_out, int out_size, void* d_ws, size_t ws_size,
                              hipStream_t stream) {
    const float*  x    = (const float*)  d_in[0];
    const float4* emb0 = (const float4*) d_in[1];
    const float4* emb1 = (const float4*) d_in[2];
    const float4* emb2 = (const float4*) d_in[3];
    const float*  w1   = (const float*)  d_in[4];
    const float*  b1   = (const float*)  d_in[5];
    const float*  w2   = (const float*)  d_in[6];
    const float*  b2   = (const float*)  d_in[7];
    const float*  w3   = (const float*)  d_in[8];
    const float*  b3   = (const float*)  d_in[9];
    float* out = (float*)d_out;

    int npts = in_sizes[0] / 3;
    const size_t need = (size_t)(NC0 + NC1 + NC2) * 32;   // 10.6 MB quad tables

    if (d_ws != nullptr && ws_size >= need) {
        int cells = NC0 + NC1 + NC2;
        pack_tables<<<(cells + 255) / 256, 256, 0, stream>>>(emb0, emb1, emb2, (half8*)d_ws);
        dgn_mfma<<<768, TPB, 0, stream>>>(x, (const half8*)d_ws,
                                          w1, b1, w2, b2, w3, b3, out, npts);
    } else {
        dgn_mfma_fb<<<768, TPB, 0, stream>>>(x, emb0, emb1, emb2,
                                             w1, b1, w2, b2, w3, b3, out, npts);
    }
}

// Round 10
// 212.896 us; speedup vs baseline: 1.4016x; 1.0190x over previous
//
#include <hip/hip_runtime.h>

typedef _Float16 half8 __attribute__((ext_vector_type(8)));
typedef _Float16 half4 __attribute__((ext_vector_type(4)));
typedef _Float16 h2    __attribute__((ext_vector_type(2)));
typedef __fp16  fp16x2 __attribute__((ext_vector_type(2)));
typedef float floatx4 __attribute__((ext_vector_type(4)));

#define TPB 256

// ---- fp16 flat-table geometry (r10): entry = 4 halves = 8B, indexed like the
// reference tab[y*res+x] (stride res). Corners are ADJACENT PAIRS:
//   {v00,v10} = entries c, c+1   -> one 16B load
//   {v01,v11} = entries c+res, c+res+1 -> one 16B load
// Same 2 requests/point/table as the r4 quad layout, but 4x smaller:
// emb0 2.1MB + emb1 0.56MB < 4MB per-XCD L2 -> gathers become L2 HITS.
#define N0E (512 * 513 + 2)      // max accessed index 512*513 -> +2 pad
#define N1E (264 * 265 + 2)      // max accessed index 264*265 -> +2 pad
#define NC2 (16 * 16)            // emb2 quad cells (stays in LDS)

struct GAddr { int i00, i10, i01, i11; float wx, wy; };

__device__ __forceinline__ GAddr gaddr(int res, float u, float v) {
    float r = (float)res;
    float sx = u * r, sy = v * r;
    int x0 = (int)sx, y0 = (int)sy;            // truncation, matches astype(int32)
    float wx = sx - (float)x0, wy = sy - (float)y0;
    int x1 = min(x0 + 1, res), y1 = min(y0 + 1, res);
    GAddr g;
    g.i00 = y0 * res + x0;  g.i10 = y0 * res + x1;   // reference stride = res
    g.i01 = y1 * res + x0;  g.i11 = y1 * res + x1;
    g.wx = wx; g.wy = wy;
    return g;
}

struct GQ { int c; float wx, wy; };

__device__ __forceinline__ GQ gq(int res, float u, float v) {
    float r = (float)res;
    float sx = u * r, sy = v * r;
    int x0 = (int)sx, y0 = (int)sy;
    GQ g; g.c = y0 * res + x0; g.wx = sx - (float)x0; g.wy = sy - (float)y0;
    return g;
}

__device__ __forceinline__ void bil4(float4 v00, float4 v10, float4 v01, float4 v11,
                                     float wx, float wy, float* f) {
    float omx = 1.0f - wx, omy = 1.0f - wy;
    f[0] = (v00.x * omx + v10.x * wx) * omy + (v01.x * omx + v11.x * wx) * wy;
    f[1] = (v00.y * omx + v10.y * wx) * omy + (v01.y * omx + v11.y * wx) * wy;
    f[2] = (v00.z * omx + v10.z * wx) * omy + (v01.z * omx + v11.z * wx) * wy;
    f[3] = (v00.w * omx + v10.w * wx) * omy + (v01.w * omx + v11.w * wx) * wy;
}

__device__ __forceinline__ h2 pk2(float a, float b) {
    fp16x2 r = __builtin_amdgcn_cvt_pkrtz(a, b);
    union { fp16x2 f; h2 h; } u; u.f = r; return u.h;
}

// packed-fp16 bilinear on {v00[4],v10[4]} (q0) and {v01[4],v11[4]} (q1).
__device__ __forceinline__ void bilq(half8 q0, half8 q1, float wx, float wy, h2* f) {
    h2 wx2  = pk2(wx, wx),           wy2  = pk2(wy, wy);
    h2 omx2 = pk2(1.f - wx, 1.f - wx), omy2 = pk2(1.f - wy, 1.f - wy);
    union { half8 v; h2 p[4]; } a, b;
    a.v = q0; b.v = q1;
    h2 t0 = a.p[0] * omx2 + a.p[2] * wx2;
    h2 t1 = a.p[1] * omx2 + a.p[3] * wx2;
    h2 c0 = b.p[0] * omx2 + b.p[2] * wx2;
    h2 c1 = b.p[1] * omx2 + b.p[3] * wx2;
    f[0] = t0 * omy2 + c0 * wy2;
    f[1] = t1 * omy2 + c1 * wy2;
}

// packed relu: cvt first, then v_pk_max_f16 vs 0.
__device__ __forceinline__ half4 relu_pk4(float a, float b, float c, float d) {
    union { half4 v; h2 p[2]; } u;
    u.p[0] = pk2(a, b);
    u.p[1] = pk2(c, d);
    half4 z = {(_Float16)0, (_Float16)0, (_Float16)0, (_Float16)0};
    return __builtin_elementwise_max(u.v, z);
}

// f32 relu variant for the fallback kernel (kept identical to validated r3).
__device__ __forceinline__ half4 relu_pk4f(float a, float b, float c, float d) {
    union { half4 v; fp16x2 p[2]; } u;
    u.p[0] = __builtin_amdgcn_cvt_pkrtz(fmaxf(a, 0.0f), fmaxf(b, 0.0f));
    u.p[1] = __builtin_amdgcn_cvt_pkrtz(fmaxf(c, 0.0f), fmaxf(d, 0.0f));
    return u.v;
}

// ---- per-launch pack: fp16 flat tables for emb0/emb1 + 8KB emb2 quad table.
// ws layout (halves): [0, N0E*4) tab0 | [N0E*4, (N0E+N1E)*4) tab1 | quad2 (8KB)
__global__ void pack_tables(const float4* __restrict__ e0,
                            const float4* __restrict__ e1,
                            const float4* __restrict__ e2,
                            _Float16* __restrict__ w)
{
    int i = blockIdx.x * blockDim.x + threadIdx.x;
    if (i < N0E) {
        float4 A = e0[i];                       // i <= 262657 < 513^2 ok
        half4* d = (half4*)(w + (size_t)i * 4);
        union { half4 v; h2 p[2]; } u;
        u.p[0] = pk2(A.x, A.y); u.p[1] = pk2(A.z, A.w);
        *d = u.v;
    } else if (i < N0E + N1E) {
        int c = i - N0E;                        // c <= 69961 < 265^2 ok
        float4 A = e1[c];
        half4* d = (half4*)(w + (size_t)(N0E + c) * 4);
        union { half4 v; h2 p[2]; } u;
        u.p[0] = pk2(A.x, A.y); u.p[1] = pk2(A.z, A.w);
        *d = u.v;
    } else if (i < N0E + N1E + NC2) {
        int c = i - N0E - N1E;                  // emb2 quad cell, res=16
        float4 A = e2[c], B = e2[c + 1], C = e2[c + 16], D = e2[c + 17];
        half8* q = (half8*)(w + (size_t)(N0E + N1E) * 4);
        union { half8 v; h2 p[4]; } u0, u1;
        u0.p[0] = pk2(A.x, A.y); u0.p[1] = pk2(A.z, A.w);
        u0.p[2] = pk2(B.x, B.y); u0.p[3] = pk2(B.z, B.w);
        u1.p[0] = pk2(C.x, C.y); u1.p[1] = pk2(C.z, C.w);
        u1.p[2] = pk2(D.x, D.y); u1.p[3] = pk2(D.z, D.w);
        q[2 * c]     = u0.v;
        q[2 * c + 1] = u1.v;
    }
}

// Session ledger: the ONLY lever that moved time was fewer/narrower memory
// requests (r4: -34%). Occupancy (r1/r3), VALU (r8), x-latency (r8), and
// gather-issue placement (r9) were all null. r9's FETCH=316MB decomposes as
// 50MB x + ~260MB ~= 64B x 4.2M points: EVERY emb0 gather missed L2, because
// the quad table (8.4MB) thrashes the 4MB per-XCD L2. r10: fp16 flat tables
// (adjacent-pair corners, same 2 reqs/point/table, 4x smaller) -> emb0+emb1 =
// 2.7MB, L2-RESIDENT. Misses -> hits; FETCH should collapse to ~100MB.
__global__ __launch_bounds__(TPB, 3) void dgn_mfma(
    const float*    __restrict__ x,
    const _Float16* __restrict__ tabs,
    const float*  __restrict__ w1, const float* __restrict__ b1,
    const float*  __restrict__ w2, const float* __restrict__ b2,
    const float*  __restrict__ w3, const float* __restrict__ b3,
    float*        __restrict__ out, int npts)
{
    __shared__ __align__(16) _Float16 smem[4 * 4096];   // 4 waves * 8KB, wave-private
    __shared__ __align__(16) _Float16 w2l[4096];        // 8KB shared w2 fragments
    __shared__ __align__(16) _Float16 e2l[4096];        // 8KB emb2 quad table

    const _Float16* t0h = tabs;
    const _Float16* t1h = tabs + (size_t)N0E * 4;
    const half8*    q2t = (const half8*)(tabs + (size_t)(N0E + N1E) * 4);

    const int tid  = threadIdx.x;
    const int lane = tid & 63;
    const int wv   = tid >> 6;
    const int l15  = lane & 15;
    const int quad = lane >> 4;

    // ---- one-time staging: w2 fragments (swizzled) + emb2 quad table ----
    for (int e = tid; e < 4096; e += TPB) {
        int nt = e >> 10, rem = e & 1023, lw = rem >> 6, s = rem & 63;
        int oh = ((s & 3) << 4) | (s >> 2);             // sigma^{-1}
        w2l[nt * 1024 + lw * 64 + (s ^ ((lw & 7) << 3))] =
            (_Float16)w2[oh * 64 + nt * 16 + lw];
    }
    for (int e = tid; e < 2 * NC2; e += TPB)            // 512 x half8 = 8KB
        ((half8*)e2l)[e] = q2t[e];
    __syncthreads();

    // ---- persistent weight fragments. w1 K-permutation: slot k<12 -> row k+1
    // (features), slot 12 -> row 0 (idf), slots 13-15 -> zero. ----
    half8 w1f[4];
    #pragma unroll
    for (int nt = 0; nt < 4; ++nt)
        #pragma unroll
        for (int j = 0; j < 8; ++j) {
            int k = quad * 8 + j;
            int row = (k < 12) ? (k + 1) : ((k == 12) ? 0 : -1);
            w1f[nt][j] = (row >= 0) ? (_Float16)w1[row * 64 + nt * 16 + l15] : (_Float16)0.0f;
        }
    float b1v[4], b2v[4];
    #pragma unroll
    for (int nt = 0; nt < 4; ++nt) { b1v[nt] = b1[nt * 16 + l15]; b2v[nt] = b2[nt * 16 + l15]; }
    half8 w3f[2];
    #pragma unroll
    for (int ks = 0; ks < 2; ++ks)
        #pragma unroll
        for (int j = 0; j < 8; ++j) {
            int s  = ks * 32 + quad * 8 + j;
            int oh = ((s & 3) << 4) | (s >> 2);
            w3f[ks][j] = (l15 < 3) ? (_Float16)w3[oh * 3 + l15] : (_Float16)0.0f;
        }
    const float qsel = (quad == 0) ? 1.0f : 0.0f;
    const float qb30 = qsel * b3[0], qb31 = qsel * b3[1], qb32 = qsel * b3[2];

    // ---- precomputed LDS addresses (half-element units) ----
    const int bufh = wv * 4096;
    const int ewr0 = bufh + lane * 64 + ((lane & 7) ^ 0) * 8;
    const int ewr1 = bufh + lane * 64 + ((lane & 7) ^ 1) * 8;
    const int erd  = bufh + l15 * 64 + (quad ^ (l15 & 7)) * 8;          // quad<2 only
    int hwb[4];
    #pragma unroll
    for (int r = 0; r < 4; ++r) {
        int pr = quad * 4 + r;
        hwb[r] = bufh + pr * 64 + (((l15 >> 1) ^ (pr & 7)) * 8) + (l15 & 1) * 4;
    }
    int rd2[2];
    #pragma unroll
    for (int ks = 0; ks < 2; ++ks)
        rd2[ks] = bufh + l15 * 64 + (((ks * 4 + quad) ^ (l15 & 7)) * 8);
    int w2a[2];
    #pragma unroll
    for (int ks = 0; ks < 2; ++ks)
        w2a[ks] = l15 * 64 + (((ks * 4 + quad) ^ (l15 & 7)) * 8);

    const int ntiles = npts >> 8;
    const int gdim   = gridDim.x;

    // ---- prologue: x[t0] and x[t0+g] loaded; tile-0 gathers in flight ----
    float cidf, cu, cv;            // x of current tile
    float nidf, nu, nv;            // x of next tile (2-deep pipeline)
    float wx0, wy0, wx1, wy1;
    half8 t0a, t0b, t1a, t1b;
    {
        int p0 = (blockIdx.x << 8) + (wv << 6) + lane;
        cidf = x[3 * p0]; cu = x[3 * p0 + 1]; cv = x[3 * p0 + 2];
        int tn = blockIdx.x + gdim;
        int p1 = (((tn < ntiles) ? tn : blockIdx.x) << 8) + (wv << 6) + lane;
        nidf = x[3 * p1]; nu = x[3 * p1 + 1]; nv = x[3 * p1 + 2];
        GQ g0 = gq(512, cu, cv); wx0 = g0.wx; wy0 = g0.wy;
        t0a = *(const half8*)&t0h[4 * g0.c];
        t0b = *(const half8*)&t0h[4 * (g0.c + 512)];
        GQ g1 = gq(264, cu, cv); wx1 = g1.wx; wy1 = g1.wy;
        t1a = *(const half8*)&t1h[4 * g1.c];
        t1b = *(const half8*)&t1h[4 * (g1.c + 264)];
    }

    for (int tile = blockIdx.x; tile < ntiles; tile += gdim) {
        // ---- 1. issue NEXT tile's emb0/emb1 gathers at the very top ----
        float nwx0, nwy0, nwx1, nwy1;
        half8 m0a, m0b, m1a, m1b;
        {
            GQ g0 = gq(512, nu, nv); nwx0 = g0.wx; nwy0 = g0.wy;
            m0a = *(const half8*)&t0h[4 * g0.c];
            m0b = *(const half8*)&t0h[4 * (g0.c + 512)];
            GQ g1 = gq(264, nu, nv); nwx1 = g1.wx; nwy1 = g1.wy;
            m1a = *(const half8*)&t1h[4 * g1.c];
            m1b = *(const half8*)&t1h[4 * (g1.c + 264)];
        }

        // ---- 2. issue x load for tile+2 (consumed next iteration) ----
        int nxt2 = tile + 2 * gdim;
        int ptn = (((nxt2 < ntiles) ? nxt2 : tile) << 8) + (wv << 6) + lane;
        float fidf = x[3 * ptn], fu = x[3 * ptn + 1], fv = x[3 * ptn + 2];

        // ---- 3. finish current tile's features (emb2 from LDS) ----
        h2 F0[2], F1[2], F2[2];
        bilq(t0a, t0b, wx0, wy0, F0);
        bilq(t1a, t1b, wx1, wy1, F1);
        {
            GQ g2 = gq(16, cu, cv);
            half8 qa = *(const half8*)&e2l[g2.c * 16];
            half8 qb = *(const half8*)&e2l[g2.c * 16 + 8];
            bilq(qa, qb, g2.wx, g2.wy, F2);
        }
        // E pack: slots 0-11 = features, slot 12 = idf, 13-15 = 0
        union H8 { half8 v; h2 p[4]; } e0u, e1u;
        e0u.p[0] = F0[0]; e0u.p[1] = F0[1]; e0u.p[2] = F1[0]; e0u.p[3] = F1[1];
        e1u.p[0] = F2[0]; e1u.p[1] = F2[1];
        e1u.p[2] = pk2(cidf, 0.0f); e1u.p[3] = pk2(0.0f, 0.0f);
        *(half8*)&smem[ewr0] = e0u.v;
        *(half8*)&smem[ewr1] = e1u.v;

        // ---- layer 1: K=32 (quads 2-3 feed zeros), bias in C-init ----
        #pragma unroll
        for (int mt = 0; mt < 4; ++mt) {
            half8 ea = { (_Float16)0, (_Float16)0, (_Float16)0, (_Float16)0,
                         (_Float16)0, (_Float16)0, (_Float16)0, (_Float16)0 };
            if (quad < 2) ea = *(const half8*)&smem[erd + mt * 1024];
            floatx4 acc[4];
            #pragma unroll
            for (int nt = 0; nt < 4; ++nt) {
                acc[nt] = (floatx4){ b1v[nt], b1v[nt], b1v[nt], b1v[nt] };
                acc[nt] = __builtin_amdgcn_mfma_f32_16x16x32_f16(ea, w1f[nt], acc[nt], 0, 0, 0);
            }
            #pragma unroll
            for (int r = 0; r < 4; ++r)
                *(half4*)&smem[hwb[r] + mt * 1024] =
                    relu_pk4(acc[0][r], acc[1][r], acc[2][r], acc[3][r]);
        }

        // ---- layer 2 (K=64): w2 frags reloaded phase-locally from LDS ----
        half8 w2r[4][2];
        #pragma unroll
        for (int nt = 0; nt < 4; ++nt)
            #pragma unroll
            for (int ks = 0; ks < 2; ++ks)
                w2r[nt][ks] = *(const half8*)&w2l[nt * 1024 + w2a[ks]];
        #pragma unroll
        for (int mt = 0; mt < 4; ++mt) {
            floatx4 acc[4];
            #pragma unroll
            for (int nt = 0; nt < 4; ++nt)
                acc[nt] = (floatx4){ b2v[nt], b2v[nt], b2v[nt], b2v[nt] };
            #pragma unroll
            for (int ks = 0; ks < 2; ++ks) {
                half8 a2 = *(const half8*)&smem[rd2[ks] + mt * 1024];
                #pragma unroll
                for (int nt = 0; nt < 4; ++nt)
                    acc[nt] = __builtin_amdgcn_mfma_f32_16x16x32_f16(a2, w2r[nt][ks], acc[nt], 0, 0, 0);
            }
            #pragma unroll
            for (int r = 0; r < 4; ++r)
                *(half4*)&smem[hwb[r] + mt * 1024] =
                    relu_pk4(acc[0][r], acc[1][r], acc[2][r], acc[3][r]);
        }

        // ---- layer 3 (transposed) ----
        #pragma unroll
        for (int mt = 0; mt < 4; ++mt) {
            floatx4 acc3 = (floatx4){ qb30, qb31, qb32, 0.0f };
            #pragma unroll
            for (int ks = 0; ks < 2; ++ks) {
                half8 bfr = *(const half8*)&smem[rd2[ks] + mt * 1024];
                acc3 = __builtin_amdgcn_mfma_f32_16x16x32_f16(w3f[ks], bfr, acc3, 0, 0, 0);
            }
            if (quad == 0) {
                const int P = (tile << 8) + (wv << 6) + mt * 16 + l15;
                out[3 * P + 0] = acc3[0];
                out[3 * P + 1] = acc3[1];
                out[3 * P + 2] = acc3[2];
            }
        }

        // ---- rotate pipeline registers ----
        cidf = nidf; cu = nu; cv = nv;
        nidf = fidf; nu = fu; nv = fv;
        wx0 = nwx0; wy0 = nwy0; wx1 = nwx1; wy1 = nwy1;
        t0a = m0a; t0b = m0b; t1a = m1a; t1b = m1b;
    }
}

// ---- fallback (validated round-3 kernel, float4 gathers) for tiny ws ----
__global__ __launch_bounds__(TPB, 3) void dgn_mfma_fb(
    const float*  __restrict__ x,
    const float4* __restrict__ emb0,
    const float4* __restrict__ emb1,
    const float4* __restrict__ emb2,
    const float*  __restrict__ w1, const float* __restrict__ b1,
    const float*  __restrict__ w2, const float* __restrict__ b2,
    const float*  __restrict__ w3, const float* __restrict__ b3,
    float*        __restrict__ out, int npts)
{
    __shared__ __align__(16) _Float16 smem[4 * 4096];
    __shared__ __align__(16) _Float16 w2l[4096];

    const int tid  = threadIdx.x;
    const int lane = tid & 63;
    const int wv   = tid >> 6;
    const int l15  = lane & 15;
    const int quad = lane >> 4;

    for (int e = tid; e < 4096; e += TPB) {
        int nt = e >> 10, rem = e & 1023, lw = rem >> 6, s = rem & 63;
        int oh = ((s & 3) << 4) | (s >> 2);
        w2l[nt * 1024 + lw * 64 + (s ^ ((lw & 7) << 3))] =
            (_Float16)w2[oh * 64 + nt * 16 + lw];
    }
    __syncthreads();

    half8 w1f[4];
    #pragma unroll
    for (int nt = 0; nt < 4; ++nt)
        #pragma unroll
        for (int j = 0; j < 8; ++j) {
            int k = quad * 8 + j;
            w1f[nt][j] = (k < 13) ? (_Float16)w1[k * 64 + nt * 16 + l15] : (_Float16)0.0f;
        }
    float b1v[4], b2v[4];
    #pragma unroll
    for (int nt = 0; nt < 4; ++nt) { b1v[nt] = b1[nt * 16 + l15]; b2v[nt] = b2[nt * 16 + l15]; }
    half8 w3f[2];
    #pragma unroll
    for (int ks = 0; ks < 2; ++ks)
        #pragma unroll
        for (int j = 0; j < 8; ++j) {
            int s  = ks * 32 + quad * 8 + j;
            int oh = ((s & 3) << 4) | (s >> 2);
            w3f[ks][j] = (l15 < 3) ? (_Float16)w3[oh * 3 + l15] : (_Float16)0.0f;
        }
    const float qsel = (quad == 0) ? 1.0f : 0.0f;
    const float qb30 = qsel * b3[0], qb31 = qsel * b3[1], qb32 = qsel * b3[2];

    const int bufh = wv * 4096;
    const int ewr0 = bufh + lane * 64 + ((lane & 7) ^ 0) * 8;
    const int ewr1 = bufh + lane * 64 + ((lane & 7) ^ 1) * 8;
    const int erd  = bufh + l15 * 64 + (quad ^ (l15 & 7)) * 8;
    int hwb[4];
    #pragma unroll
    for (int r = 0; r < 4; ++r) {
        int pr = quad * 4 + r;
        hwb[r] = bufh + pr * 64 + (((l15 >> 1) ^ (pr & 7)) * 8) + (l15 & 1) * 4;
    }
    int rd2[2];
    #pragma unroll
    for (int ks = 0; ks < 2; ++ks)
        rd2[ks] = bufh + l15 * 64 + (((ks * 4 + quad) ^ (l15 & 7)) * 8);
    int w2a[2];
    #pragma unroll
    for (int ks = 0; ks < 2; ++ks)
        w2a[ks] = l15 * 64 + (((ks * 4 + quad) ^ (l15 & 7)) * 8);

    const int ntiles = npts >> 8;
    const int gdim   = gridDim.x;

    float cidf, cu, cv, wx0, wy0, wx1, wy1;
    float4 t00, t01, t02, t03, t10, t11, t12, t13;
    {
        int p0 = (blockIdx.x << 8) + (wv << 6) + lane;
        cidf = x[3 * p0]; cu = x[3 * p0 + 1]; cv = x[3 * p0 + 2];
        GAddr g0 = gaddr(512, cu, cv); wx0 = g0.wx; wy0 = g0.wy;
        t00 = emb0[g0.i00]; t01 = emb0[g0.i10]; t02 = emb0[g0.i01]; t03 = emb0[g0.i11];
        GAddr g1 = gaddr(264, cu, cv); wx1 = g1.wx; wy1 = g1.wy;
        t10 = emb1[g1.i00]; t11 = emb1[g1.i10]; t12 = emb1[g1.i01]; t13 = emb1[g1.i11];
    }

    for (int tile = blockIdx.x; tile < ntiles; tile += gdim) {
        float f[12];
        bil4(t00, t01, t02, t03, wx0, wy0, f);
        bil4(t10, t11, t12, t13, wx1, wy1, f + 4);
        {
            GAddr g2 = gaddr(16, cu, cv);
            bil4(emb2[g2.i00], emb2[g2.i10], emb2[g2.i01], emb2[g2.i11], g2.wx, g2.wy, f + 8);
        }
        union H8 { half8 v; fp16x2 p[4]; } e0u, e1u;
        e0u.p[0] = __builtin_amdgcn_cvt_pkrtz(cidf, f[0]);
        e0u.p[1] = __builtin_amdgcn_cvt_pkrtz(f[1], f[2]);
        e0u.p[2] = __builtin_amdgcn_cvt_pkrtz(f[3], f[4]);
        e0u.p[3] = __builtin_amdgcn_cvt_pkrtz(f[5], f[6]);
        e1u.p[0] = __builtin_amdgcn_cvt_pkrtz(f[7], f[8]);
        e1u.p[1] = __builtin_amdgcn_cvt_pkrtz(f[9], f[10]);
        e1u.p[2] = __builtin_amdgcn_cvt_pkrtz(f[11], 0.0f);
        e1u.p[3] = __builtin_amdgcn_cvt_pkrtz(0.0f, 0.0f);
        *(half8*)&smem[ewr0] = e0u.v;
        *(half8*)&smem[ewr1] = e1u.v;

        int nxt = tile + gdim;
        int ptn = (((nxt < ntiles) ? nxt : tile) << 8) + (wv << 6) + lane;
        float nidf = x[3 * ptn], nu = x[3 * ptn + 1], nv = x[3 * ptn + 2];

        #pragma unroll
        for (int mt = 0; mt < 4; ++mt) {
            half8 ea = { (_Float16)0, (_Float16)0, (_Float16)0, (_Float16)0,
                         (_Float16)0, (_Float16)0, (_Float16)0, (_Float16)0 };
            if (quad < 2) ea = *(const half8*)&smem[erd + mt * 1024];
            floatx4 acc[4];
            #pragma unroll
            for (int nt = 0; nt < 4; ++nt) {
                acc[nt] = (floatx4){ b1v[nt], b1v[nt], b1v[nt], b1v[nt] };
                acc[nt] = __builtin_amdgcn_mfma_f32_16x16x32_f16(ea, w1f[nt], acc[nt], 0, 0, 0);
            }
            #pragma unroll
            for (int r = 0; r < 4; ++r)
                *(half4*)&smem[hwb[r] + mt * 1024] =
                    relu_pk4f(acc[0][r], acc[1][r], acc[2][r], acc[3][r]);
        }

        float nwx0, nwy0, nwx1, nwy1;
        float4 n00, n01, n02, n03, n10, n11, n12, n13;
        {
            GAddr g0 = gaddr(512, nu, nv); nwx0 = g0.wx; nwy0 = g0.wy;
            n00 = emb0[g0.i00]; n01 = emb0[g0.i10]; n02 = emb0[g0.i01]; n03 = emb0[g0.i11];
            GAddr g1 = gaddr(264, nu, nv); nwx1 = g1.wx; nwy1 = g1.wy;
            n10 = emb1[g1.i00]; n11 = emb1[g1.i10]; n12 = emb1[g1.i01]; n13 = emb1[g1.i11];
        }

        half8 w2r[4][2];
        #pragma unroll
        for (int nt = 0; nt < 4; ++nt)
            #pragma unroll
            for (int ks = 0; ks < 2; ++ks)
                w2r[nt][ks] = *(const half8*)&w2l[nt * 1024 + w2a[ks]];
        #pragma unroll
        for (int mt = 0; mt < 4; ++mt) {
            floatx4 acc[4];
            #pragma unroll
            for (int nt = 0; nt < 4; ++nt)
                acc[nt] = (floatx4){ b2v[nt], b2v[nt], b2v[nt], b2v[nt] };
            #pragma unroll
            for (int ks = 0; ks < 2; ++ks) {
                half8 a2 = *(const half8*)&smem[rd2[ks] + mt * 1024];
                #pragma unroll
                for (int nt = 0; nt < 4; ++nt)
                    acc[nt] = __builtin_amdgcn_mfma_f32_16x16x32_f16(a2, w2r[nt][ks], acc[nt], 0, 0, 0);
            }
            #pragma unroll
            for (int r = 0; r < 4; ++r)
                *(half4*)&smem[hwb[r] + mt * 1024] =
                    relu_pk4f(acc[0][r], acc[1][r], acc[2][r], acc[3][r]);
        }

        #pragma unroll
        for (int mt = 0; mt < 4; ++mt) {
            floatx4 acc3 = (floatx4){ qb30, qb31, qb32, 0.0f };
            #pragma unroll
            for (int ks = 0; ks < 2; ++ks) {
                half8 bfr = *(const half8*)&smem[rd2[ks] + mt * 1024];
                acc3 = __builtin_amdgcn_mfma_f32_16x16x32_f16(w3f[ks], bfr, acc3, 0, 0, 0);
            }
            if (quad == 0) {
                const int P = (tile << 8) + (wv << 6) + mt * 16 + l15;
                out[3 * P + 0] = acc3[0];
                out[3 * P + 1] = acc3[1];
                out[3 * P + 2] = acc3[2];
            }
        }

        cidf = nidf; cu = nu; cv = nv;
        wx0 = nwx0; wy0 = nwy0; wx1 = nwx1; wy1 = nwy1;
        t00 = n00; t01 = n01; t02 = n02; t03 = n03;
        t10 = n10; t11 = n11; t12 = n12; t13 = n13;
    }
}

extern "C" void kernel_launch(void* const* d_in, const int* in_sizes, int n_in,
                              void* d_out, int out_size, void* d_ws, size_t ws_size,
                              hipStream_t stream) {
    const float*  x    = (const float*)  d_in[0];
    const float4* emb0 = (const float4*) d_in[1];
    const float4* emb1 = (const float4*) d_in[2];
    const float4* emb2 = (const float4*) d_in[3];
    const float*  w1   = (const float*)  d_in[4];
    const float*  b1   = (const float*)  d_in[5];
    const float*  w2   = (const float*)  d_in[6];
    const float*  b2   = (const float*)  d_in[7];
    const float*  w3   = (const float*)  d_in[8];
    const float*  b3   = (const float*)  d_in[9];
    float* out = (float*)d_out;

    int npts = in_sizes[0] / 3;
    const size_t need = (size_t)(N0E + N1E) * 8 + (size_t)NC2 * 32;   // ~2.7 MB

    if (d_ws != nullptr && ws_size >= need) {
        int work = N0E + N1E + NC2;
        pack_tables<<<(work + 255) / 256, 256, 0, stream>>>(emb0, emb1, emb2, (_Float16*)d_ws);
        dgn_mfma<<<768, TPB, 0, stream>>>(x, (const _Float16*)d_ws,
                                          w1, b1, w2, b2, w3, b3, out, npts);
    } else {
        dgn_mfma_fb<<<768, TPB, 0, stream>>>(x, emb0, emb1, emb2,
                                             w1, b1, w2, b2, w3, b3, out, npts);
    }
}

// Round 11
// 191.179 us; speedup vs baseline: 1.5608x; 1.1136x over previous
//
#include <hip/hip_runtime.h>

typedef _Float16 half8 __attribute__((ext_vector_type(8)));
typedef _Float16 half4 __attribute__((ext_vector_type(4)));
typedef _Float16 h2    __attribute__((ext_vector_type(2)));
typedef __fp16  fp16x2 __attribute__((ext_vector_type(2)));
typedef float floatx4 __attribute__((ext_vector_type(4)));
typedef float floatx2 __attribute__((ext_vector_type(2)));
typedef int   intx4  __attribute__((ext_vector_type(4)));
typedef intx4 intx4a __attribute__((aligned(8)));   // 8B-aligned 16B load

#define TPB 256
#define SCALE   8192.0f            // 2^13: lifts O(1e-4) table values into e4m3 range
#define INVSC   0.0001220703125f   // 2^-13, folded into bilinear y-weights (exact)

// ---- fp8 row-pair tables (r11): entry i = {tab[i], tab[i+res]} = 8B (2 dwords
// of 4x e4m3). Corners of cell c are P[c] (v00,v01) and P[c+1] (v10,v11),
// adjacent -> ONE 16B load per table per point (was 2). emb0 2.1MB + emb1
// 0.56MB stay L2-resident (r10 win preserved).
#define N0E (512 * 512 + 1)
#define N1E (264 * 264 + 1)
#define NC2 (16 * 16)              // emb2 quad cells (fp16, LDS)

struct GAddr { int i00, i10, i01, i11; float wx, wy; };

__device__ __forceinline__ GAddr gaddr(int res, float u, float v) {
    float r = (float)res;
    float sx = u * r, sy = v * r;
    int x0 = (int)sx, y0 = (int)sy;            // truncation, matches astype(int32)
    float wx = sx - (float)x0, wy = sy - (float)y0;
    int x1 = min(x0 + 1, res), y1 = min(y0 + 1, res);
    GAddr g;
    g.i00 = y0 * res + x0;  g.i10 = y0 * res + x1;   // reference stride = res
    g.i01 = y1 * res + x0;  g.i11 = y1 * res + x1;
    g.wx = wx; g.wy = wy;
    return g;
}

struct GQ { int c; float wx, wy; };

__device__ __forceinline__ GQ gq(int res, float u, float v) {
    float r = (float)res;
    float sx = u * r, sy = v * r;
    int x0 = (int)sx, y0 = (int)sy;
    GQ g; g.c = y0 * res + x0; g.wx = sx - (float)x0; g.wy = sy - (float)y0;
    return g;
}

__device__ __forceinline__ void bil4(float4 v00, float4 v10, float4 v01, float4 v11,
                                     float wx, float wy, float* f) {
    float omx = 1.0f - wx, omy = 1.0f - wy;
    f[0] = (v00.x * omx + v10.x * wx) * omy + (v01.x * omx + v11.x * wx) * wy;
    f[1] = (v00.y * omx + v10.y * wx) * omy + (v01.y * omx + v11.y * wx) * wy;
    f[2] = (v00.z * omx + v10.z * wx) * omy + (v01.z * omx + v11.z * wx) * wy;
    f[3] = (v00.w * omx + v10.w * wx) * omy + (v01.w * omx + v11.w * wx) * wy;
}

__device__ __forceinline__ h2 pk2(float a, float b) {
    fp16x2 r = __builtin_amdgcn_cvt_pkrtz(a, b);
    union { fp16x2 f; h2 h; } u; u.f = r; return u.h;
}

// fp8 quad decode + f32 bilinear. q = {v00,v01,v10,v11} dwords of 4x e4m3
// (scaled 2^13); omyS/wyS carry the exact 2^-13 down-scale.
__device__ __forceinline__ void bil8(intx4 q, float wx, float omyS, float wyS, float* f) {
    floatx2 a00 = __builtin_amdgcn_cvt_pk_f32_fp8(q.x, false);
    floatx2 b00 = __builtin_amdgcn_cvt_pk_f32_fp8(q.x, true);
    floatx2 a01 = __builtin_amdgcn_cvt_pk_f32_fp8(q.y, false);
    floatx2 b01 = __builtin_amdgcn_cvt_pk_f32_fp8(q.y, true);
    floatx2 a10 = __builtin_amdgcn_cvt_pk_f32_fp8(q.z, false);
    floatx2 b10 = __builtin_amdgcn_cvt_pk_f32_fp8(q.z, true);
    floatx2 a11 = __builtin_amdgcn_cvt_pk_f32_fp8(q.w, false);
    floatx2 b11 = __builtin_amdgcn_cvt_pk_f32_fp8(q.w, true);
    float omx = 1.0f - wx;
    f[0] = (a00[0] * omx + a10[0] * wx) * omyS + (a01[0] * omx + a11[0] * wx) * wyS;
    f[1] = (a00[1] * omx + a10[1] * wx) * omyS + (a01[1] * omx + a11[1] * wx) * wyS;
    f[2] = (b00[0] * omx + b10[0] * wx) * omyS + (b01[0] * omx + b11[0] * wx) * wyS;
    f[3] = (b00[1] * omx + b10[1] * wx) * omyS + (b01[1] * omx + b11[1] * wx) * wyS;
}

// packed-fp16 bilinear (emb2 LDS path, unchanged/unscaled)
__device__ __forceinline__ void bilq(half8 q0, half8 q1, float wx, float wy, h2* f) {
    h2 wx2  = pk2(wx, wx),           wy2  = pk2(wy, wy);
    h2 omx2 = pk2(1.f - wx, 1.f - wx), omy2 = pk2(1.f - wy, 1.f - wy);
    union { half8 v; h2 p[4]; } a, b;
    a.v = q0; b.v = q1;
    h2 t0 = a.p[0] * omx2 + a.p[2] * wx2;
    h2 t1 = a.p[1] * omx2 + a.p[3] * wx2;
    h2 c0 = b.p[0] * omx2 + b.p[2] * wx2;
    h2 c1 = b.p[1] * omx2 + b.p[3] * wx2;
    f[0] = t0 * omy2 + c0 * wy2;
    f[1] = t1 * omy2 + c1 * wy2;
}

// packed relu: cvt first, then v_pk_max_f16 vs 0.
__device__ __forceinline__ half4 relu_pk4(float a, float b, float c, float d) {
    union { half4 v; h2 p[2]; } u;
    u.p[0] = pk2(a, b);
    u.p[1] = pk2(c, d);
    half4 z = {(_Float16)0, (_Float16)0, (_Float16)0, (_Float16)0};
    return __builtin_elementwise_max(u.v, z);
}

// f32 relu variant for the fallback kernel (kept identical to validated r3).
__device__ __forceinline__ half4 relu_pk4f(float a, float b, float c, float d) {
    union { half4 v; fp16x2 p[2]; } u;
    u.p[0] = __builtin_amdgcn_cvt_pkrtz(fmaxf(a, 0.0f), fmaxf(b, 0.0f));
    u.p[1] = __builtin_amdgcn_cvt_pkrtz(fmaxf(c, 0.0f), fmaxf(d, 0.0f));
    return u.v;
}

// ---- per-launch pack. ws layout (ints): [0, 2*N0E) t0 rowpair | next 2*N1E
// t1 rowpair | emb2 fp16 quad (8KB). e4m3 encode via HW cvt_pk_fp8_f32.
__global__ void pack_tables(const float4* __restrict__ e0,
                            const float4* __restrict__ e1,
                            const float4* __restrict__ e2,
                            int* __restrict__ w)
{
    int i = blockIdx.x * blockDim.x + threadIdx.x;
    if (i < N0E) {
        float4 A = e0[i];                 // tab[i];       i+512 <= 262656 < 513^2
        float4 C = e0[i + 512];           // tab[i+res]
        int d0 = __builtin_amdgcn_cvt_pk_fp8_f32(A.x * SCALE, A.y * SCALE, 0, false);
        d0     = __builtin_amdgcn_cvt_pk_fp8_f32(A.z * SCALE, A.w * SCALE, d0, true);
        int d1 = __builtin_amdgcn_cvt_pk_fp8_f32(C.x * SCALE, C.y * SCALE, 0, false);
        d1     = __builtin_amdgcn_cvt_pk_fp8_f32(C.z * SCALE, C.w * SCALE, d1, true);
        w[2 * i] = d0; w[2 * i + 1] = d1;
    } else if (i < N0E + N1E) {
        int c = i - N0E;                  // c+264 <= 69960 < 265^2
        float4 A = e1[c];
        float4 C = e1[c + 264];
        int d0 = __builtin_amdgcn_cvt_pk_fp8_f32(A.x * SCALE, A.y * SCALE, 0, false);
        d0     = __builtin_amdgcn_cvt_pk_fp8_f32(A.z * SCALE, A.w * SCALE, d0, true);
        int d1 = __builtin_amdgcn_cvt_pk_fp8_f32(C.x * SCALE, C.y * SCALE, 0, false);
        d1     = __builtin_amdgcn_cvt_pk_fp8_f32(C.z * SCALE, C.w * SCALE, d1, true);
        w[2 * (N0E + c)] = d0; w[2 * (N0E + c) + 1] = d1;
    } else if (i < N0E + N1E + NC2) {
        int c = i - N0E - N1E;            // emb2 quad cell, res=16, fp16 UNscaled
        float4 A = e2[c], B = e2[c + 1], C = e2[c + 16], D = e2[c + 17];
        half8* q = (half8*)(w + 2 * (N0E + N1E));
        union { half8 v; h2 p[4]; } u0, u1;
        u0.p[0] = pk2(A.x, A.y); u0.p[1] = pk2(A.z, A.w);
        u0.p[2] = pk2(B.x, B.y); u0.p[3] = pk2(B.z, B.w);
        u1.p[0] = pk2(C.x, C.y); u1.p[1] = pk2(C.z, C.w);
        u1.p[2] = pk2(D.x, D.y); u1.p[3] = pk2(D.z, D.w);
        q[2 * c]     = u0.v;
        q[2 * c + 1] = u1.v;
    }
}

// Ledger r0-r10: only request/line reduction moved time (r4 -34%). r10 made
// tables L2-resident (FETCH 316->37MB) with NO dur change -> miss service was
// not the wall; the surviving theory is TA/TCP per-lane line-access
// throughput on divergent gathers (64-lane random gather ~ 64 serialized
// line accesses, hit or miss). r11: fp8 row-pair tables -> ONE 16B gather
// per table per point (was 2): instructions AND line-touches halve again.
// 2^13 pre-scale (e4m3 subnormal floor) undone exactly via y-weights.
__global__ __launch_bounds__(TPB, 3) void dgn_mfma(
    const float* __restrict__ x,
    const int2*  __restrict__ tabs,
    const float*  __restrict__ w1, const float* __restrict__ b1,
    const float*  __restrict__ w2, const float* __restrict__ b2,
    const float*  __restrict__ w3, const float* __restrict__ b3,
    float*        __restrict__ out, int npts)
{
    __shared__ __align__(16) _Float16 smem[4 * 4096];   // 4 waves * 8KB, wave-private
    __shared__ __align__(16) _Float16 w2l[4096];        // 8KB shared w2 fragments
    __shared__ __align__(16) _Float16 e2l[4096];        // 8KB emb2 quad table

    const int2*  p0  = tabs;
    const int2*  p1  = tabs + N0E;
    const half8* q2t = (const half8*)(tabs + N0E + N1E);

    const int tid  = threadIdx.x;
    const int lane = tid & 63;
    const int wv   = tid >> 6;
    const int l15  = lane & 15;
    const int quad = lane >> 4;

    // ---- one-time staging: w2 fragments (swizzled) + emb2 quad table ----
    for (int e = tid; e < 4096; e += TPB) {
        int nt = e >> 10, rem = e & 1023, lw = rem >> 6, s = rem & 63;
        int oh = ((s & 3) << 4) | (s >> 2);             // sigma^{-1}
        w2l[nt * 1024 + lw * 64 + (s ^ ((lw & 7) << 3))] =
            (_Float16)w2[oh * 64 + nt * 16 + lw];
    }
    for (int e = tid; e < 2 * NC2; e += TPB)            // 512 x half8 = 8KB
        ((half8*)e2l)[e] = q2t[e];
    __syncthreads();

    // ---- persistent weight fragments. w1 K-permutation: slot k<12 -> row k+1
    // (features), slot 12 -> row 0 (idf), slots 13-15 -> zero. ----
    half8 w1f[4];
    #pragma unroll
    for (int nt = 0; nt < 4; ++nt)
        #pragma unroll
        for (int j = 0; j < 8; ++j) {
            int k = quad * 8 + j;
            int row = (k < 12) ? (k + 1) : ((k == 12) ? 0 : -1);
            w1f[nt][j] = (row >= 0) ? (_Float16)w1[row * 64 + nt * 16 + l15] : (_Float16)0.0f;
        }
    float b1v[4], b2v[4];
    #pragma unroll
    for (int nt = 0; nt < 4; ++nt) { b1v[nt] = b1[nt * 16 + l15]; b2v[nt] = b2[nt * 16 + l15]; }
    half8 w3f[2];
    #pragma unroll
    for (int ks = 0; ks < 2; ++ks)
        #pragma unroll
        for (int j = 0; j < 8; ++j) {
            int s  = ks * 32 + quad * 8 + j;
            int oh = ((s & 3) << 4) | (s >> 2);
            w3f[ks][j] = (l15 < 3) ? (_Float16)w3[oh * 3 + l15] : (_Float16)0.0f;
        }
    const float qsel = (quad == 0) ? 1.0f : 0.0f;
    const float qb30 = qsel * b3[0], qb31 = qsel * b3[1], qb32 = qsel * b3[2];

    // ---- precomputed LDS addresses (half-element units) ----
    const int bufh = wv * 4096;
    const int ewr0 = bufh + lane * 64 + ((lane & 7) ^ 0) * 8;
    const int ewr1 = bufh + lane * 64 + ((lane & 7) ^ 1) * 8;
    const int erd  = bufh + l15 * 64 + (quad ^ (l15 & 7)) * 8;          // quad<2 only
    int hwb[4];
    #pragma unroll
    for (int r = 0; r < 4; ++r) {
        int pr = quad * 4 + r;
        hwb[r] = bufh + pr * 64 + (((l15 >> 1) ^ (pr & 7)) * 8) + (l15 & 1) * 4;
    }
    int rd2[2];
    #pragma unroll
    for (int ks = 0; ks < 2; ++ks)
        rd2[ks] = bufh + l15 * 64 + (((ks * 4 + quad) ^ (l15 & 7)) * 8);
    int w2a[2];
    #pragma unroll
    for (int ks = 0; ks < 2; ++ks)
        w2a[ks] = l15 * 64 + (((ks * 4 + quad) ^ (l15 & 7)) * 8);

    const int ntiles = npts >> 8;
    const int gdim   = gridDim.x;

    // ---- prologue: x[t0], x[t0+g] loaded; tile-0 gathers in flight ----
    float cidf, cu, cv;            // x of current tile
    float nidf, nu, nv;            // x of next tile (2-deep pipeline)
    float wx0, wy0, wx1, wy1;
    intx4 t0q, t1q;
    {
        int p0i = (blockIdx.x << 8) + (wv << 6) + lane;
        cidf = x[3 * p0i]; cu = x[3 * p0i + 1]; cv = x[3 * p0i + 2];
        int tn = blockIdx.x + gdim;
        int p1i = (((tn < ntiles) ? tn : blockIdx.x) << 8) + (wv << 6) + lane;
        nidf = x[3 * p1i]; nu = x[3 * p1i + 1]; nv = x[3 * p1i + 2];
        GQ g0 = gq(512, cu, cv); wx0 = g0.wx; wy0 = g0.wy;
        t0q = *(const intx4a*)&p0[g0.c];
        GQ g1 = gq(264, cu, cv); wx1 = g1.wx; wy1 = g1.wy;
        t1q = *(const intx4a*)&p1[g1.c];
    }

    for (int tile = blockIdx.x; tile < ntiles; tile += gdim) {
        // ---- 1. issue NEXT tile's gathers at the very top (1 load/table) ----
        float nwx0, nwy0, nwx1, nwy1;
        intx4 m0q, m1q;
        {
            GQ g0 = gq(512, nu, nv); nwx0 = g0.wx; nwy0 = g0.wy;
            m0q = *(const intx4a*)&p0[g0.c];
            GQ g1 = gq(264, nu, nv); nwx1 = g1.wx; nwy1 = g1.wy;
            m1q = *(const intx4a*)&p1[g1.c];
        }

        // ---- 2. issue x load for tile+2 (consumed next iteration) ----
        int nxt2 = tile + 2 * gdim;
        int ptn = (((nxt2 < ntiles) ? nxt2 : tile) << 8) + (wv << 6) + lane;
        float fidf = x[3 * ptn], fu = x[3 * ptn + 1], fv = x[3 * ptn + 2];

        // ---- 3. finish current tile's features: fp8 decode + f32 lerp
        //         (2^-13 folded into y-weights); emb2 from LDS ----
        float f0[4], f1[4];
        bil8(t0q, wx0, (1.0f - wy0) * INVSC, wy0 * INVSC, f0);
        bil8(t1q, wx1, (1.0f - wy1) * INVSC, wy1 * INVSC, f1);
        h2 F2[2];
        {
            GQ g2 = gq(16, cu, cv);
            half8 qa = *(const half8*)&e2l[g2.c * 16];
            half8 qb = *(const half8*)&e2l[g2.c * 16 + 8];
            bilq(qa, qb, g2.wx, g2.wy, F2);
        }
        // E pack: slots 0-11 = features, slot 12 = idf, 13-15 = 0
        union H8 { half8 v; h2 p[4]; } e0u, e1u;
        e0u.p[0] = pk2(f0[0], f0[1]); e0u.p[1] = pk2(f0[2], f0[3]);
        e0u.p[2] = pk2(f1[0], f1[1]); e0u.p[3] = pk2(f1[2], f1[3]);
        e1u.p[0] = F2[0]; e1u.p[1] = F2[1];
        e1u.p[2] = pk2(cidf, 0.0f); e1u.p[3] = pk2(0.0f, 0.0f);
        *(half8*)&smem[ewr0] = e0u.v;
        *(half8*)&smem[ewr1] = e1u.v;

        // ---- layer 1: K=32 (quads 2-3 feed zeros), bias in C-init ----
        #pragma unroll
        for (int mt = 0; mt < 4; ++mt) {
            half8 ea = { (_Float16)0, (_Float16)0, (_Float16)0, (_Float16)0,
                         (_Float16)0, (_Float16)0, (_Float16)0, (_Float16)0 };
            if (quad < 2) ea = *(const half8*)&smem[erd + mt * 1024];
            floatx4 acc[4];
            #pragma unroll
            for (int nt = 0; nt < 4; ++nt) {
                acc[nt] = (floatx4){ b1v[nt], b1v[nt], b1v[nt], b1v[nt] };
                acc[nt] = __builtin_amdgcn_mfma_f32_16x16x32_f16(ea, w1f[nt], acc[nt], 0, 0, 0);
            }
            #pragma unroll
            for (int r = 0; r < 4; ++r)
                *(half4*)&smem[hwb[r] + mt * 1024] =
                    relu_pk4(acc[0][r], acc[1][r], acc[2][r], acc[3][r]);
        }

        // ---- layer 2 (K=64): w2 frags reloaded phase-locally from LDS ----
        half8 w2r[4][2];
        #pragma unroll
        for (int nt = 0; nt < 4; ++nt)
            #pragma unroll
            for (int ks = 0; ks < 2; ++ks)
                w2r[nt][ks] = *(const half8*)&w2l[nt * 1024 + w2a[ks]];
        #pragma unroll
        for (int mt = 0; mt < 4; ++mt) {
            floatx4 acc[4];
            #pragma unroll
            for (int nt = 0; nt < 4; ++nt)
                acc[nt] = (floatx4){ b2v[nt], b2v[nt], b2v[nt], b2v[nt] };
            #pragma unroll
            for (int ks = 0; ks < 2; ++ks) {
                half8 a2 = *(const half8*)&smem[rd2[ks] + mt * 1024];
                #pragma unroll
                for (int nt = 0; nt < 4; ++nt)
                    acc[nt] = __builtin_amdgcn_mfma_f32_16x16x32_f16(a2, w2r[nt][ks], acc[nt], 0, 0, 0);
            }
            #pragma unroll
            for (int r = 0; r < 4; ++r)
                *(half4*)&smem[hwb[r] + mt * 1024] =
                    relu_pk4(acc[0][r], acc[1][r], acc[2][r], acc[3][r]);
        }

        // ---- layer 3 (transposed) ----
        #pragma unroll
        for (int mt = 0; mt < 4; ++mt) {
            floatx4 acc3 = (floatx4){ qb30, qb31, qb32, 0.0f };
            #pragma unroll
            for (int ks = 0; ks < 2; ++ks) {
                half8 bfr = *(const half8*)&smem[rd2[ks] + mt * 1024];
                acc3 = __builtin_amdgcn_mfma_f32_16x16x32_f16(w3f[ks], bfr, acc3, 0, 0, 0);
            }
            if (quad == 0) {
                const int P = (tile << 8) + (wv << 6) + mt * 16 + l15;
                out[3 * P + 0] = acc3[0];
                out[3 * P + 1] = acc3[1];
                out[3 * P + 2] = acc3[2];
            }
        }

        // ---- rotate pipeline registers ----
        cidf = nidf; cu = nu; cv = nv;
        nidf = fidf; nu = fu; nv = fv;
        wx0 = nwx0; wy0 = nwy0; wx1 = nwx1; wy1 = nwy1;
        t0q = m0q; t1q = m1q;
    }
}

// ---- fallback (validated round-3 kernel, float4 gathers) for tiny ws ----
__global__ __launch_bounds__(TPB, 3) void dgn_mfma_fb(
    const float*  __restrict__ x,
    const float4* __restrict__ emb0,
    const float4* __restrict__ emb1,
    const float4* __restrict__ emb2,
    const float*  __restrict__ w1, const float* __restrict__ b1,
    const float*  __restrict__ w2, const float* __restrict__ b2,
    const float*  __restrict__ w3, const float* __restrict__ b3,
    float*        __restrict__ out, int npts)
{
    __shared__ __align__(16) _Float16 smem[4 * 4096];
    __shared__ __align__(16) _Float16 w2l[4096];

    const int tid  = threadIdx.x;
    const int lane = tid & 63;
    const int wv   = tid >> 6;
    const int l15  = lane & 15;
    const int quad = lane >> 4;

    for (int e = tid; e < 4096; e += TPB) {
        int nt = e >> 10, rem = e & 1023, lw = rem >> 6, s = rem & 63;
        int oh = ((s & 3) << 4) | (s >> 2);
        w2l[nt * 1024 + lw * 64 + (s ^ ((lw & 7) << 3))] =
            (_Float16)w2[oh * 64 + nt * 16 + lw];
    }
    __syncthreads();

    half8 w1f[4];
    #pragma unroll
    for (int nt = 0; nt < 4; ++nt)
        #pragma unroll
        for (int j = 0; j < 8; ++j) {
            int k = quad * 8 + j;
            w1f[nt][j] = (k < 13) ? (_Float16)w1[k * 64 + nt * 16 + l15] : (_Float16)0.0f;
        }
    float b1v[4], b2v[4];
    #pragma unroll
    for (int nt = 0; nt < 4; ++nt) { b1v[nt] = b1[nt * 16 + l15]; b2v[nt] = b2[nt * 16 + l15]; }
    half8 w3f[2];
    #pragma unroll
    for (int ks = 0; ks < 2; ++ks)
        #pragma unroll
        for (int j = 0; j < 8; ++j) {
            int s  = ks * 32 + quad * 8 + j;
            int oh = ((s & 3) << 4) | (s >> 2);
            w3f[ks][j] = (l15 < 3) ? (_Float16)w3[oh * 3 + l15] : (_Float16)0.0f;
        }
    const float qsel = (quad == 0) ? 1.0f : 0.0f;
    const float qb30 = qsel * b3[0], qb31 = qsel * b3[1], qb32 = qsel * b3[2];

    const int bufh = wv * 4096;
    const int ewr0 = bufh + lane * 64 + ((lane & 7) ^ 0) * 8;
    const int ewr1 = bufh + lane * 64 + ((lane & 7) ^ 1) * 8;
    const int erd  = bufh + l15 * 64 + (quad ^ (l15 & 7)) * 8;
    int hwb[4];
    #pragma unroll
    for (int r = 0; r < 4; ++r) {
        int pr = quad * 4 + r;
        hwb[r] = bufh + pr * 64 + (((l15 >> 1) ^ (pr & 7)) * 8) + (l15 & 1) * 4;
    }
    int rd2[2];
    #pragma unroll
    for (int ks = 0; ks < 2; ++ks)
        rd2[ks] = bufh + l15 * 64 + (((ks * 4 + quad) ^ (l15 & 7)) * 8);
    int w2a[2];
    #pragma unroll
    for (int ks = 0; ks < 2; ++ks)
        w2a[ks] = l15 * 64 + (((ks * 4 + quad) ^ (l15 & 7)) * 8);

    const int ntiles = npts >> 8;
    const int gdim   = gridDim.x;

    float cidf, cu, cv, wx0, wy0, wx1, wy1;
    float4 t00, t01, t02, t03, t10, t11, t12, t13;
    {
        int p0 = (blockIdx.x << 8) + (wv << 6) + lane;
        cidf = x[3 * p0]; cu = x[3 * p0 + 1]; cv = x[3 * p0 + 2];
        GAddr g0 = gaddr(512, cu, cv); wx0 = g0.wx; wy0 = g0.wy;
        t00 = emb0[g0.i00]; t01 = emb0[g0.i10]; t02 = emb0[g0.i01]; t03 = emb0[g0.i11];
        GAddr g1 = gaddr(264, cu, cv); wx1 = g1.wx; wy1 = g1.wy;
        t10 = emb1[g1.i00]; t11 = emb1[g1.i10]; t12 = emb1[g1.i01]; t13 = emb1[g1.i11];
    }

    for (int tile = blockIdx.x; tile < ntiles; tile += gdim) {
        float f[12];
        bil4(t00, t01, t02, t03, wx0, wy0, f);
        bil4(t10, t11, t12, t13, wx1, wy1, f + 4);
        {
            GAddr g2 = gaddr(16, cu, cv);
            bil4(emb2[g2.i00], emb2[g2.i10], emb2[g2.i01], emb2[g2.i11], g2.wx, g2.wy, f + 8);
        }
        union H8 { half8 v; fp16x2 p[4]; } e0u, e1u;
        e0u.p[0] = __builtin_amdgcn_cvt_pkrtz(cidf, f[0]);
        e0u.p[1] = __builtin_amdgcn_cvt_pkrtz(f[1], f[2]);
        e0u.p[2] = __builtin_amdgcn_cvt_pkrtz(f[3], f[4]);
        e0u.p[3] = __builtin_amdgcn_cvt_pkrtz(f[5], f[6]);
        e1u.p[0] = __builtin_amdgcn_cvt_pkrtz(f[7], f[8]);
        e1u.p[1] = __builtin_amdgcn_cvt_pkrtz(f[9], f[10]);
        e1u.p[2] = __builtin_amdgcn_cvt_pkrtz(f[11], 0.0f);
        e1u.p[3] = __builtin_amdgcn_cvt_pkrtz(0.0f, 0.0f);
        *(half8*)&smem[ewr0] = e0u.v;
        *(half8*)&smem[ewr1] = e1u.v;

        int nxt = tile + gdim;
        int ptn = (((nxt < ntiles) ? nxt : tile) << 8) + (wv << 6) + lane;
        float nidf = x[3 * ptn], nu = x[3 * ptn + 1], nv = x[3 * ptn + 2];

        #pragma unroll
        for (int mt = 0; mt < 4; ++mt) {
            half8 ea = { (_Float16)0, (_Float16)0, (_Float16)0, (_Float16)0,
                         (_Float16)0, (_Float16)0, (_Float16)0, (_Float16)0 };
            if (quad < 2) ea = *(const half8*)&smem[erd + mt * 1024];
            floatx4 acc[4];
            #pragma unroll
            for (int nt = 0; nt < 4; ++nt) {
                acc[nt] = (floatx4){ b1v[nt], b1v[nt], b1v[nt], b1v[nt] };
                acc[nt] = __builtin_amdgcn_mfma_f32_16x16x32_f16(ea, w1f[nt], acc[nt], 0, 0, 0);
            }
            #pragma unroll
            for (int r = 0; r < 4; ++r)
                *(half4*)&smem[hwb[r] + mt * 1024] =
                    relu_pk4f(acc[0][r], acc[1][r], acc[2][r], acc[3][r]);
        }

        float nwx0, nwy0, nwx1, nwy1;
        float4 n00, n01, n02, n03, n10, n11, n12, n13;
        {
            GAddr g0 = gaddr(512, nu, nv); nwx0 = g0.wx; nwy0 = g0.wy;
            n00 = emb0[g0.i00]; n01 = emb0[g0.i10]; n02 = emb0[g0.i01]; n03 = emb0[g0.i11];
            GAddr g1 = gaddr(264, nu, nv); nwx1 = g1.wx; nwy1 = g1.wy;
            n10 = emb1[g1.i00]; n11 = emb1[g1.i10]; n12 = emb1[g1.i01]; n13 = emb1[g1.i11];
        }

        half8 w2r[4][2];
        #pragma unroll
        for (int nt = 0; nt < 4; ++nt)
            #pragma unroll
            for (int ks = 0; ks < 2; ++ks)
                w2r[nt][ks] = *(const half8*)&w2l[nt * 1024 + w2a[ks]];
        #pragma unroll
        for (int mt = 0; mt < 4; ++mt) {
            floatx4 acc[4];
            #pragma unroll
            for (int nt = 0; nt < 4; ++nt)
                acc[nt] = (floatx4){ b2v[nt], b2v[nt], b2v[nt], b2v[nt] };
            #pragma unroll
            for (int ks = 0; ks < 2; ++ks) {
                half8 a2 = *(const half8*)&smem[rd2[ks] + mt * 1024];
                #pragma unroll
                for (int nt = 0; nt < 4; ++nt)
                    acc[nt] = __builtin_amdgcn_mfma_f32_16x16x32_f16(a2, w2r[nt][ks], acc[nt], 0, 0, 0);
            }
            #pragma unroll
            for (int r = 0; r < 4; ++r)
                *(half4*)&smem[hwb[r] + mt * 1024] =
                    relu_pk4f(acc[0][r], acc[1][r], acc[2][r], acc[3][r]);
        }

        #pragma unroll
        for (int mt = 0; mt < 4; ++mt) {
            floatx4 acc3 = (floatx4){ qb30, qb31, qb32, 0.0f };
            #pragma unroll
            for (int ks = 0; ks < 2; ++ks) {
                half8 bfr = *(const half8*)&smem[rd2[ks] + mt * 1024];
                acc3 = __builtin_amdgcn_mfma_f32_16x16x32_f16(w3f[ks], bfr, acc3, 0, 0, 0);
            }
            if (quad == 0) {
                const int P = (tile << 8) + (wv << 6) + mt * 16 + l15;
                out[3 * P + 0] = acc3[0];
                out[3 * P + 1] = acc3[1];
                out[3 * P + 2] = acc3[2];
            }
        }

        cidf = nidf; cu = nu; cv = nv;
        wx0 = nwx0; wy0 = nwy0; wx1 = nwx1; wy1 = nwy1;
        t00 = n00; t01 = n01; t02 = n02; t03 = n03;
        t10 = n10; t11 = n11; t12 = n12; t13 = n13;
    }
}

extern "C" void kernel_launch(void* const* d_in, const int* in_sizes, int n_in,
                              void* d_out, int out_size, void* d_ws, size_t ws_size,
                              hipStream_t stream) {
    const float*  x    = (const float*)  d_in[0];
    const float4* emb0 = (const float4*) d_in[1];
    const float4* emb1 = (const float4*) d_in[2];
    const float4* emb2 = (const float4*) d_in[3];
    const float*  w1   = (const float*)  d_in[4];
    const float*  b1   = (const float*)  d_in[5];
    const float*  w2   = (const float*)  d_in[6];
    const float*  b2   = (const float*)  d_in[7];
    const float*  w3   = (const float*)  d_in[8];
    const float*  b3   = (const float*)  d_in[9];
    float* out = (float*)d_out;

    int npts = in_sizes[0] / 3;
    const size_t need = (size_t)(N0E + N1E) * 8 + (size_t)NC2 * 32;   // ~2.7 MB

    if (d_ws != nullptr && ws_size >= need) {
        int work = N0E + N1E + NC2;
        pack_tables<<<(work + 255) / 256, 256, 0, stream>>>(emb0, emb1, emb2, (int*)d_ws);
        dgn_mfma<<<768, TPB, 0, stream>>>(x, (const int2*)d_ws,
                                          w1, b1, w2, b2, w3, b3, out, npts);
    } else {
        dgn_mfma_fb<<<768, TPB, 0, stream>>>(x, emb0, emb1, emb2,
                                             w1, b1, w2, b2, w3, b3, out, npts);
    }
}